// Round 1
// baseline (845.949 us; speedup 1.0000x reference)
//
#include <hip/hip_runtime.h>
#include <math.h>

// Problem constants (fixed by the reference)
#define D_DIM 128
#define H_DIM 128
#define NHEAD 4
#define QKV_N 1664   // 3*NH*H + H (q|k|v|skip packed columns)
#define SQRT_H_INV 0.08838834764831845f  // 1/sqrt(128)

__device__ __forceinline__ float grp16_sum(float v) {
  v += __shfl_xor(v, 1);
  v += __shfl_xor(v, 2);
  v += __shfl_xor(v, 4);
  v += __shfl_xor(v, 8);
  return v;
}

// ---------------------------------------------------------------------------
// K0: event encoder MLP (single block, 128 threads) -> e[128]
// ---------------------------------------------------------------------------
__global__ __launch_bounds__(128) void k_event(
    const float* __restrict__ ef, int EV,
    const float* __restrict__ w1, const float* __restrict__ b1,
    const float* __restrict__ g1, const float* __restrict__ bt1,
    const float* __restrict__ w2, const float* __restrict__ b2,
    const float* __restrict__ g2, const float* __restrict__ bt2,
    const float* __restrict__ ett, const int* __restrict__ etid,
    const float* __restrict__ inten, int K,
    float* __restrict__ e_out)
{
  __shared__ float sh[H_DIM];
  __shared__ float red[H_DIM];
  const int t = threadIdx.x;

  float acc = b1[t];
  for (int i = 0; i < EV; ++i) acc += ef[i] * w1[i * H_DIM + t];

  // LayerNorm 1
  red[t] = acc; __syncthreads();
  for (int s = 64; s > 0; s >>= 1) { if (t < s) red[t] += red[t + s]; __syncthreads(); }
  float mu = red[0] / H_DIM; __syncthreads();
  float d = acc - mu;
  red[t] = d * d; __syncthreads();
  for (int s = 64; s > 0; s >>= 1) { if (t < s) red[t] += red[t + s]; __syncthreads(); }
  float var = red[0] / H_DIM; __syncthreads();
  float y = d * rsqrtf(var + 1e-5f) * g1[t] + bt1[t];
  y = fmaxf(y, 0.f);
  sh[t] = y; __syncthreads();

  float acc2 = b2[t];
  for (int i = 0; i < H_DIM; ++i) acc2 += sh[i] * w2[i * H_DIM + t];

  // LayerNorm 2
  red[t] = acc2; __syncthreads();
  for (int s = 64; s > 0; s >>= 1) { if (t < s) red[t] += red[t + s]; __syncthreads(); }
  mu = red[0] / H_DIM; __syncthreads();
  d = acc2 - mu;
  red[t] = d * d; __syncthreads();
  for (int s = 64; s > 0; s >>= 1) { if (t < s) red[t] += red[t + s]; __syncthreads(); }
  var = red[0] / H_DIM; __syncthreads();
  float y2 = d * rsqrtf(var + 1e-5f) * g2[t] + bt2[t];
  y2 = fmaxf(y2, 0.f);

  // + mean_k ett[etid[k]] * inten[k]
  float m = 0.f;
  for (int k = 0; k < K; ++k) m += ett[etid[k] * H_DIM + t] * inten[k];
  e_out[t] = y2 + m / (float)K;
}

// ---------------------------------------------------------------------------
// K1: constant column vector  cvec[j] = e @ W[128:256, j] + b[j]  (q|k|v|skip)
// ---------------------------------------------------------------------------
__global__ __launch_bounds__(256) void k_cvec(
    const float* __restrict__ e,
    const float* __restrict__ wq, const float* __restrict__ bq,
    const float* __restrict__ wk, const float* __restrict__ bk,
    const float* __restrict__ wv, const float* __restrict__ bv,
    const float* __restrict__ wskip, const float* __restrict__ bskip,
    float* __restrict__ cvec)
{
  __shared__ float es[H_DIM];
  const int t = threadIdx.x;
  if (t < H_DIM) es[t] = e[t];
  __syncthreads();
  int j = blockIdx.x * 256 + t;
  if (j >= QKV_N) return;
  const float* W; const float* b; int col; int stride;
  if (j < 512)       { W = wq;    b = bq;    col = j;        stride = 512; }
  else if (j < 1024) { W = wk;    b = bk;    col = j - 512;  stride = 512; }
  else if (j < 1536) { W = wv;    b = bv;    col = j - 1024; stride = 512; }
  else               { W = wskip; b = bskip; col = j - 1536; stride = 128; }
  float a = b[col];
  for (int i = 0; i < H_DIM; ++i) a += es[i] * W[(D_DIM + i) * stride + col];
  cvec[j] = a;
}

// K1b: pack B1[128][1664] = rows 0..127 of [wq | wk | wv | wskip]
__global__ __launch_bounds__(256) void k_pack(
    const float* __restrict__ wq, const float* __restrict__ wk,
    const float* __restrict__ wv, const float* __restrict__ wskip,
    float* __restrict__ B1)
{
  int idx = blockIdx.x * 256 + threadIdx.x;
  if (idx >= D_DIM * QKV_N) return;
  int i = idx / QKV_N, j = idx - i * QKV_N;
  float v;
  if (j < 512)       v = wq[i * 512 + j];
  else if (j < 1024) v = wk[i * 512 + (j - 512)];
  else if (j < 1536) v = wv[i * 512 + (j - 1024)];
  else               v = wskip[i * 128 + (j - 1536)];
  B1[idx] = v;
}

// K1c: LSTM constant bias = bih + bhh
__global__ __launch_bounds__(256) void k_cvec2(
    const float* __restrict__ bih, const float* __restrict__ bhh,
    float* __restrict__ cvec2)
{
  int j = blockIdx.x * 256 + threadIdx.x;
  if (j < 512) cvec2[j] = bih[j] + bhh[j];
}

// ---------------------------------------------------------------------------
// SGEMM, K fixed = 128.  C[M,Nn] = A[M,128] @ B[128,Nn] (+cvec[Nn])
// Optional row gather via ids. BM=BN=128, BK=32, 256 thr, 8x8 per thread.
// ---------------------------------------------------------------------------
__global__ __launch_bounds__(256) void sgemm_k128(
    const float* __restrict__ A, const int* __restrict__ ids,
    const float* __restrict__ B, const float* __restrict__ cvec,
    float* __restrict__ C, int M, int Nn)
{
  __shared__ float As[32][132];  // [k][m] transposed, padded
  __shared__ float Bs[32][132];  // [k][n] padded
  const int t = threadIdx.x;
  const int tx = t & 15;
  const int ty = t >> 4;
  const int bm = blockIdx.y * 128;
  const int bn = blockIdx.x * 128;

  float acc[8][8];
#pragma unroll
  for (int i = 0; i < 8; ++i)
#pragma unroll
    for (int j = 0; j < 8; ++j) acc[i][j] = 0.f;

  for (int k0 = 0; k0 < 128; k0 += 32) {
#pragma unroll
    for (int i = 0; i < 4; ++i) {
      int f = t + i * 256;          // 0..1023
      int m = f >> 3;               // 128 rows
      int kc = (f & 7) << 2;        // 0..28
      int row = bm + m;
      float4 a4 = make_float4(0.f, 0.f, 0.f, 0.f);
      if (row < M) {
        int ar = ids ? ids[row] : row;
        a4 = *(const float4*)(A + (size_t)ar * 128 + k0 + kc);
      }
      As[kc + 0][m] = a4.x; As[kc + 1][m] = a4.y;
      As[kc + 2][m] = a4.z; As[kc + 3][m] = a4.w;
    }
#pragma unroll
    for (int i = 0; i < 4; ++i) {
      int f = t + i * 256;
      int kr = f >> 5;              // 32 rows
      int nc = (f & 31) << 2;       // 0..124
      float4 b4 = *(const float4*)(B + (size_t)(k0 + kr) * Nn + bn + nc);
      *(float4*)&Bs[kr][nc] = b4;
    }
    __syncthreads();
#pragma unroll
    for (int k = 0; k < 32; ++k) {
      float a[8], b[8];
      *(float4*)&a[0] = *(const float4*)&As[k][ty * 8];
      *(float4*)&a[4] = *(const float4*)&As[k][ty * 8 + 4];
      *(float4*)&b[0] = *(const float4*)&Bs[k][tx * 8];
      *(float4*)&b[4] = *(const float4*)&Bs[k][tx * 8 + 4];
#pragma unroll
      for (int i = 0; i < 8; ++i)
#pragma unroll
        for (int j = 0; j < 8; ++j)
          acc[i][j] = fmaf(a[i], b[j], acc[i][j]);
    }
    __syncthreads();
  }

#pragma unroll
  for (int i = 0; i < 8; ++i) {
    int m = bm + ty * 8 + i;
    if (m >= M) continue;
    float* crow = C + (size_t)m * Nn + bn + tx * 8;
#pragma unroll
    for (int jj = 0; jj < 8; jj += 4) {
      int n = bn + tx * 8 + jj;
      float4 o;
      o.x = acc[i][jj + 0] + (cvec ? cvec[n + 0] : 0.f);
      o.y = acc[i][jj + 1] + (cvec ? cvec[n + 1] : 0.f);
      o.z = acc[i][jj + 2] + (cvec ? cvec[n + 2] : 0.f);
      o.w = acc[i][jj + 3] + (cvec ? cvec[n + 3] : 0.f);
      *(float4*)(crow + jj) = o;
    }
  }
}

// ---------------------------------------------------------------------------
// CSR build
// ---------------------------------------------------------------------------
__global__ __launch_bounds__(256) void k_zero(int* __restrict__ p, int n) {
  int i = blockIdx.x * 256 + threadIdx.x;
  if (i < n) p[i] = 0;
}
__global__ __launch_bounds__(256) void k_count(
    const int* __restrict__ dst, int* __restrict__ counts, int E) {
  int e = blockIdx.x * 256 + threadIdx.x;
  if (e < E) atomicAdd(&counts[dst[e]], 1);
}
__global__ __launch_bounds__(1024) void k_scan(
    const int* __restrict__ counts, int* __restrict__ offs,
    int* __restrict__ cursor, int N)
{
  __shared__ int sh[1024];
  const int t = threadIdx.x;
  int running = 0;
  for (int base = 0; base < N; base += 1024) {
    int v = (base + t < N) ? counts[base + t] : 0;
    __syncthreads();
    sh[t] = v; __syncthreads();
    for (int s = 1; s < 1024; s <<= 1) {
      int add = (t >= s) ? sh[t - s] : 0;
      __syncthreads();
      sh[t] += add;
      __syncthreads();
    }
    int incl = sh[t];
    if (base + t < N) {
      offs[base + t + 1] = running + incl;
      cursor[base + t] = running + incl - v;
    }
    int tot = sh[1023];
    running += tot;
  }
  if (t == 0) offs[0] = 0;
}
__global__ __launch_bounds__(256) void k_fill(
    const int* __restrict__ src, const int* __restrict__ dst,
    int* __restrict__ cursor, int* __restrict__ csr_src, int E) {
  int e = blockIdx.x * 256 + threadIdx.x;
  if (e < E) {
    int slot = atomicAdd(&cursor[dst[e]], 1);
    csr_src[slot] = src[e];
  }
}

// ---------------------------------------------------------------------------
// TransformerConv aggregation: one wave per node.
// C1 row: [q(512) | k(512) | v(512) | skip(128)]
// Lane l holds channels (l*8..l*8+7) of head (l>>4).
// ---------------------------------------------------------------------------
__global__ __launch_bounds__(256) void k_tconv(
    const float* __restrict__ C1, const int* __restrict__ offs,
    const int* __restrict__ csr_src, float* __restrict__ x1, int N)
{
  const int wid = threadIdx.x >> 6;
  const int lane = threadIdx.x & 63;
  const int node = blockIdx.x * 4 + wid;
  if (node >= N) return;
  const float* crow = C1 + (size_t)node * QKV_N;
  float q[8];
  {
    float4 q0 = *(const float4*)(crow + lane * 8);
    float4 q1 = *(const float4*)(crow + lane * 8 + 4);
    q[0]=q0.x; q[1]=q0.y; q[2]=q0.z; q[3]=q0.w;
    q[4]=q1.x; q[5]=q1.y; q[6]=q1.z; q[7]=q1.w;
  }
  const int beg = offs[node], end = offs[node + 1];
  float mx = -1e30f;
  for (int e = beg; e < end; ++e) {
    int s = csr_src[e];
    const float* kr = C1 + (size_t)s * QKV_N + 512;
    float4 k0 = *(const float4*)(kr + lane * 8);
    float4 k1 = *(const float4*)(kr + lane * 8 + 4);
    float p = q[0]*k0.x + q[1]*k0.y + q[2]*k0.z + q[3]*k0.w
            + q[4]*k1.x + q[5]*k1.y + q[6]*k1.z + q[7]*k1.w;
    p = grp16_sum(p) * SQRT_H_INV;
    mx = fmaxf(mx, p);
  }
  float ssum = 0.f;
  float acc[8] = {0.f,0.f,0.f,0.f,0.f,0.f,0.f,0.f};
  for (int e = beg; e < end; ++e) {
    int s = csr_src[e];
    const float* kr = C1 + (size_t)s * QKV_N + 512;
    float4 k0 = *(const float4*)(kr + lane * 8);
    float4 k1 = *(const float4*)(kr + lane * 8 + 4);
    float p = q[0]*k0.x + q[1]*k0.y + q[2]*k0.z + q[3]*k0.w
            + q[4]*k1.x + q[5]*k1.y + q[6]*k1.z + q[7]*k1.w;
    p = grp16_sum(p) * SQRT_H_INV;
    float w = expf(p - mx);
    ssum += w;
    const float* vr = C1 + (size_t)s * QKV_N + 1024;
    float4 v0 = *(const float4*)(vr + lane * 8);
    float4 v1 = *(const float4*)(vr + lane * 8 + 4);
    acc[0] += w*v0.x; acc[1] += w*v0.y; acc[2] += w*v0.z; acc[3] += w*v0.w;
    acc[4] += w*v1.x; acc[5] += w*v1.y; acc[6] += w*v1.z; acc[7] += w*v1.w;
  }
  float inv = 1.f / (ssum + 1e-16f);
#pragma unroll
  for (int j = 0; j < 8; ++j) acc[j] *= inv;
#pragma unroll
  for (int j = 0; j < 8; ++j) {
    acc[j] += __shfl_xor(acc[j], 16);
    acc[j] += __shfl_xor(acc[j], 32);
  }
  if (lane < 16) {
    const float* sk = crow + 1536 + lane * 8;
    float* xo = x1 + (size_t)node * 128 + lane * 8;
#pragma unroll
    for (int j = 0; j < 8; ++j) xo[j] = 0.25f * acc[j] + sk[j];
  }
}

// ---------------------------------------------------------------------------
// GAT attention coefficients: a_s[n,h] = sum_c xh[n,h,c]*as[h,c]; same for a_d
// ---------------------------------------------------------------------------
__global__ __launch_bounds__(256) void k_gat_ad(
    const float* __restrict__ xh, const float* __restrict__ as_w,
    const float* __restrict__ ad_w, float* __restrict__ a_s,
    float* __restrict__ a_d, int N)
{
  const int wid = threadIdx.x >> 6;
  const int lane = threadIdx.x & 63;
  const int node = blockIdx.x * 4 + wid;
  if (node >= N) return;
  const int head = lane >> 4;
  const int c0 = (lane & 15) * 8;
  const float* xr = xh + (size_t)node * 512 + lane * 8;
  float4 x0 = *(const float4*)(xr);
  float4 x1_ = *(const float4*)(xr + 4);
  const float* aw = as_w + head * 128 + c0;
  const float* dw = ad_w + head * 128 + c0;
  float s1 = x0.x*aw[0] + x0.y*aw[1] + x0.z*aw[2] + x0.w*aw[3]
           + x1_.x*aw[4] + x1_.y*aw[5] + x1_.z*aw[6] + x1_.w*aw[7];
  float s2 = x0.x*dw[0] + x0.y*dw[1] + x0.z*dw[2] + x0.w*dw[3]
           + x1_.x*dw[4] + x1_.y*dw[5] + x1_.z*dw[6] + x1_.w*dw[7];
  s1 = grp16_sum(s1);
  s2 = grp16_sum(s2);
  if ((lane & 15) == 0) {
    a_s[node * 4 + head] = s1;
    a_d[node * 4 + head] = s2;
  }
}

// ---------------------------------------------------------------------------
// GAT aggregation (incl. implicit self loop): one wave per node
// ---------------------------------------------------------------------------
__global__ __launch_bounds__(256) void k_gat_agg(
    const float* __restrict__ xh, const float* __restrict__ a_s,
    const float* __restrict__ a_d, const int* __restrict__ offs,
    const int* __restrict__ csr_src, const float* __restrict__ bias,
    float* __restrict__ xout, int N)
{
  const int wid = threadIdx.x >> 6;
  const int lane = threadIdx.x & 63;
  const int node = blockIdx.x * 4 + wid;
  if (node >= N) return;
  const int head = lane >> 4;
  const float adn = a_d[node * 4 + head];
  const float asn = a_s[node * 4 + head];
  const float lself = (asn + adn) >= 0.f ? (asn + adn) : 0.2f * (asn + adn);
  float mx = lself;
  const int beg = offs[node], end = offs[node + 1];
  for (int e = beg; e < end; ++e) {
    int s = csr_src[e];
    float l = a_s[s * 4 + head] + adn;
    l = l >= 0.f ? l : 0.2f * l;
    mx = fmaxf(mx, l);
  }
  float ssum = 0.f;
  float acc[8] = {0.f,0.f,0.f,0.f,0.f,0.f,0.f,0.f};
  {
    float w = expf(lself - mx);
    ssum += w;
    const float* xr = xh + (size_t)node * 512 + lane * 8;
    float4 x0 = *(const float4*)(xr);
    float4 x1_ = *(const float4*)(xr + 4);
    acc[0] += w*x0.x; acc[1] += w*x0.y; acc[2] += w*x0.z; acc[3] += w*x0.w;
    acc[4] += w*x1_.x; acc[5] += w*x1_.y; acc[6] += w*x1_.z; acc[7] += w*x1_.w;
  }
  for (int e = beg; e < end; ++e) {
    int s = csr_src[e];
    float l = a_s[s * 4 + head] + adn;
    l = l >= 0.f ? l : 0.2f * l;
    float w = expf(l - mx);
    ssum += w;
    const float* xr = xh + (size_t)s * 512 + lane * 8;
    float4 x0 = *(const float4*)(xr);
    float4 x1_ = *(const float4*)(xr + 4);
    acc[0] += w*x0.x; acc[1] += w*x0.y; acc[2] += w*x0.z; acc[3] += w*x0.w;
    acc[4] += w*x1_.x; acc[5] += w*x1_.y; acc[6] += w*x1_.z; acc[7] += w*x1_.w;
  }
  float inv = 1.f / (ssum + 1e-16f);
#pragma unroll
  for (int j = 0; j < 8; ++j) acc[j] *= inv;
#pragma unroll
  for (int j = 0; j < 8; ++j) {
    acc[j] += __shfl_xor(acc[j], 16);
    acc[j] += __shfl_xor(acc[j], 32);
  }
  if (lane < 16) {
    const float* b = bias + lane * 8;
    float* xo = xout + (size_t)node * 128 + lane * 8;
#pragma unroll
    for (int j = 0; j < 8; ++j) xo[j] = fmaxf(0.25f * acc[j] + b[j], 0.f);
  }
}

// ---------------------------------------------------------------------------
// LSTM elementwise epilogue (h0=c0=0; gate order i,f,g,o; gf unused)
// ---------------------------------------------------------------------------
__global__ __launch_bounds__(256) void k_lstm(
    const float* __restrict__ gates, float* __restrict__ out, int N)
{
  int idx = blockIdx.x * 256 + threadIdx.x;
  if (idx >= N * 128) return;
  int n = idx >> 7, c = idx & 127;
  const float* g = gates + (size_t)n * 512;
  float gi = g[c], gg = g[256 + c], go = g[384 + c];
  float cv = (1.f / (1.f + expf(-gi))) * tanhf(gg);
  float hv = (1.f / (1.f + expf(-go))) * tanhf(cv);
  out[idx] = hv;
  out[(size_t)N * 128 + idx] = cv;
}

// ---------------------------------------------------------------------------
extern "C" void kernel_launch(void* const* d_in, const int* in_sizes, int n_in,
                              void* d_out, int out_size, void* d_ws, size_t ws_size,
                              hipStream_t stream) {
  const int*   node_ids = (const int*)d_in[0];
  const int*   etid     = (const int*)d_in[1];
  const int*   src      = (const int*)d_in[2];
  const int*   dst      = (const int*)d_in[3];
  const float* ef       = (const float*)d_in[4];
  const float* inten    = (const float*)d_in[5];
  const float* nemb     = (const float*)d_in[6];
  const float* ett      = (const float*)d_in[7];
  const float* ev_w1 = (const float*)d_in[8],  *ev_b1 = (const float*)d_in[9];
  const float* ev_g1 = (const float*)d_in[10], *ev_bt1 = (const float*)d_in[11];
  const float* ev_w2 = (const float*)d_in[12], *ev_b2 = (const float*)d_in[13];
  const float* ev_g2 = (const float*)d_in[14], *ev_bt2 = (const float*)d_in[15];
  const float* wq = (const float*)d_in[16], *bq = (const float*)d_in[17];
  const float* wk = (const float*)d_in[18], *bk = (const float*)d_in[19];
  const float* wv = (const float*)d_in[20], *bv = (const float*)d_in[21];
  const float* wskip = (const float*)d_in[22], *bskip = (const float*)d_in[23];
  const float* g0_w = (const float*)d_in[24], *g0_as = (const float*)d_in[25];
  const float* g0_ad = (const float*)d_in[26], *g0_b = (const float*)d_in[27];
  const float* g1_w = (const float*)d_in[28], *g1_as = (const float*)d_in[29];
  const float* g1_ad = (const float*)d_in[30], *g1_b = (const float*)d_in[31];
  const float* wih = (const float*)d_in[32];
  const float* bih = (const float*)d_in[34], *bhh = (const float*)d_in[35];

  const int N = in_sizes[0];
  const int K = in_sizes[1];
  const int E = in_sizes[2];
  const int EV = in_sizes[4];

  float* ws = (float*)d_ws;
  size_t o = 0;
  float* e_vec = ws + o; o += 128;
  float* cvec1 = ws + o; o += QKV_N;
  float* cvec2 = ws + o; o += 512;
  float* B1    = ws + o; o += (size_t)128 * QKV_N;
  float* C1    = ws + o; o += (size_t)N * QKV_N;
  float* x_a   = ws + o; o += (size_t)N * 128;
  float* x_b   = ws + o; o += (size_t)N * 128;
  float* xh    = ws + o; o += (size_t)N * 512;
  float* a_s   = ws + o; o += (size_t)N * 4;
  float* a_d   = ws + o; o += (size_t)N * 4;
  int* counts  = (int*)(ws + o); o += N;
  int* offs    = (int*)(ws + o); o += (size_t)N + 1;
  int* cursor  = (int*)(ws + o); o += N;
  int* csr_src = (int*)(ws + o); o += E;

  float* out = (float*)d_out;

  const int nodeBlocks = (N + 3) / 4;
  const int gridMy = (N + 127) / 128;

  // --- tiny setup kernels ---
  k_event<<<1, 128, 0, stream>>>(ef, EV, ev_w1, ev_b1, ev_g1, ev_bt1,
                                 ev_w2, ev_b2, ev_g2, ev_bt2,
                                 ett, etid, inten, K, e_vec);
  k_cvec<<<(QKV_N + 255) / 256, 256, 0, stream>>>(e_vec, wq, bq, wk, bk, wv, bv,
                                                  wskip, bskip, cvec1);
  k_pack<<<(D_DIM * QKV_N + 255) / 256, 256, 0, stream>>>(wq, wk, wv, wskip, B1);
  k_cvec2<<<2, 256, 0, stream>>>(bih, bhh, cvec2);

  // --- CSR build ---
  k_zero<<<(N + 255) / 256, 256, 0, stream>>>(counts, N);
  k_count<<<(E + 255) / 256, 256, 0, stream>>>(dst, counts, E);
  k_scan<<<1, 1024, 0, stream>>>(counts, offs, cursor, N);
  k_fill<<<(E + 255) / 256, 256, 0, stream>>>(src, dst, cursor, csr_src, E);

  // --- QKV + skip fused GEMM: C1[N,1664] ---
  sgemm_k128<<<dim3(QKV_N / 128, gridMy), 256, 0, stream>>>(
      nemb, node_ids, B1, cvec1, C1, N, QKV_N);

  // --- TransformerConv aggregation -> x_a[N,128] ---
  k_tconv<<<nodeBlocks, 256, 0, stream>>>(C1, offs, csr_src, x_a, N);

  // --- GAT layer 1 ---
  sgemm_k128<<<dim3(512 / 128, gridMy), 256, 0, stream>>>(
      x_a, nullptr, g0_w, nullptr, xh, N, 512);
  k_gat_ad<<<nodeBlocks, 256, 0, stream>>>(xh, g0_as, g0_ad, a_s, a_d, N);
  k_gat_agg<<<nodeBlocks, 256, 0, stream>>>(xh, a_s, a_d, offs, csr_src, g0_b, x_b, N);

  // --- GAT layer 2 ---
  sgemm_k128<<<dim3(512 / 128, gridMy), 256, 0, stream>>>(
      x_b, nullptr, g1_w, nullptr, xh, N, 512);
  k_gat_ad<<<nodeBlocks, 256, 0, stream>>>(xh, g1_as, g1_ad, a_s, a_d, N);
  k_gat_agg<<<nodeBlocks, 256, 0, stream>>>(xh, a_s, a_d, offs, csr_src, g1_b, x_a, N);

  // --- LSTM ---
  sgemm_k128<<<dim3(512 / 128, gridMy), 256, 0, stream>>>(
      x_a, nullptr, wih, cvec2, xh, N, 512);
  k_lstm<<<((N * 128) + 255) / 256, 256, 0, stream>>>(xh, out, N);
}

// Round 2
// 763.476 us; speedup vs baseline: 1.1080x; 1.1080x over previous
//
#include <hip/hip_runtime.h>
#include <math.h>

// Problem constants (fixed by the reference)
#define D_DIM 128
#define H_DIM 128
#define NHEAD 4
#define QKV_N 1664   // 3*NH*H + H (q|k|v|skip packed columns)
#define SQRT_H_INV 0.08838834764831845f  // 1/sqrt(128)

__device__ __forceinline__ float grp16_sum(float v) {
  v += __shfl_xor(v, 1);
  v += __shfl_xor(v, 2);
  v += __shfl_xor(v, 4);
  v += __shfl_xor(v, 8);
  return v;
}

// ---------------------------------------------------------------------------
// K0: event encoder MLP (single block, 128 threads) -> e[128]
// ---------------------------------------------------------------------------
__global__ __launch_bounds__(128) void k_event(
    const float* __restrict__ ef, int EV,
    const float* __restrict__ w1, const float* __restrict__ b1,
    const float* __restrict__ g1, const float* __restrict__ bt1,
    const float* __restrict__ w2, const float* __restrict__ b2,
    const float* __restrict__ g2, const float* __restrict__ bt2,
    const float* __restrict__ ett, const int* __restrict__ etid,
    const float* __restrict__ inten, int K,
    float* __restrict__ e_out)
{
  __shared__ float sh[H_DIM];
  __shared__ float red[H_DIM];
  const int t = threadIdx.x;

  float acc = b1[t];
  for (int i = 0; i < EV; ++i) acc += ef[i] * w1[i * H_DIM + t];

  // LayerNorm 1
  red[t] = acc; __syncthreads();
  for (int s = 64; s > 0; s >>= 1) { if (t < s) red[t] += red[t + s]; __syncthreads(); }
  float mu = red[0] / H_DIM; __syncthreads();
  float d = acc - mu;
  red[t] = d * d; __syncthreads();
  for (int s = 64; s > 0; s >>= 1) { if (t < s) red[t] += red[t + s]; __syncthreads(); }
  float var = red[0] / H_DIM; __syncthreads();
  float y = d * rsqrtf(var + 1e-5f) * g1[t] + bt1[t];
  y = fmaxf(y, 0.f);
  sh[t] = y; __syncthreads();

  float acc2 = b2[t];
  for (int i = 0; i < H_DIM; ++i) acc2 += sh[i] * w2[i * H_DIM + t];

  // LayerNorm 2
  red[t] = acc2; __syncthreads();
  for (int s = 64; s > 0; s >>= 1) { if (t < s) red[t] += red[t + s]; __syncthreads(); }
  mu = red[0] / H_DIM; __syncthreads();
  d = acc2 - mu;
  red[t] = d * d; __syncthreads();
  for (int s = 64; s > 0; s >>= 1) { if (t < s) red[t] += red[t + s]; __syncthreads(); }
  var = red[0] / H_DIM; __syncthreads();
  float y2 = d * rsqrtf(var + 1e-5f) * g2[t] + bt2[t];
  y2 = fmaxf(y2, 0.f);

  // + mean_k ett[etid[k]] * inten[k]
  float m = 0.f;
  for (int k = 0; k < K; ++k) m += ett[etid[k] * H_DIM + t] * inten[k];
  e_out[t] = y2 + m / (float)K;
}

// ---------------------------------------------------------------------------
// K1: constant column vector  cvec[j] = e @ W[128:256, j] + b[j]  (q|k|v|skip)
// ---------------------------------------------------------------------------
__global__ __launch_bounds__(256) void k_cvec(
    const float* __restrict__ e,
    const float* __restrict__ wq, const float* __restrict__ bq,
    const float* __restrict__ wk, const float* __restrict__ bk,
    const float* __restrict__ wv, const float* __restrict__ bv,
    const float* __restrict__ wskip, const float* __restrict__ bskip,
    float* __restrict__ cvec)
{
  __shared__ float es[H_DIM];
  const int t = threadIdx.x;
  if (t < H_DIM) es[t] = e[t];
  __syncthreads();
  int j = blockIdx.x * 256 + t;
  if (j >= QKV_N) return;
  const float* W; const float* b; int col; int stride;
  if (j < 512)       { W = wq;    b = bq;    col = j;        stride = 512; }
  else if (j < 1024) { W = wk;    b = bk;    col = j - 512;  stride = 512; }
  else if (j < 1536) { W = wv;    b = bv;    col = j - 1024; stride = 512; }
  else               { W = wskip; b = bskip; col = j - 1536; stride = 128; }
  float a = b[col];
  for (int i = 0; i < H_DIM; ++i) a += es[i] * W[(D_DIM + i) * stride + col];
  cvec[j] = a;
}

// K1b: pack B1[128][1664] = rows 0..127 of [wq | wk | wv | wskip]
__global__ __launch_bounds__(256) void k_pack(
    const float* __restrict__ wq, const float* __restrict__ wk,
    const float* __restrict__ wv, const float* __restrict__ wskip,
    float* __restrict__ B1)
{
  int idx = blockIdx.x * 256 + threadIdx.x;
  if (idx >= D_DIM * QKV_N) return;
  int i = idx / QKV_N, j = idx - i * QKV_N;
  float v;
  if (j < 512)       v = wq[i * 512 + j];
  else if (j < 1024) v = wk[i * 512 + (j - 512)];
  else if (j < 1536) v = wv[i * 512 + (j - 1024)];
  else               v = wskip[i * 128 + (j - 1536)];
  B1[idx] = v;
}

// K1c: LSTM constant bias = bih + bhh
__global__ __launch_bounds__(256) void k_cvec2(
    const float* __restrict__ bih, const float* __restrict__ bhh,
    float* __restrict__ cvec2)
{
  int j = blockIdx.x * 256 + threadIdx.x;
  if (j < 512) cvec2[j] = bih[j] + bhh[j];
}

// ---------------------------------------------------------------------------
// SGEMM, K fixed = 128.  C[M,Nn] = A[M,128] @ B[128,Nn] (+cvec[Nn])
// Optional row gather via ids. BM=BN=128, BK=32, 256 thr, 8x8 per thread.
// ---------------------------------------------------------------------------
__global__ __launch_bounds__(256) void sgemm_k128(
    const float* __restrict__ A, const int* __restrict__ ids,
    const float* __restrict__ B, const float* __restrict__ cvec,
    float* __restrict__ C, int M, int Nn)
{
  __shared__ float As[32][132];  // [k][m] transposed, padded
  __shared__ float Bs[32][132];  // [k][n] padded
  const int t = threadIdx.x;
  const int tx = t & 15;
  const int ty = t >> 4;
  const int bm = blockIdx.y * 128;
  const int bn = blockIdx.x * 128;

  float acc[8][8];
#pragma unroll
  for (int i = 0; i < 8; ++i)
#pragma unroll
    for (int j = 0; j < 8; ++j) acc[i][j] = 0.f;

  for (int k0 = 0; k0 < 128; k0 += 32) {
#pragma unroll
    for (int i = 0; i < 4; ++i) {
      int f = t + i * 256;          // 0..1023
      int m = f >> 3;               // 128 rows
      int kc = (f & 7) << 2;        // 0..28
      int row = bm + m;
      float4 a4 = make_float4(0.f, 0.f, 0.f, 0.f);
      if (row < M) {
        int ar = ids ? ids[row] : row;
        a4 = *(const float4*)(A + (size_t)ar * 128 + k0 + kc);
      }
      As[kc + 0][m] = a4.x; As[kc + 1][m] = a4.y;
      As[kc + 2][m] = a4.z; As[kc + 3][m] = a4.w;
    }
#pragma unroll
    for (int i = 0; i < 4; ++i) {
      int f = t + i * 256;
      int kr = f >> 5;              // 32 rows
      int nc = (f & 31) << 2;       // 0..124
      float4 b4 = *(const float4*)(B + (size_t)(k0 + kr) * Nn + bn + nc);
      *(float4*)&Bs[kr][nc] = b4;
    }
    __syncthreads();
#pragma unroll
    for (int k = 0; k < 32; ++k) {
      float a[8], b[8];
      *(float4*)&a[0] = *(const float4*)&As[k][ty * 8];
      *(float4*)&a[4] = *(const float4*)&As[k][ty * 8 + 4];
      *(float4*)&b[0] = *(const float4*)&Bs[k][tx * 8];
      *(float4*)&b[4] = *(const float4*)&Bs[k][tx * 8 + 4];
#pragma unroll
      for (int i = 0; i < 8; ++i)
#pragma unroll
        for (int j = 0; j < 8; ++j)
          acc[i][j] = fmaf(a[i], b[j], acc[i][j]);
    }
    __syncthreads();
  }

#pragma unroll
  for (int i = 0; i < 8; ++i) {
    int m = bm + ty * 8 + i;
    if (m >= M) continue;
    float* crow = C + (size_t)m * Nn + bn + tx * 8;
#pragma unroll
    for (int jj = 0; jj < 8; jj += 4) {
      int n = bn + tx * 8 + jj;
      float4 o;
      o.x = acc[i][jj + 0] + (cvec ? cvec[n + 0] : 0.f);
      o.y = acc[i][jj + 1] + (cvec ? cvec[n + 1] : 0.f);
      o.z = acc[i][jj + 2] + (cvec ? cvec[n + 2] : 0.f);
      o.w = acc[i][jj + 3] + (cvec ? cvec[n + 3] : 0.f);
      *(float4*)(crow + jj) = o;
    }
  }
}

// ---------------------------------------------------------------------------
// CSR build
// ---------------------------------------------------------------------------
__global__ __launch_bounds__(256) void k_zero(int* __restrict__ p, int n) {
  int i = blockIdx.x * 256 + threadIdx.x;
  if (i < n) p[i] = 0;
}
__global__ __launch_bounds__(256) void k_count(
    const int* __restrict__ dst, int* __restrict__ counts, int E) {
  int e = blockIdx.x * 256 + threadIdx.x;
  if (e < E) atomicAdd(&counts[dst[e]], 1);
}
__global__ __launch_bounds__(1024) void k_scan(
    const int* __restrict__ counts, int* __restrict__ offs,
    int* __restrict__ cursor, int N)
{
  __shared__ int sh[1024];
  const int t = threadIdx.x;
  int running = 0;
  for (int base = 0; base < N; base += 1024) {
    int v = (base + t < N) ? counts[base + t] : 0;
    __syncthreads();
    sh[t] = v; __syncthreads();
    for (int s = 1; s < 1024; s <<= 1) {
      int add = (t >= s) ? sh[t - s] : 0;
      __syncthreads();
      sh[t] += add;
      __syncthreads();
    }
    int incl = sh[t];
    if (base + t < N) {
      offs[base + t + 1] = running + incl;
      cursor[base + t] = running + incl - v;
    }
    int tot = sh[1023];
    running += tot;
  }
  if (t == 0) offs[0] = 0;
}
__global__ __launch_bounds__(256) void k_fill(
    const int* __restrict__ src, const int* __restrict__ dst,
    int* __restrict__ cursor, int* __restrict__ csr_src, int E) {
  int e = blockIdx.x * 256 + threadIdx.x;
  if (e < E) {
    int slot = atomicAdd(&cursor[dst[e]], 1);
    csr_src[slot] = src[e];
  }
}

// ---------------------------------------------------------------------------
// TransformerConv aggregation, ONLINE softmax (single pass over edges).
// One wave per node. C1 row: [q(512) | k(512) | v(512) | skip(128)]
// Lane l holds channels (l*8..l*8+7) of head (l>>4).
// ---------------------------------------------------------------------------
__global__ __launch_bounds__(256) void k_tconv(
    const float* __restrict__ C1, const int* __restrict__ offs,
    const int* __restrict__ csr_src, float* __restrict__ x1, int N)
{
  const int wid = threadIdx.x >> 6;
  const int lane = threadIdx.x & 63;
  const int node = blockIdx.x * 4 + wid;
  if (node >= N) return;
  const float* crow = C1 + (size_t)node * QKV_N;
  float q[8];
  {
    float4 q0 = *(const float4*)(crow + lane * 8);
    float4 q1 = *(const float4*)(crow + lane * 8 + 4);
    q[0]=q0.x; q[1]=q0.y; q[2]=q0.z; q[3]=q0.w;
    q[4]=q1.x; q[5]=q1.y; q[6]=q1.z; q[7]=q1.w;
  }
  const int beg = offs[node], end = offs[node + 1];
  float mx = -1e30f;
  float ssum = 0.f;
  float acc[8] = {0.f,0.f,0.f,0.f,0.f,0.f,0.f,0.f};

  int e = beg;
  for (; e + 2 <= end; e += 2) {
    int s0 = csr_src[e];
    int s1 = csr_src[e + 1];
    const float* r0 = C1 + (size_t)s0 * QKV_N + 512 + lane * 8;
    const float* r1 = C1 + (size_t)s1 * QKV_N + 512 + lane * 8;
    float4 ka0 = *(const float4*)(r0);
    float4 ka1 = *(const float4*)(r0 + 4);
    float4 kb0 = *(const float4*)(r1);
    float4 kb1 = *(const float4*)(r1 + 4);
    float4 va0 = *(const float4*)(r0 + 512);
    float4 va1 = *(const float4*)(r0 + 516);
    float4 vb0 = *(const float4*)(r1 + 512);
    float4 vb1 = *(const float4*)(r1 + 516);
    float p0 = q[0]*ka0.x + q[1]*ka0.y + q[2]*ka0.z + q[3]*ka0.w
             + q[4]*ka1.x + q[5]*ka1.y + q[6]*ka1.z + q[7]*ka1.w;
    float p1 = q[0]*kb0.x + q[1]*kb0.y + q[2]*kb0.z + q[3]*kb0.w
             + q[4]*kb1.x + q[5]*kb1.y + q[6]*kb1.z + q[7]*kb1.w;
    p0 = grp16_sum(p0) * SQRT_H_INV;
    p1 = grp16_sum(p1) * SQRT_H_INV;
    float nm = fmaxf(mx, fmaxf(p0, p1));
    float sc = expf(mx - nm);      // exp(-inf)=0 handles first iteration
    float w0 = expf(p0 - nm);
    float w1 = expf(p1 - nm);
    ssum = ssum * sc + w0 + w1;
    acc[0] = acc[0]*sc + w0*va0.x + w1*vb0.x;
    acc[1] = acc[1]*sc + w0*va0.y + w1*vb0.y;
    acc[2] = acc[2]*sc + w0*va0.z + w1*vb0.z;
    acc[3] = acc[3]*sc + w0*va0.w + w1*vb0.w;
    acc[4] = acc[4]*sc + w0*va1.x + w1*vb1.x;
    acc[5] = acc[5]*sc + w0*va1.y + w1*vb1.y;
    acc[6] = acc[6]*sc + w0*va1.z + w1*vb1.z;
    acc[7] = acc[7]*sc + w0*va1.w + w1*vb1.w;
    mx = nm;
  }
  if (e < end) {
    int s0 = csr_src[e];
    const float* r0 = C1 + (size_t)s0 * QKV_N + 512 + lane * 8;
    float4 ka0 = *(const float4*)(r0);
    float4 ka1 = *(const float4*)(r0 + 4);
    float4 va0 = *(const float4*)(r0 + 512);
    float4 va1 = *(const float4*)(r0 + 516);
    float p0 = q[0]*ka0.x + q[1]*ka0.y + q[2]*ka0.z + q[3]*ka0.w
             + q[4]*ka1.x + q[5]*ka1.y + q[6]*ka1.z + q[7]*ka1.w;
    p0 = grp16_sum(p0) * SQRT_H_INV;
    float nm = fmaxf(mx, p0);
    float sc = expf(mx - nm);
    float w0 = expf(p0 - nm);
    ssum = ssum * sc + w0;
    acc[0] = acc[0]*sc + w0*va0.x;
    acc[1] = acc[1]*sc + w0*va0.y;
    acc[2] = acc[2]*sc + w0*va0.z;
    acc[3] = acc[3]*sc + w0*va0.w;
    acc[4] = acc[4]*sc + w0*va1.x;
    acc[5] = acc[5]*sc + w0*va1.y;
    acc[6] = acc[6]*sc + w0*va1.z;
    acc[7] = acc[7]*sc + w0*va1.w;
  }

  float inv = 1.f / (ssum + 1e-16f);
#pragma unroll
  for (int j = 0; j < 8; ++j) acc[j] *= inv;
#pragma unroll
  for (int j = 0; j < 8; ++j) {
    acc[j] += __shfl_xor(acc[j], 16);
    acc[j] += __shfl_xor(acc[j], 32);
  }
  if (lane < 16) {
    const float* sk = crow + 1536 + lane * 8;
    float* xo = x1 + (size_t)node * 128 + lane * 8;
#pragma unroll
    for (int j = 0; j < 8; ++j) xo[j] = 0.25f * acc[j] + sk[j];
  }
}

// ---------------------------------------------------------------------------
// GAT attention coefficients: a_s[n,h] = sum_c xh[n,h,c]*as[h,c]; same for a_d
// ---------------------------------------------------------------------------
__global__ __launch_bounds__(256) void k_gat_ad(
    const float* __restrict__ xh, const float* __restrict__ as_w,
    const float* __restrict__ ad_w, float* __restrict__ a_s,
    float* __restrict__ a_d, int N)
{
  const int wid = threadIdx.x >> 6;
  const int lane = threadIdx.x & 63;
  const int node = blockIdx.x * 4 + wid;
  if (node >= N) return;
  const int head = lane >> 4;
  const int c0 = (lane & 15) * 8;
  const float* xr = xh + (size_t)node * 512 + lane * 8;
  float4 x0 = *(const float4*)(xr);
  float4 x1_ = *(const float4*)(xr + 4);
  const float* aw = as_w + head * 128 + c0;
  const float* dw = ad_w + head * 128 + c0;
  float s1 = x0.x*aw[0] + x0.y*aw[1] + x0.z*aw[2] + x0.w*aw[3]
           + x1_.x*aw[4] + x1_.y*aw[5] + x1_.z*aw[6] + x1_.w*aw[7];
  float s2 = x0.x*dw[0] + x0.y*dw[1] + x0.z*dw[2] + x0.w*dw[3]
           + x1_.x*dw[4] + x1_.y*dw[5] + x1_.z*dw[6] + x1_.w*dw[7];
  s1 = grp16_sum(s1);
  s2 = grp16_sum(s2);
  if ((lane & 15) == 0) {
    a_s[node * 4 + head] = s1;
    a_d[node * 4 + head] = s2;
  }
}

// ---------------------------------------------------------------------------
// GAT aggregation (incl. implicit self loop), ONLINE softmax single pass.
// ---------------------------------------------------------------------------
__global__ __launch_bounds__(256) void k_gat_agg(
    const float* __restrict__ xh, const float* __restrict__ a_s,
    const float* __restrict__ a_d, const int* __restrict__ offs,
    const int* __restrict__ csr_src, const float* __restrict__ bias,
    float* __restrict__ xout, int N)
{
  const int wid = threadIdx.x >> 6;
  const int lane = threadIdx.x & 63;
  const int node = blockIdx.x * 4 + wid;
  if (node >= N) return;
  const int head = lane >> 4;
  const float adn = a_d[node * 4 + head];
  const float asn = a_s[node * 4 + head];
  float lself = asn + adn;
  lself = lself >= 0.f ? lself : 0.2f * lself;

  // init with self loop (w = exp(0) = 1 at mx = lself)
  float mx = lself;
  float ssum = 1.f;
  float acc[8];
  {
    const float* xr = xh + (size_t)node * 512 + lane * 8;
    float4 x0 = *(const float4*)(xr);
    float4 x1_ = *(const float4*)(xr + 4);
    acc[0]=x0.x; acc[1]=x0.y; acc[2]=x0.z; acc[3]=x0.w;
    acc[4]=x1_.x; acc[5]=x1_.y; acc[6]=x1_.z; acc[7]=x1_.w;
  }

  const int beg = offs[node], end = offs[node + 1];
  int e = beg;
  for (; e + 2 <= end; e += 2) {
    int s0 = csr_src[e];
    int s1 = csr_src[e + 1];
    float l0 = a_s[s0 * 4 + head] + adn;
    float l1 = a_s[s1 * 4 + head] + adn;
    l0 = l0 >= 0.f ? l0 : 0.2f * l0;
    l1 = l1 >= 0.f ? l1 : 0.2f * l1;
    const float* r0 = xh + (size_t)s0 * 512 + lane * 8;
    const float* r1 = xh + (size_t)s1 * 512 + lane * 8;
    float4 xa0 = *(const float4*)(r0);
    float4 xa1 = *(const float4*)(r0 + 4);
    float4 xb0 = *(const float4*)(r1);
    float4 xb1 = *(const float4*)(r1 + 4);
    float nm = fmaxf(mx, fmaxf(l0, l1));
    float sc = expf(mx - nm);
    float w0 = expf(l0 - nm);
    float w1 = expf(l1 - nm);
    ssum = ssum * sc + w0 + w1;
    acc[0] = acc[0]*sc + w0*xa0.x + w1*xb0.x;
    acc[1] = acc[1]*sc + w0*xa0.y + w1*xb0.y;
    acc[2] = acc[2]*sc + w0*xa0.z + w1*xb0.z;
    acc[3] = acc[3]*sc + w0*xa0.w + w1*xb0.w;
    acc[4] = acc[4]*sc + w0*xa1.x + w1*xb1.x;
    acc[5] = acc[5]*sc + w0*xa1.y + w1*xb1.y;
    acc[6] = acc[6]*sc + w0*xa1.z + w1*xb1.z;
    acc[7] = acc[7]*sc + w0*xa1.w + w1*xb1.w;
    mx = nm;
  }
  if (e < end) {
    int s0 = csr_src[e];
    float l0 = a_s[s0 * 4 + head] + adn;
    l0 = l0 >= 0.f ? l0 : 0.2f * l0;
    const float* r0 = xh + (size_t)s0 * 512 + lane * 8;
    float4 xa0 = *(const float4*)(r0);
    float4 xa1 = *(const float4*)(r0 + 4);
    float nm = fmaxf(mx, l0);
    float sc = expf(mx - nm);
    float w0 = expf(l0 - nm);
    ssum = ssum * sc + w0;
    acc[0] = acc[0]*sc + w0*xa0.x;
    acc[1] = acc[1]*sc + w0*xa0.y;
    acc[2] = acc[2]*sc + w0*xa0.z;
    acc[3] = acc[3]*sc + w0*xa0.w;
    acc[4] = acc[4]*sc + w0*xa1.x;
    acc[5] = acc[5]*sc + w0*xa1.y;
    acc[6] = acc[6]*sc + w0*xa1.z;
    acc[7] = acc[7]*sc + w0*xa1.w;
  }

  float inv = 1.f / (ssum + 1e-16f);
#pragma unroll
  for (int j = 0; j < 8; ++j) acc[j] *= inv;
#pragma unroll
  for (int j = 0; j < 8; ++j) {
    acc[j] += __shfl_xor(acc[j], 16);
    acc[j] += __shfl_xor(acc[j], 32);
  }
  if (lane < 16) {
    const float* b = bias + lane * 8;
    float* xo = xout + (size_t)node * 128 + lane * 8;
#pragma unroll
    for (int j = 0; j < 8; ++j) xo[j] = fmaxf(0.25f * acc[j] + b[j], 0.f);
  }
}

// ---------------------------------------------------------------------------
// LSTM elementwise epilogue (h0=c0=0; gate order i,f,g,o; gf unused)
// ---------------------------------------------------------------------------
__global__ __launch_bounds__(256) void k_lstm(
    const float* __restrict__ gates, float* __restrict__ out, int N)
{
  int idx = blockIdx.x * 256 + threadIdx.x;
  if (idx >= N * 128) return;
  int n = idx >> 7, c = idx & 127;
  const float* g = gates + (size_t)n * 512;
  float gi = g[c], gg = g[256 + c], go = g[384 + c];
  float cv = (1.f / (1.f + expf(-gi))) * tanhf(gg);
  float hv = (1.f / (1.f + expf(-go))) * tanhf(cv);
  out[idx] = hv;
  out[(size_t)N * 128 + idx] = cv;
}

// ---------------------------------------------------------------------------
extern "C" void kernel_launch(void* const* d_in, const int* in_sizes, int n_in,
                              void* d_out, int out_size, void* d_ws, size_t ws_size,
                              hipStream_t stream) {
  const int*   node_ids = (const int*)d_in[0];
  const int*   etid     = (const int*)d_in[1];
  const int*   src      = (const int*)d_in[2];
  const int*   dst      = (const int*)d_in[3];
  const float* ef       = (const float*)d_in[4];
  const float* inten    = (const float*)d_in[5];
  const float* nemb     = (const float*)d_in[6];
  const float* ett      = (const float*)d_in[7];
  const float* ev_w1 = (const float*)d_in[8],  *ev_b1 = (const float*)d_in[9];
  const float* ev_g1 = (const float*)d_in[10], *ev_bt1 = (const float*)d_in[11];
  const float* ev_w2 = (const float*)d_in[12], *ev_b2 = (const float*)d_in[13];
  const float* ev_g2 = (const float*)d_in[14], *ev_bt2 = (const float*)d_in[15];
  const float* wq = (const float*)d_in[16], *bq = (const float*)d_in[17];
  const float* wk = (const float*)d_in[18], *bk = (const float*)d_in[19];
  const float* wv = (const float*)d_in[20], *bv = (const float*)d_in[21];
  const float* wskip = (const float*)d_in[22], *bskip = (const float*)d_in[23];
  const float* g0_w = (const float*)d_in[24], *g0_as = (const float*)d_in[25];
  const float* g0_ad = (const float*)d_in[26], *g0_b = (const float*)d_in[27];
  const float* g1_w = (const float*)d_in[28], *g1_as = (const float*)d_in[29];
  const float* g1_ad = (const float*)d_in[30], *g1_b = (const float*)d_in[31];
  const float* wih = (const float*)d_in[32];
  const float* bih = (const float*)d_in[34], *bhh = (const float*)d_in[35];

  const int N = in_sizes[0];
  const int K = in_sizes[1];
  const int E = in_sizes[2];
  const int EV = in_sizes[4];

  float* ws = (float*)d_ws;
  size_t o = 0;
  float* e_vec = ws + o; o += 128;
  float* cvec1 = ws + o; o += QKV_N;
  float* cvec2 = ws + o; o += 512;
  float* B1    = ws + o; o += (size_t)128 * QKV_N;
  float* C1    = ws + o; o += (size_t)N * QKV_N;
  float* x_a   = ws + o; o += (size_t)N * 128;
  float* x_b   = ws + o; o += (size_t)N * 128;
  float* xh    = ws + o; o += (size_t)N * 512;
  float* a_s   = ws + o; o += (size_t)N * 4;
  float* a_d   = ws + o; o += (size_t)N * 4;
  int* counts  = (int*)(ws + o); o += N;
  int* offs    = (int*)(ws + o); o += (size_t)N + 1;
  int* cursor  = (int*)(ws + o); o += N;
  int* csr_src = (int*)(ws + o); o += E;

  float* out = (float*)d_out;

  const int nodeBlocks = (N + 3) / 4;
  const int gridMy = (N + 127) / 128;

  // --- tiny setup kernels ---
  k_event<<<1, 128, 0, stream>>>(ef, EV, ev_w1, ev_b1, ev_g1, ev_bt1,
                                 ev_w2, ev_b2, ev_g2, ev_bt2,
                                 ett, etid, inten, K, e_vec);
  k_cvec<<<(QKV_N + 255) / 256, 256, 0, stream>>>(e_vec, wq, bq, wk, bk, wv, bv,
                                                  wskip, bskip, cvec1);
  k_pack<<<(D_DIM * QKV_N + 255) / 256, 256, 0, stream>>>(wq, wk, wv, wskip, B1);
  k_cvec2<<<2, 256, 0, stream>>>(bih, bhh, cvec2);

  // --- CSR build ---
  k_zero<<<(N + 255) / 256, 256, 0, stream>>>(counts, N);
  k_count<<<(E + 255) / 256, 256, 0, stream>>>(dst, counts, E);
  k_scan<<<1, 1024, 0, stream>>>(counts, offs, cursor, N);
  k_fill<<<(E + 255) / 256, 256, 0, stream>>>(src, dst, cursor, csr_src, E);

  // --- QKV + skip fused GEMM: C1[N,1664] ---
  sgemm_k128<<<dim3(QKV_N / 128, gridMy), 256, 0, stream>>>(
      nemb, node_ids, B1, cvec1, C1, N, QKV_N);

  // --- TransformerConv aggregation -> x_a[N,128] ---
  k_tconv<<<nodeBlocks, 256, 0, stream>>>(C1, offs, csr_src, x_a, N);

  // --- GAT layer 1 ---
  sgemm_k128<<<dim3(512 / 128, gridMy), 256, 0, stream>>>(
      x_a, nullptr, g0_w, nullptr, xh, N, 512);
  k_gat_ad<<<nodeBlocks, 256, 0, stream>>>(xh, g0_as, g0_ad, a_s, a_d, N);
  k_gat_agg<<<nodeBlocks, 256, 0, stream>>>(xh, a_s, a_d, offs, csr_src, g0_b, x_b, N);

  // --- GAT layer 2 ---
  sgemm_k128<<<dim3(512 / 128, gridMy), 256, 0, stream>>>(
      x_b, nullptr, g1_w, nullptr, xh, N, 512);
  k_gat_ad<<<nodeBlocks, 256, 0, stream>>>(xh, g1_as, g1_ad, a_s, a_d, N);
  k_gat_agg<<<nodeBlocks, 256, 0, stream>>>(xh, a_s, a_d, offs, csr_src, g1_b, x_a, N);

  // --- LSTM ---
  sgemm_k128<<<dim3(512 / 128, gridMy), 256, 0, stream>>>(
      x_a, nullptr, wih, cvec2, xh, N, 512);
  k_lstm<<<((N * 128) + 255) / 256, 256, 0, stream>>>(xh, out, N);
}

// Round 3
// 732.171 us; speedup vs baseline: 1.1554x; 1.0428x over previous
//
#include <hip/hip_runtime.h>
#include <math.h>

// Problem constants (fixed by the reference)
#define D_DIM 128
#define H_DIM 128
#define NHEAD 4
#define QKV_N 1664   // 3*NH*H + H (q|k|v|skip packed columns)
#define SQRT_H_INV 0.08838834764831845f  // 1/sqrt(128)

__device__ __forceinline__ float grp16_sum(float v) {
  v += __shfl_xor(v, 1);
  v += __shfl_xor(v, 2);
  v += __shfl_xor(v, 4);
  v += __shfl_xor(v, 8);
  return v;
}

// ---------------------------------------------------------------------------
// K0: event encoder MLP (single block, 128 threads) -> e[128]
// ---------------------------------------------------------------------------
__global__ __launch_bounds__(128) void k_event(
    const float* __restrict__ ef, int EV,
    const float* __restrict__ w1, const float* __restrict__ b1,
    const float* __restrict__ g1, const float* __restrict__ bt1,
    const float* __restrict__ w2, const float* __restrict__ b2,
    const float* __restrict__ g2, const float* __restrict__ bt2,
    const float* __restrict__ ett, const int* __restrict__ etid,
    const float* __restrict__ inten, int K,
    float* __restrict__ e_out)
{
  __shared__ float sh[H_DIM];
  __shared__ float red[H_DIM];
  const int t = threadIdx.x;

  float acc = b1[t];
  for (int i = 0; i < EV; ++i) acc += ef[i] * w1[i * H_DIM + t];

  // LayerNorm 1
  red[t] = acc; __syncthreads();
  for (int s = 64; s > 0; s >>= 1) { if (t < s) red[t] += red[t + s]; __syncthreads(); }
  float mu = red[0] / H_DIM; __syncthreads();
  float d = acc - mu;
  red[t] = d * d; __syncthreads();
  for (int s = 64; s > 0; s >>= 1) { if (t < s) red[t] += red[t + s]; __syncthreads(); }
  float var = red[0] / H_DIM; __syncthreads();
  float y = d * rsqrtf(var + 1e-5f) * g1[t] + bt1[t];
  y = fmaxf(y, 0.f);
  sh[t] = y; __syncthreads();

  float acc2 = b2[t];
  for (int i = 0; i < H_DIM; ++i) acc2 += sh[i] * w2[i * H_DIM + t];

  // LayerNorm 2
  red[t] = acc2; __syncthreads();
  for (int s = 64; s > 0; s >>= 1) { if (t < s) red[t] += red[t + s]; __syncthreads(); }
  mu = red[0] / H_DIM; __syncthreads();
  d = acc2 - mu;
  red[t] = d * d; __syncthreads();
  for (int s = 64; s > 0; s >>= 1) { if (t < s) red[t] += red[t + s]; __syncthreads(); }
  var = red[0] / H_DIM; __syncthreads();
  float y2 = d * rsqrtf(var + 1e-5f) * g2[t] + bt2[t];
  y2 = fmaxf(y2, 0.f);

  // + mean_k ett[etid[k]] * inten[k]
  float m = 0.f;
  for (int k = 0; k < K; ++k) m += ett[etid[k] * H_DIM + t] * inten[k];
  e_out[t] = y2 + m / (float)K;
}

// ---------------------------------------------------------------------------
// K1: constant column vector  cvec[j] = e @ W[128:256, j] + b[j]  (q|k|v|skip)
// ---------------------------------------------------------------------------
__global__ __launch_bounds__(256) void k_cvec(
    const float* __restrict__ e,
    const float* __restrict__ wq, const float* __restrict__ bq,
    const float* __restrict__ wk, const float* __restrict__ bk,
    const float* __restrict__ wv, const float* __restrict__ bv,
    const float* __restrict__ wskip, const float* __restrict__ bskip,
    float* __restrict__ cvec)
{
  __shared__ float es[H_DIM];
  const int t = threadIdx.x;
  if (t < H_DIM) es[t] = e[t];
  __syncthreads();
  int j = blockIdx.x * 256 + t;
  if (j >= QKV_N) return;
  const float* W; const float* b; int col; int stride;
  if (j < 512)       { W = wq;    b = bq;    col = j;        stride = 512; }
  else if (j < 1024) { W = wk;    b = bk;    col = j - 512;  stride = 512; }
  else if (j < 1536) { W = wv;    b = bv;    col = j - 1024; stride = 512; }
  else               { W = wskip; b = bskip; col = j - 1536; stride = 128; }
  float a = b[col];
  for (int i = 0; i < H_DIM; ++i) a += es[i] * W[(D_DIM + i) * stride + col];
  cvec[j] = a;
}

// K1b: pack B1[128][1664] = rows 0..127 of [wq | wk | wv | wskip]
__global__ __launch_bounds__(256) void k_pack(
    const float* __restrict__ wq, const float* __restrict__ wk,
    const float* __restrict__ wv, const float* __restrict__ wskip,
    float* __restrict__ B1)
{
  int idx = blockIdx.x * 256 + threadIdx.x;
  if (idx >= D_DIM * QKV_N) return;
  int i = idx / QKV_N, j = idx - i * QKV_N;
  float v;
  if (j < 512)       v = wq[i * 512 + j];
  else if (j < 1024) v = wk[i * 512 + (j - 512)];
  else if (j < 1536) v = wv[i * 512 + (j - 1024)];
  else               v = wskip[i * 128 + (j - 1536)];
  B1[idx] = v;
}

// K1c: LSTM constant bias = bih + bhh
__global__ __launch_bounds__(256) void k_cvec2(
    const float* __restrict__ bih, const float* __restrict__ bhh,
    float* __restrict__ cvec2)
{
  int j = blockIdx.x * 256 + threadIdx.x;
  if (j < 512) cvec2[j] = bih[j] + bhh[j];
}

// ---------------------------------------------------------------------------
// SGEMM, K fixed = 128.  C[M,Nn] = A[M,128] @ B[128,Nn] (+cvec[Nn])
// Optional row gather via ids. BM=BN=128, BK=32, 256 thr.
// Per-thread 2x2 blocks of 4x4 (fragments at tx*4 / tx*4+64 -> 2-way banks).
// Register-prefetch of next k-tile overlaps global loads with FMA loop.
// ---------------------------------------------------------------------------
__global__ __launch_bounds__(256, 4) void sgemm_k128(
    const float* __restrict__ A, const int* __restrict__ ids,
    const float* __restrict__ B, const float* __restrict__ cvec,
    float* __restrict__ C, int M, int Nn)
{
  __shared__ float As[32][132];  // [k][m] transposed, padded (132*4B = 33*16B aligned)
  __shared__ float Bs[32][132];  // [k][n] padded
  const int t = threadIdx.x;
  const int tx = t & 15;
  const int ty = t >> 4;
  const int bm = blockIdx.y * 128;
  const int bn = blockIdx.x * 128;

  // Load mappings (constant across k-tiles)
  int am[4], akc[4], ar[4];
  bool aok[4];
  int bkr[4], bnc[4];
#pragma unroll
  for (int i = 0; i < 4; ++i) {
    int f = t + i * 256;          // 0..1023
    am[i]  = f >> 3;              // 128 rows
    akc[i] = (f & 7) << 2;        // 0..28
    int row = bm + am[i];
    aok[i] = row < M;
    ar[i]  = aok[i] ? (ids ? ids[row] : row) : 0;
    bkr[i] = f >> 5;              // 32 rows
    bnc[i] = (f & 31) << 2;       // 0..124
  }

  float4 pa[4], pb[4];
#pragma unroll
  for (int i = 0; i < 4; ++i) {
    pa[i] = aok[i] ? *(const float4*)(A + (size_t)ar[i] * 128 + akc[i])
                   : make_float4(0.f, 0.f, 0.f, 0.f);
    pb[i] = *(const float4*)(B + (size_t)bkr[i] * Nn + bn + bnc[i]);
  }

  float acc[2][2][4][4];
#pragma unroll
  for (int p = 0; p < 2; ++p)
#pragma unroll
    for (int q = 0; q < 2; ++q)
#pragma unroll
      for (int i = 0; i < 4; ++i)
#pragma unroll
        for (int j = 0; j < 4; ++j) acc[p][q][i][j] = 0.f;

  for (int kt = 0; kt < 4; ++kt) {
#pragma unroll
    for (int i = 0; i < 4; ++i) {
      As[akc[i] + 0][am[i]] = pa[i].x;
      As[akc[i] + 1][am[i]] = pa[i].y;
      As[akc[i] + 2][am[i]] = pa[i].z;
      As[akc[i] + 3][am[i]] = pa[i].w;
      *(float4*)&Bs[bkr[i]][bnc[i]] = pb[i];
    }
    __syncthreads();
    if (kt < 3) {
      const int k0 = (kt + 1) * 32;
#pragma unroll
      for (int i = 0; i < 4; ++i) {
        pa[i] = aok[i] ? *(const float4*)(A + (size_t)ar[i] * 128 + k0 + akc[i])
                       : make_float4(0.f, 0.f, 0.f, 0.f);
        pb[i] = *(const float4*)(B + (size_t)(k0 + bkr[i]) * Nn + bn + bnc[i]);
      }
    }
#pragma unroll 8
    for (int k = 0; k < 32; ++k) {
      float4 a0 = *(const float4*)&As[k][ty * 4];
      float4 a1 = *(const float4*)&As[k][ty * 4 + 64];
      float4 b0 = *(const float4*)&Bs[k][tx * 4];
      float4 b1 = *(const float4*)&Bs[k][tx * 4 + 64];
      float av[2][4] = {{a0.x, a0.y, a0.z, a0.w}, {a1.x, a1.y, a1.z, a1.w}};
      float bv[2][4] = {{b0.x, b0.y, b0.z, b0.w}, {b1.x, b1.y, b1.z, b1.w}};
#pragma unroll
      for (int p = 0; p < 2; ++p)
#pragma unroll
        for (int i = 0; i < 4; ++i)
#pragma unroll
          for (int q = 0; q < 2; ++q)
#pragma unroll
            for (int j = 0; j < 4; ++j)
              acc[p][q][i][j] = fmaf(av[p][i], bv[q][j], acc[p][q][i][j]);
    }
    __syncthreads();
  }

#pragma unroll
  for (int p = 0; p < 2; ++p) {
#pragma unroll
    for (int i = 0; i < 4; ++i) {
      int m = bm + p * 64 + ty * 4 + i;
      if (m >= M) continue;
      float* crow = C + (size_t)m * Nn;
#pragma unroll
      for (int q = 0; q < 2; ++q) {
        int n = bn + q * 64 + tx * 4;
        float4 o;
        o.x = acc[p][q][i][0] + (cvec ? cvec[n + 0] : 0.f);
        o.y = acc[p][q][i][1] + (cvec ? cvec[n + 1] : 0.f);
        o.z = acc[p][q][i][2] + (cvec ? cvec[n + 2] : 0.f);
        o.w = acc[p][q][i][3] + (cvec ? cvec[n + 3] : 0.f);
        *(float4*)(crow + n) = o;
      }
    }
  }
}

// ---------------------------------------------------------------------------
// CSR build
// ---------------------------------------------------------------------------
__global__ __launch_bounds__(256) void k_zero(int* __restrict__ p, int n) {
  int i = blockIdx.x * 256 + threadIdx.x;
  if (i < n) p[i] = 0;
}
__global__ __launch_bounds__(256) void k_count(
    const int* __restrict__ dst, int* __restrict__ counts, int E) {
  int e = blockIdx.x * 256 + threadIdx.x;
  if (e < E) atomicAdd(&counts[dst[e]], 1);
}
// Single-block scan, shfl-based (3 barriers per 1024-chunk)
__global__ __launch_bounds__(1024) void k_scan(
    const int* __restrict__ counts, int* __restrict__ offs,
    int* __restrict__ cursor, int N)
{
  __shared__ int wsum[16];
  const int t = threadIdx.x;
  const int lane = t & 63;
  const int wid = t >> 6;
  int running = 0;
  for (int base = 0; base < N; base += 1024) {
    int v = (base + t < N) ? counts[base + t] : 0;
    int incl = v;
#pragma unroll
    for (int s = 1; s < 64; s <<= 1) {
      int u = __shfl_up(incl, s);
      if (lane >= s) incl += u;
    }
    if (lane == 63) wsum[wid] = incl;
    __syncthreads();
    if (wid == 0) {
      int w = (lane < 16) ? wsum[lane] : 0;
#pragma unroll
      for (int s = 1; s < 16; s <<= 1) {
        int u = __shfl_up(w, s);
        if (lane >= s) w += u;
      }
      if (lane < 16) wsum[lane] = w;
    }
    __syncthreads();
    int wpre = (wid > 0) ? wsum[wid - 1] : 0;
    int tot = wsum[15];
    int inclg = incl + wpre;
    if (base + t < N) {
      offs[base + t + 1] = running + inclg;
      cursor[base + t] = running + inclg - v;
    }
    running += tot;
    __syncthreads();
  }
  if (t == 0) offs[0] = 0;
}
__global__ __launch_bounds__(256) void k_fill(
    const int* __restrict__ src, const int* __restrict__ dst,
    int* __restrict__ cursor, int* __restrict__ csr_src, int E) {
  int e = blockIdx.x * 256 + threadIdx.x;
  if (e < E) {
    int slot = atomicAdd(&cursor[dst[e]], 1);
    csr_src[slot] = src[e];
  }
}

// ---------------------------------------------------------------------------
// TransformerConv aggregation, ONLINE softmax (single pass over edges).
// One wave per node. C1 row: [q(512) | k(512) | v(512) | skip(128)]
// Lane l holds channels (l*8..l*8+7) of head (l>>4).
// ---------------------------------------------------------------------------
__global__ __launch_bounds__(256) void k_tconv(
    const float* __restrict__ C1, const int* __restrict__ offs,
    const int* __restrict__ csr_src, float* __restrict__ x1, int N)
{
  const int wid = threadIdx.x >> 6;
  const int lane = threadIdx.x & 63;
  const int node = blockIdx.x * 4 + wid;
  if (node >= N) return;
  const float* crow = C1 + (size_t)node * QKV_N;
  float q[8];
  {
    float4 q0 = *(const float4*)(crow + lane * 8);
    float4 q1 = *(const float4*)(crow + lane * 8 + 4);
    q[0]=q0.x; q[1]=q0.y; q[2]=q0.z; q[3]=q0.w;
    q[4]=q1.x; q[5]=q1.y; q[6]=q1.z; q[7]=q1.w;
  }
  const int beg = offs[node], end = offs[node + 1];
  float mx = -1e30f;
  float ssum = 0.f;
  float acc[8] = {0.f,0.f,0.f,0.f,0.f,0.f,0.f,0.f};

  int e = beg;
  for (; e + 2 <= end; e += 2) {
    int s0 = csr_src[e];
    int s1 = csr_src[e + 1];
    const float* r0 = C1 + (size_t)s0 * QKV_N + 512 + lane * 8;
    const float* r1 = C1 + (size_t)s1 * QKV_N + 512 + lane * 8;
    float4 ka0 = *(const float4*)(r0);
    float4 ka1 = *(const float4*)(r0 + 4);
    float4 kb0 = *(const float4*)(r1);
    float4 kb1 = *(const float4*)(r1 + 4);
    float4 va0 = *(const float4*)(r0 + 512);
    float4 va1 = *(const float4*)(r0 + 516);
    float4 vb0 = *(const float4*)(r1 + 512);
    float4 vb1 = *(const float4*)(r1 + 516);
    float p0 = q[0]*ka0.x + q[1]*ka0.y + q[2]*ka0.z + q[3]*ka0.w
             + q[4]*ka1.x + q[5]*ka1.y + q[6]*ka1.z + q[7]*ka1.w;
    float p1 = q[0]*kb0.x + q[1]*kb0.y + q[2]*kb0.z + q[3]*kb0.w
             + q[4]*kb1.x + q[5]*kb1.y + q[6]*kb1.z + q[7]*kb1.w;
    p0 = grp16_sum(p0) * SQRT_H_INV;
    p1 = grp16_sum(p1) * SQRT_H_INV;
    float nm = fmaxf(mx, fmaxf(p0, p1));
    float sc = expf(mx - nm);      // exp(-inf)=0 handles first iteration
    float w0 = expf(p0 - nm);
    float w1 = expf(p1 - nm);
    ssum = ssum * sc + w0 + w1;
    acc[0] = acc[0]*sc + w0*va0.x + w1*vb0.x;
    acc[1] = acc[1]*sc + w0*va0.y + w1*vb0.y;
    acc[2] = acc[2]*sc + w0*va0.z + w1*vb0.z;
    acc[3] = acc[3]*sc + w0*va0.w + w1*vb0.w;
    acc[4] = acc[4]*sc + w0*va1.x + w1*vb1.x;
    acc[5] = acc[5]*sc + w0*va1.y + w1*vb1.y;
    acc[6] = acc[6]*sc + w0*va1.z + w1*vb1.z;
    acc[7] = acc[7]*sc + w0*va1.w + w1*vb1.w;
    mx = nm;
  }
  if (e < end) {
    int s0 = csr_src[e];
    const float* r0 = C1 + (size_t)s0 * QKV_N + 512 + lane * 8;
    float4 ka0 = *(const float4*)(r0);
    float4 ka1 = *(const float4*)(r0 + 4);
    float4 va0 = *(const float4*)(r0 + 512);
    float4 va1 = *(const float4*)(r0 + 516);
    float p0 = q[0]*ka0.x + q[1]*ka0.y + q[2]*ka0.z + q[3]*ka0.w
             + q[4]*ka1.x + q[5]*ka1.y + q[6]*ka1.z + q[7]*ka1.w;
    p0 = grp16_sum(p0) * SQRT_H_INV;
    float nm = fmaxf(mx, p0);
    float sc = expf(mx - nm);
    float w0 = expf(p0 - nm);
    ssum = ssum * sc + w0;
    acc[0] = acc[0]*sc + w0*va0.x;
    acc[1] = acc[1]*sc + w0*va0.y;
    acc[2] = acc[2]*sc + w0*va0.z;
    acc[3] = acc[3]*sc + w0*va0.w;
    acc[4] = acc[4]*sc + w0*va1.x;
    acc[5] = acc[5]*sc + w0*va1.y;
    acc[6] = acc[6]*sc + w0*va1.z;
    acc[7] = acc[7]*sc + w0*va1.w;
  }

  float inv = 1.f / (ssum + 1e-16f);
#pragma unroll
  for (int j = 0; j < 8; ++j) acc[j] *= inv;
#pragma unroll
  for (int j = 0; j < 8; ++j) {
    acc[j] += __shfl_xor(acc[j], 16);
    acc[j] += __shfl_xor(acc[j], 32);
  }
  if (lane < 16) {
    const float* sk = crow + 1536 + lane * 8;
    float* xo = x1 + (size_t)node * 128 + lane * 8;
#pragma unroll
    for (int j = 0; j < 8; ++j) xo[j] = 0.25f * acc[j] + sk[j];
  }
}

// ---------------------------------------------------------------------------
// GAT attention coefficients: a_s[n,h] = sum_c xh[n,h,c]*as[h,c]; same for a_d
// ---------------------------------------------------------------------------
__global__ __launch_bounds__(256) void k_gat_ad(
    const float* __restrict__ xh, const float* __restrict__ as_w,
    const float* __restrict__ ad_w, float* __restrict__ a_s,
    float* __restrict__ a_d, int N)
{
  const int wid = threadIdx.x >> 6;
  const int lane = threadIdx.x & 63;
  const int node = blockIdx.x * 4 + wid;
  if (node >= N) return;
  const int head = lane >> 4;
  const int c0 = (lane & 15) * 8;
  const float* xr = xh + (size_t)node * 512 + lane * 8;
  float4 x0 = *(const float4*)(xr);
  float4 x1_ = *(const float4*)(xr + 4);
  const float* aw = as_w + head * 128 + c0;
  const float* dw = ad_w + head * 128 + c0;
  float s1 = x0.x*aw[0] + x0.y*aw[1] + x0.z*aw[2] + x0.w*aw[3]
           + x1_.x*aw[4] + x1_.y*aw[5] + x1_.z*aw[6] + x1_.w*aw[7];
  float s2 = x0.x*dw[0] + x0.y*dw[1] + x0.z*dw[2] + x0.w*dw[3]
           + x1_.x*dw[4] + x1_.y*dw[5] + x1_.z*dw[6] + x1_.w*dw[7];
  s1 = grp16_sum(s1);
  s2 = grp16_sum(s2);
  if ((lane & 15) == 0) {
    a_s[node * 4 + head] = s1;
    a_d[node * 4 + head] = s2;
  }
}

// ---------------------------------------------------------------------------
// GAT aggregation (incl. implicit self loop), ONLINE softmax single pass.
// ---------------------------------------------------------------------------
__global__ __launch_bounds__(256) void k_gat_agg(
    const float* __restrict__ xh, const float* __restrict__ a_s,
    const float* __restrict__ a_d, const int* __restrict__ offs,
    const int* __restrict__ csr_src, const float* __restrict__ bias,
    float* __restrict__ xout, int N)
{
  const int wid = threadIdx.x >> 6;
  const int lane = threadIdx.x & 63;
  const int node = blockIdx.x * 4 + wid;
  if (node >= N) return;
  const int head = lane >> 4;
  const float adn = a_d[node * 4 + head];
  const float asn = a_s[node * 4 + head];
  float lself = asn + adn;
  lself = lself >= 0.f ? lself : 0.2f * lself;

  // init with self loop (w = exp(0) = 1 at mx = lself)
  float mx = lself;
  float ssum = 1.f;
  float acc[8];
  {
    const float* xr = xh + (size_t)node * 512 + lane * 8;
    float4 x0 = *(const float4*)(xr);
    float4 x1_ = *(const float4*)(xr + 4);
    acc[0]=x0.x; acc[1]=x0.y; acc[2]=x0.z; acc[3]=x0.w;
    acc[4]=x1_.x; acc[5]=x1_.y; acc[6]=x1_.z; acc[7]=x1_.w;
  }

  const int beg = offs[node], end = offs[node + 1];
  int e = beg;
  for (; e + 2 <= end; e += 2) {
    int s0 = csr_src[e];
    int s1 = csr_src[e + 1];
    float l0 = a_s[s0 * 4 + head] + adn;
    float l1 = a_s[s1 * 4 + head] + adn;
    l0 = l0 >= 0.f ? l0 : 0.2f * l0;
    l1 = l1 >= 0.f ? l1 : 0.2f * l1;
    const float* r0 = xh + (size_t)s0 * 512 + lane * 8;
    const float* r1 = xh + (size_t)s1 * 512 + lane * 8;
    float4 xa0 = *(const float4*)(r0);
    float4 xa1 = *(const float4*)(r0 + 4);
    float4 xb0 = *(const float4*)(r1);
    float4 xb1 = *(const float4*)(r1 + 4);
    float nm = fmaxf(mx, fmaxf(l0, l1));
    float sc = expf(mx - nm);
    float w0 = expf(l0 - nm);
    float w1 = expf(l1 - nm);
    ssum = ssum * sc + w0 + w1;
    acc[0] = acc[0]*sc + w0*xa0.x + w1*xb0.x;
    acc[1] = acc[1]*sc + w0*xa0.y + w1*xb0.y;
    acc[2] = acc[2]*sc + w0*xa0.z + w1*xb0.z;
    acc[3] = acc[3]*sc + w0*xa0.w + w1*xb0.w;
    acc[4] = acc[4]*sc + w0*xa1.x + w1*xb1.x;
    acc[5] = acc[5]*sc + w0*xa1.y + w1*xb1.y;
    acc[6] = acc[6]*sc + w0*xa1.z + w1*xb1.z;
    acc[7] = acc[7]*sc + w0*xa1.w + w1*xb1.w;
    mx = nm;
  }
  if (e < end) {
    int s0 = csr_src[e];
    float l0 = a_s[s0 * 4 + head] + adn;
    l0 = l0 >= 0.f ? l0 : 0.2f * l0;
    const float* r0 = xh + (size_t)s0 * 512 + lane * 8;
    float4 xa0 = *(const float4*)(r0);
    float4 xa1 = *(const float4*)(r0 + 4);
    float nm = fmaxf(mx, l0);
    float sc = expf(mx - nm);
    float w0 = expf(l0 - nm);
    ssum = ssum * sc + w0;
    acc[0] = acc[0]*sc + w0*xa0.x;
    acc[1] = acc[1]*sc + w0*xa0.y;
    acc[2] = acc[2]*sc + w0*xa0.z;
    acc[3] = acc[3]*sc + w0*xa0.w;
    acc[4] = acc[4]*sc + w0*xa1.x;
    acc[5] = acc[5]*sc + w0*xa1.y;
    acc[6] = acc[6]*sc + w0*xa1.z;
    acc[7] = acc[7]*sc + w0*xa1.w;
  }

  float inv = 1.f / (ssum + 1e-16f);
#pragma unroll
  for (int j = 0; j < 8; ++j) acc[j] *= inv;
#pragma unroll
  for (int j = 0; j < 8; ++j) {
    acc[j] += __shfl_xor(acc[j], 16);
    acc[j] += __shfl_xor(acc[j], 32);
  }
  if (lane < 16) {
    const float* b = bias + lane * 8;
    float* xo = xout + (size_t)node * 128 + lane * 8;
#pragma unroll
    for (int j = 0; j < 8; ++j) xo[j] = fmaxf(0.25f * acc[j] + b[j], 0.f);
  }
}

// ---------------------------------------------------------------------------
// LSTM elementwise epilogue (h0=c0=0; gate order i,f,g,o; gf unused)
// ---------------------------------------------------------------------------
__global__ __launch_bounds__(256) void k_lstm(
    const float* __restrict__ gates, float* __restrict__ out, int N)
{
  int idx = blockIdx.x * 256 + threadIdx.x;
  if (idx >= N * 128) return;
  int n = idx >> 7, c = idx & 127;
  const float* g = gates + (size_t)n * 512;
  float gi = g[c], gg = g[256 + c], go = g[384 + c];
  float cv = (1.f / (1.f + expf(-gi))) * tanhf(gg);
  float hv = (1.f / (1.f + expf(-go))) * tanhf(cv);
  out[idx] = hv;
  out[(size_t)N * 128 + idx] = cv;
}

// ---------------------------------------------------------------------------
extern "C" void kernel_launch(void* const* d_in, const int* in_sizes, int n_in,
                              void* d_out, int out_size, void* d_ws, size_t ws_size,
                              hipStream_t stream) {
  const int*   node_ids = (const int*)d_in[0];
  const int*   etid     = (const int*)d_in[1];
  const int*   src      = (const int*)d_in[2];
  const int*   dst      = (const int*)d_in[3];
  const float* ef       = (const float*)d_in[4];
  const float* inten    = (const float*)d_in[5];
  const float* nemb     = (const float*)d_in[6];
  const float* ett      = (const float*)d_in[7];
  const float* ev_w1 = (const float*)d_in[8],  *ev_b1 = (const float*)d_in[9];
  const float* ev_g1 = (const float*)d_in[10], *ev_bt1 = (const float*)d_in[11];
  const float* ev_w2 = (const float*)d_in[12], *ev_b2 = (const float*)d_in[13];
  const float* ev_g2 = (const float*)d_in[14], *ev_bt2 = (const float*)d_in[15];
  const float* wq = (const float*)d_in[16], *bq = (const float*)d_in[17];
  const float* wk = (const float*)d_in[18], *bk = (const float*)d_in[19];
  const float* wv = (const float*)d_in[20], *bv = (const float*)d_in[21];
  const float* wskip = (const float*)d_in[22], *bskip = (const float*)d_in[23];
  const float* g0_w = (const float*)d_in[24], *g0_as = (const float*)d_in[25];
  const float* g0_ad = (const float*)d_in[26], *g0_b = (const float*)d_in[27];
  const float* g1_w = (const float*)d_in[28], *g1_as = (const float*)d_in[29];
  const float* g1_ad = (const float*)d_in[30], *g1_b = (const float*)d_in[31];
  const float* wih = (const float*)d_in[32];
  const float* bih = (const float*)d_in[34], *bhh = (const float*)d_in[35];

  const int N = in_sizes[0];
  const int K = in_sizes[1];
  const int E = in_sizes[2];
  const int EV = in_sizes[4];

  float* ws = (float*)d_ws;
  size_t o = 0;
  float* e_vec = ws + o; o += 128;
  float* cvec1 = ws + o; o += QKV_N;
  float* cvec2 = ws + o; o += 512;
  float* B1    = ws + o; o += (size_t)128 * QKV_N;
  float* C1    = ws + o; o += (size_t)N * QKV_N;
  float* x_a   = ws + o; o += (size_t)N * 128;
  float* x_b   = ws + o; o += (size_t)N * 128;
  float* xh    = ws + o; o += (size_t)N * 512;
  float* a_s   = ws + o; o += (size_t)N * 4;
  float* a_d   = ws + o; o += (size_t)N * 4;
  int* counts  = (int*)(ws + o); o += N;
  int* offs    = (int*)(ws + o); o += (size_t)N + 1;
  int* cursor  = (int*)(ws + o); o += N;
  int* csr_src = (int*)(ws + o); o += E;

  float* out = (float*)d_out;

  const int nodeBlocks = (N + 3) / 4;
  const int gridMy = (N + 127) / 128;

  // --- tiny setup kernels ---
  k_event<<<1, 128, 0, stream>>>(ef, EV, ev_w1, ev_b1, ev_g1, ev_bt1,
                                 ev_w2, ev_b2, ev_g2, ev_bt2,
                                 ett, etid, inten, K, e_vec);
  k_cvec<<<(QKV_N + 255) / 256, 256, 0, stream>>>(e_vec, wq, bq, wk, bk, wv, bv,
                                                  wskip, bskip, cvec1);
  k_pack<<<(D_DIM * QKV_N + 255) / 256, 256, 0, stream>>>(wq, wk, wv, wskip, B1);
  k_cvec2<<<2, 256, 0, stream>>>(bih, bhh, cvec2);

  // --- CSR build ---
  k_zero<<<(N + 255) / 256, 256, 0, stream>>>(counts, N);
  k_count<<<(E + 255) / 256, 256, 0, stream>>>(dst, counts, E);
  k_scan<<<1, 1024, 0, stream>>>(counts, offs, cursor, N);
  k_fill<<<(E + 255) / 256, 256, 0, stream>>>(src, dst, cursor, csr_src, E);

  // --- QKV + skip fused GEMM: C1[N,1664] ---
  sgemm_k128<<<dim3(QKV_N / 128, gridMy), 256, 0, stream>>>(
      nemb, node_ids, B1, cvec1, C1, N, QKV_N);

  // --- TransformerConv aggregation -> x_a[N,128] ---
  k_tconv<<<nodeBlocks, 256, 0, stream>>>(C1, offs, csr_src, x_a, N);

  // --- GAT layer 1 ---
  sgemm_k128<<<dim3(512 / 128, gridMy), 256, 0, stream>>>(
      x_a, nullptr, g0_w, nullptr, xh, N, 512);
  k_gat_ad<<<nodeBlocks, 256, 0, stream>>>(xh, g0_as, g0_ad, a_s, a_d, N);
  k_gat_agg<<<nodeBlocks, 256, 0, stream>>>(xh, a_s, a_d, offs, csr_src, g0_b, x_b, N);

  // --- GAT layer 2 ---
  sgemm_k128<<<dim3(512 / 128, gridMy), 256, 0, stream>>>(
      x_b, nullptr, g1_w, nullptr, xh, N, 512);
  k_gat_ad<<<nodeBlocks, 256, 0, stream>>>(xh, g1_as, g1_ad, a_s, a_d, N);
  k_gat_agg<<<nodeBlocks, 256, 0, stream>>>(xh, a_s, a_d, offs, csr_src, g1_b, x_a, N);

  // --- LSTM ---
  sgemm_k128<<<dim3(512 / 128, gridMy), 256, 0, stream>>>(
      x_a, nullptr, wih, cvec2, xh, N, 512);
  k_lstm<<<((N * 128) + 255) / 256, 256, 0, stream>>>(xh, out, N);
}

// Round 4
// 643.091 us; speedup vs baseline: 1.3154x; 1.1385x over previous
//
#include <hip/hip_runtime.h>
#include <math.h>

// Problem constants (fixed by the reference)
#define D_DIM 128
#define H_DIM 128
#define QKV_N 1664   // 3*NH*H + H (q|k|v|skip packed columns)
#define SQRT_H_INV 0.08838834764831845f  // 1/sqrt(128)

typedef unsigned short u16;
typedef unsigned short ushort8v __attribute__((ext_vector_type(8)));
typedef __bf16 bf16x8 __attribute__((ext_vector_type(8)));
typedef float f32x4 __attribute__((ext_vector_type(4)));

__device__ __forceinline__ float grp16_sum(float v) {
  v += __shfl_xor(v, 1);
  v += __shfl_xor(v, 2);
  v += __shfl_xor(v, 4);
  v += __shfl_xor(v, 8);
  return v;
}

__device__ __forceinline__ void split_bf16(float x, u16& h, u16& l) {
  __bf16 hb = (__bf16)x;
  float rm = x - (float)hb;
  __bf16 lb = (__bf16)rm;
  h = __builtin_bit_cast(u16, hb);
  l = __builtin_bit_cast(u16, lb);
}

// ---------------------------------------------------------------------------
// K0: event encoder MLP (single block, 128 threads) -> e[128]
// ---------------------------------------------------------------------------
__global__ __launch_bounds__(128) void k_event(
    const float* __restrict__ ef, int EV,
    const float* __restrict__ w1, const float* __restrict__ b1,
    const float* __restrict__ g1, const float* __restrict__ bt1,
    const float* __restrict__ w2, const float* __restrict__ b2,
    const float* __restrict__ g2, const float* __restrict__ bt2,
    const float* __restrict__ ett, const int* __restrict__ etid,
    const float* __restrict__ inten, int K,
    float* __restrict__ e_out)
{
  __shared__ float sh[H_DIM];
  __shared__ float red[H_DIM];
  const int t = threadIdx.x;

  float acc = b1[t];
  for (int i = 0; i < EV; ++i) acc += ef[i] * w1[i * H_DIM + t];

  // LayerNorm 1
  red[t] = acc; __syncthreads();
  for (int s = 64; s > 0; s >>= 1) { if (t < s) red[t] += red[t + s]; __syncthreads(); }
  float mu = red[0] / H_DIM; __syncthreads();
  float d = acc - mu;
  red[t] = d * d; __syncthreads();
  for (int s = 64; s > 0; s >>= 1) { if (t < s) red[t] += red[t + s]; __syncthreads(); }
  float var = red[0] / H_DIM; __syncthreads();
  float y = d * rsqrtf(var + 1e-5f) * g1[t] + bt1[t];
  y = fmaxf(y, 0.f);
  sh[t] = y; __syncthreads();

  float acc2 = b2[t];
  for (int i = 0; i < H_DIM; ++i) acc2 += sh[i] * w2[i * H_DIM + t];

  // LayerNorm 2
  red[t] = acc2; __syncthreads();
  for (int s = 64; s > 0; s >>= 1) { if (t < s) red[t] += red[t + s]; __syncthreads(); }
  mu = red[0] / H_DIM; __syncthreads();
  d = acc2 - mu;
  red[t] = d * d; __syncthreads();
  for (int s = 64; s > 0; s >>= 1) { if (t < s) red[t] += red[t + s]; __syncthreads(); }
  var = red[0] / H_DIM; __syncthreads();
  float y2 = d * rsqrtf(var + 1e-5f) * g2[t] + bt2[t];
  y2 = fmaxf(y2, 0.f);

  float m = 0.f;
  for (int k = 0; k < K; ++k) m += ett[etid[k] * H_DIM + t] * inten[k];
  e_out[t] = y2 + m / (float)K;
}

// ---------------------------------------------------------------------------
// K1: constant column vector  cvec[j] = e @ W[128:256, j] + b[j]  (q|k|v|skip)
// ---------------------------------------------------------------------------
__global__ __launch_bounds__(256) void k_cvec(
    const float* __restrict__ e,
    const float* __restrict__ wq, const float* __restrict__ bq,
    const float* __restrict__ wk, const float* __restrict__ bk,
    const float* __restrict__ wv, const float* __restrict__ bv,
    const float* __restrict__ wskip, const float* __restrict__ bskip,
    float* __restrict__ cvec)
{
  __shared__ float es[H_DIM];
  const int t = threadIdx.x;
  if (t < H_DIM) es[t] = e[t];
  __syncthreads();
  int j = blockIdx.x * 256 + t;
  if (j >= QKV_N) return;
  const float* W; const float* b; int col; int stride;
  if (j < 512)       { W = wq;    b = bq;    col = j;        stride = 512; }
  else if (j < 1024) { W = wk;    b = bk;    col = j - 512;  stride = 512; }
  else if (j < 1536) { W = wv;    b = bv;    col = j - 1024; stride = 512; }
  else               { W = wskip; b = bskip; col = j - 1536; stride = 128; }
  float a = b[col];
  for (int i = 0; i < H_DIM; ++i) a += es[i] * W[(D_DIM + i) * stride + col];
  cvec[j] = a;
}

// K1b: pack B1[128][1664] = rows 0..127 of [wq | wk | wv | wskip]
__global__ __launch_bounds__(256) void k_pack(
    const float* __restrict__ wq, const float* __restrict__ wk,
    const float* __restrict__ wv, const float* __restrict__ wskip,
    float* __restrict__ B1)
{
  int idx = blockIdx.x * 256 + threadIdx.x;
  if (idx >= D_DIM * QKV_N) return;
  int i = idx / QKV_N, j = idx - i * QKV_N;
  float v;
  if (j < 512)       v = wq[i * 512 + j];
  else if (j < 1024) v = wk[i * 512 + (j - 512)];
  else if (j < 1536) v = wv[i * 512 + (j - 1024)];
  else               v = wskip[i * 128 + (j - 1536)];
  B1[idx] = v;
}

// K1c: LSTM constant bias = bih + bhh
__global__ __launch_bounds__(256) void k_cvec2(
    const float* __restrict__ bih, const float* __restrict__ bhh,
    float* __restrict__ cvec2)
{
  int j = blockIdx.x * 256 + threadIdx.x;
  if (j < 512) cvec2[j] = bih[j] + bhh[j];
}

// ---------------------------------------------------------------------------
// Split A [M,128] fp32 (with optional row gather) into swizzled hi/lo bf16.
// Layout: row*128 + (g ^ (row&7))*8 + j   (g = k granule of 8, 16 per row)
// Rows in [M, Mpad) are zero-filled.
// ---------------------------------------------------------------------------
__global__ __launch_bounds__(256) void k_split_a(
    const float* __restrict__ A, const int* __restrict__ ids,
    u16* __restrict__ hi, u16* __restrict__ lo, int M, int Mpad)
{
  int idx = blockIdx.x * 256 + threadIdx.x;   // row*16 + g
  if (idx >= Mpad * 16) return;
  int row = idx >> 4, g = idx & 15;
  int gp = g ^ (row & 7);
  size_t dst = (size_t)row * 128 + gp * 8;
  if (row < M) {
    int ar = ids ? ids[row] : row;
    const float* srcp = A + (size_t)ar * 128 + g * 8;
#pragma unroll
    for (int j = 0; j < 8; ++j) {
      u16 h, l;
      split_bf16(srcp[j], h, l);
      hi[dst + j] = h; lo[dst + j] = l;
    }
  } else {
#pragma unroll
    for (int j = 0; j < 8; ++j) { hi[dst + j] = 0; lo[dst + j] = 0; }
  }
}

// ---------------------------------------------------------------------------
// Split+transpose B: W [128][Nc] fp32 -> Bt hi/lo [Nc][128] bf16, swizzled.
// ---------------------------------------------------------------------------
__global__ __launch_bounds__(256) void k_split_bt(
    const float* __restrict__ W,
    u16* __restrict__ hi, u16* __restrict__ lo, int Nc)
{
  int idx = blockIdx.x * 256 + threadIdx.x;  // n*16 + g
  if (idx >= Nc * 16) return;
  int n = idx >> 4, g = idx & 15;
  int gp = g ^ (n & 7);
  size_t dst = (size_t)n * 128 + gp * 8;
#pragma unroll
  for (int j = 0; j < 8; ++j) {
    u16 h, l;
    split_bf16(W[(size_t)(g * 8 + j) * Nc + n], h, l);
    hi[dst + j] = h; lo[dst + j] = l;
  }
}

// ---------------------------------------------------------------------------
// Split-bf16 MFMA GEMM: C[M,Nn] = A[M,128] @ B[128,Nn] (+cvec)
// A/B pre-split hi/lo bf16, granule-swizzled. BM=BN=128, full-K LDS stage.
// 256 thr = 4 waves, each computes 64x64 via 16 mfma_f32_16x16x32_bf16 frags,
// 3 split terms: hh + hl + lh (lo*lo dropped, ~2^-18 rel).
// ---------------------------------------------------------------------------
__global__ __launch_bounds__(256, 1) void mfma_gemm(
    const u16* __restrict__ Ahi, const u16* __restrict__ Alo,
    const u16* __restrict__ Bhi, const u16* __restrict__ Blo,
    const float* __restrict__ cvec, float* __restrict__ C, int M, int Nn)
{
  __shared__ u16 lds[4 * 16384];   // 128 KB
  u16* As_hi = lds;
  u16* As_lo = lds + 16384;
  u16* Bs_hi = lds + 32768;
  u16* Bs_lo = lds + 49152;

  const int t = threadIdx.x;
  const int bm = blockIdx.y * 128;
  const int bn = blockIdx.x * 128;

  const u16* gAh = Ahi + (size_t)bm * 128;
  const u16* gAl = Alo + (size_t)bm * 128;
  const u16* gBh = Bhi + (size_t)bn * 128;
  const u16* gBl = Blo + (size_t)bn * 128;

#pragma unroll
  for (int i = 0; i < 8; ++i) {
    int off = (i * 256 + t) * 8;
    *(ushort8v*)&As_hi[off] = *(const ushort8v*)&gAh[off];
    *(ushort8v*)&As_lo[off] = *(const ushort8v*)&gAl[off];
    *(ushort8v*)&Bs_hi[off] = *(const ushort8v*)&gBh[off];
    *(ushort8v*)&Bs_lo[off] = *(const ushort8v*)&gBl[off];
  }
  __syncthreads();

  const int lane = t & 63;
  const int wid = t >> 6;
  const int wr = wid >> 1, wc = wid & 1;
  const int abase = wr * 64 + (lane & 15);
  const int bbase = wc * 64 + (lane & 15);

  f32x4 acc[4][4];
  const f32x4 zero = {0.f, 0.f, 0.f, 0.f};
#pragma unroll
  for (int i = 0; i < 4; ++i)
#pragma unroll
    for (int j = 0; j < 4; ++j) acc[i][j] = zero;

#pragma unroll
  for (int ks = 0; ks < 4; ++ks) {
    const int gp = ((ks << 2) + (lane >> 4)) ^ (lane & 7);
    bf16x8 ah[4], al[4], bh[4], bl[4];
#pragma unroll
    for (int i = 0; i < 4; ++i) {
      int ra = (abase + i * 16) * 128 + gp * 8;
      ah[i] = *(const bf16x8*)&As_hi[ra];
      al[i] = *(const bf16x8*)&As_lo[ra];
      int rb = (bbase + i * 16) * 128 + gp * 8;
      bh[i] = *(const bf16x8*)&Bs_hi[rb];
      bl[i] = *(const bf16x8*)&Bs_lo[rb];
    }
#pragma unroll
    for (int i = 0; i < 4; ++i)
#pragma unroll
      for (int j = 0; j < 4; ++j) {
        acc[i][j] = __builtin_amdgcn_mfma_f32_16x16x32_bf16(ah[i], bh[j], acc[i][j], 0, 0, 0);
        acc[i][j] = __builtin_amdgcn_mfma_f32_16x16x32_bf16(ah[i], bl[j], acc[i][j], 0, 0, 0);
        acc[i][j] = __builtin_amdgcn_mfma_f32_16x16x32_bf16(al[i], bh[j], acc[i][j], 0, 0, 0);
      }
  }

  const int rq = (lane >> 4) << 2;   // 0,4,8,12
  const int cq = lane & 15;
#pragma unroll
  for (int j = 0; j < 4; ++j) {
    int col = bn + wc * 64 + j * 16 + cq;
    float cv = cvec ? cvec[col] : 0.f;
#pragma unroll
    for (int i = 0; i < 4; ++i) {
#pragma unroll
      for (int r = 0; r < 4; ++r) {
        int row = bm + wr * 64 + i * 16 + rq + r;
        if (row < M) C[(size_t)row * Nn + col] = acc[i][j][r] + cv;
      }
    }
  }
}

// ---------------------------------------------------------------------------
// CSR build
// ---------------------------------------------------------------------------
__global__ __launch_bounds__(256) void k_zero(int* __restrict__ p, int n) {
  int i = blockIdx.x * 256 + threadIdx.x;
  if (i < n) p[i] = 0;
}
__global__ __launch_bounds__(256) void k_count(
    const int* __restrict__ dst, int* __restrict__ counts, int E) {
  int e = blockIdx.x * 256 + threadIdx.x;
  if (e < E) atomicAdd(&counts[dst[e]], 1);
}
__global__ __launch_bounds__(1024) void k_scan(
    const int* __restrict__ counts, int* __restrict__ offs,
    int* __restrict__ cursor, int N)
{
  __shared__ int wsum[16];
  const int t = threadIdx.x;
  const int lane = t & 63;
  const int wid = t >> 6;
  int running = 0;
  for (int base = 0; base < N; base += 1024) {
    int v = (base + t < N) ? counts[base + t] : 0;
    int incl = v;
#pragma unroll
    for (int s = 1; s < 64; s <<= 1) {
      int u = __shfl_up(incl, s);
      if (lane >= s) incl += u;
    }
    if (lane == 63) wsum[wid] = incl;
    __syncthreads();
    if (wid == 0) {
      int w = (lane < 16) ? wsum[lane] : 0;
#pragma unroll
      for (int s = 1; s < 16; s <<= 1) {
        int u = __shfl_up(w, s);
        if (lane >= s) w += u;
      }
      if (lane < 16) wsum[lane] = w;
    }
    __syncthreads();
    int wpre = (wid > 0) ? wsum[wid - 1] : 0;
    int tot = wsum[15];
    int inclg = incl + wpre;
    if (base + t < N) {
      offs[base + t + 1] = running + inclg;
      cursor[base + t] = running + inclg - v;
    }
    running += tot;
    __syncthreads();
  }
  if (t == 0) offs[0] = 0;
}
__global__ __launch_bounds__(256) void k_fill(
    const int* __restrict__ src, const int* __restrict__ dst,
    int* __restrict__ cursor, int* __restrict__ csr_src, int E) {
  int e = blockIdx.x * 256 + threadIdx.x;
  if (e < E) {
    int slot = atomicAdd(&cursor[dst[e]], 1);
    csr_src[slot] = src[e];
  }
}

// ---------------------------------------------------------------------------
// TransformerConv aggregation, ONLINE softmax. One wave per node.
// Output written directly as swizzled hi/lo bf16 split (GEMM A-operand form).
// Pad rows [N, Npad) zero-filled (grid covers Npad).
// ---------------------------------------------------------------------------
__global__ __launch_bounds__(256) void k_tconv(
    const float* __restrict__ C1, const int* __restrict__ offs,
    const int* __restrict__ csr_src,
    u16* __restrict__ Xhi, u16* __restrict__ Xlo, int N)
{
  const int wid = threadIdx.x >> 6;
  const int lane = threadIdx.x & 63;
  const int node = blockIdx.x * 4 + wid;
  if (node >= N) {
    if (lane < 16) {
      size_t dst = (size_t)node * 128 + (size_t)((lane ^ (node & 7)) * 8);
#pragma unroll
      for (int j = 0; j < 8; ++j) { Xhi[dst + j] = 0; Xlo[dst + j] = 0; }
    }
    return;
  }
  const float* crow = C1 + (size_t)node * QKV_N;
  float q[8];
  {
    float4 q0 = *(const float4*)(crow + lane * 8);
    float4 q1 = *(const float4*)(crow + lane * 8 + 4);
    q[0]=q0.x; q[1]=q0.y; q[2]=q0.z; q[3]=q0.w;
    q[4]=q1.x; q[5]=q1.y; q[6]=q1.z; q[7]=q1.w;
  }
  const int beg = offs[node], end = offs[node + 1];
  float mx = -1e30f;
  float ssum = 0.f;
  float acc[8] = {0.f,0.f,0.f,0.f,0.f,0.f,0.f,0.f};

  int e = beg;
  for (; e + 2 <= end; e += 2) {
    int s0 = csr_src[e];
    int s1 = csr_src[e + 1];
    const float* r0 = C1 + (size_t)s0 * QKV_N + 512 + lane * 8;
    const float* r1 = C1 + (size_t)s1 * QKV_N + 512 + lane * 8;
    float4 ka0 = *(const float4*)(r0);
    float4 ka1 = *(const float4*)(r0 + 4);
    float4 kb0 = *(const float4*)(r1);
    float4 kb1 = *(const float4*)(r1 + 4);
    float4 va0 = *(const float4*)(r0 + 512);
    float4 va1 = *(const float4*)(r0 + 516);
    float4 vb0 = *(const float4*)(r1 + 512);
    float4 vb1 = *(const float4*)(r1 + 516);
    float p0 = q[0]*ka0.x + q[1]*ka0.y + q[2]*ka0.z + q[3]*ka0.w
             + q[4]*ka1.x + q[5]*ka1.y + q[6]*ka1.z + q[7]*ka1.w;
    float p1 = q[0]*kb0.x + q[1]*kb0.y + q[2]*kb0.z + q[3]*kb0.w
             + q[4]*kb1.x + q[5]*kb1.y + q[6]*kb1.z + q[7]*kb1.w;
    p0 = grp16_sum(p0) * SQRT_H_INV;
    p1 = grp16_sum(p1) * SQRT_H_INV;
    float nm = fmaxf(mx, fmaxf(p0, p1));
    float sc = expf(mx - nm);
    float w0 = expf(p0 - nm);
    float w1 = expf(p1 - nm);
    ssum = ssum * sc + w0 + w1;
    acc[0] = acc[0]*sc + w0*va0.x + w1*vb0.x;
    acc[1] = acc[1]*sc + w0*va0.y + w1*vb0.y;
    acc[2] = acc[2]*sc + w0*va0.z + w1*vb0.z;
    acc[3] = acc[3]*sc + w0*va0.w + w1*vb0.w;
    acc[4] = acc[4]*sc + w0*va1.x + w1*vb1.x;
    acc[5] = acc[5]*sc + w0*va1.y + w1*vb1.y;
    acc[6] = acc[6]*sc + w0*va1.z + w1*vb1.z;
    acc[7] = acc[7]*sc + w0*va1.w + w1*vb1.w;
    mx = nm;
  }
  if (e < end) {
    int s0 = csr_src[e];
    const float* r0 = C1 + (size_t)s0 * QKV_N + 512 + lane * 8;
    float4 ka0 = *(const float4*)(r0);
    float4 ka1 = *(const float4*)(r0 + 4);
    float4 va0 = *(const float4*)(r0 + 512);
    float4 va1 = *(const float4*)(r0 + 516);
    float p0 = q[0]*ka0.x + q[1]*ka0.y + q[2]*ka0.z + q[3]*ka0.w
             + q[4]*ka1.x + q[5]*ka1.y + q[6]*ka1.z + q[7]*ka1.w;
    p0 = grp16_sum(p0) * SQRT_H_INV;
    float nm = fmaxf(mx, p0);
    float sc = expf(mx - nm);
    float w0 = expf(p0 - nm);
    ssum = ssum * sc + w0;
    acc[0] = acc[0]*sc + w0*va0.x;
    acc[1] = acc[1]*sc + w0*va0.y;
    acc[2] = acc[2]*sc + w0*va0.z;
    acc[3] = acc[3]*sc + w0*va0.w;
    acc[4] = acc[4]*sc + w0*va1.x;
    acc[5] = acc[5]*sc + w0*va1.y;
    acc[6] = acc[6]*sc + w0*va1.z;
    acc[7] = acc[7]*sc + w0*va1.w;
  }

  float inv = 1.f / (ssum + 1e-16f);
#pragma unroll
  for (int j = 0; j < 8; ++j) acc[j] *= inv;
#pragma unroll
  for (int j = 0; j < 8; ++j) {
    acc[j] += __shfl_xor(acc[j], 16);
    acc[j] += __shfl_xor(acc[j], 32);
  }
  if (lane < 16) {
    const float* sk = crow + 1536 + lane * 8;
    size_t dst = (size_t)node * 128 + (size_t)((lane ^ (node & 7)) * 8);
#pragma unroll
    for (int j = 0; j < 8; ++j) {
      float x = 0.25f * acc[j] + sk[j];
      u16 h, l;
      split_bf16(x, h, l);
      Xhi[dst + j] = h; Xlo[dst + j] = l;
    }
  }
}

// ---------------------------------------------------------------------------
// GAT attention coefficients
// ---------------------------------------------------------------------------
__global__ __launch_bounds__(256) void k_gat_ad(
    const float* __restrict__ xh, const float* __restrict__ as_w,
    const float* __restrict__ ad_w, float* __restrict__ a_s,
    float* __restrict__ a_d, int N)
{
  const int wid = threadIdx.x >> 6;
  const int lane = threadIdx.x & 63;
  const int node = blockIdx.x * 4 + wid;
  if (node >= N) return;
  const int head = lane >> 4;
  const int c0 = (lane & 15) * 8;
  const float* xr = xh + (size_t)node * 512 + lane * 8;
  float4 x0 = *(const float4*)(xr);
  float4 x1_ = *(const float4*)(xr + 4);
  const float* aw = as_w + head * 128 + c0;
  const float* dw = ad_w + head * 128 + c0;
  float s1 = x0.x*aw[0] + x0.y*aw[1] + x0.z*aw[2] + x0.w*aw[3]
           + x1_.x*aw[4] + x1_.y*aw[5] + x1_.z*aw[6] + x1_.w*aw[7];
  float s2 = x0.x*dw[0] + x0.y*dw[1] + x0.z*dw[2] + x0.w*dw[3]
           + x1_.x*dw[4] + x1_.y*dw[5] + x1_.z*dw[6] + x1_.w*dw[7];
  s1 = grp16_sum(s1);
  s2 = grp16_sum(s2);
  if ((lane & 15) == 0) {
    a_s[node * 4 + head] = s1;
    a_d[node * 4 + head] = s2;
  }
}

// ---------------------------------------------------------------------------
// GAT aggregation (incl. self loop), ONLINE softmax; writes split hi/lo bf16.
// ---------------------------------------------------------------------------
__global__ __launch_bounds__(256) void k_gat_agg(
    const float* __restrict__ xh, const float* __restrict__ a_s,
    const float* __restrict__ a_d, const int* __restrict__ offs,
    const int* __restrict__ csr_src, const float* __restrict__ bias,
    u16* __restrict__ Xhi, u16* __restrict__ Xlo, int N)
{
  const int wid = threadIdx.x >> 6;
  const int lane = threadIdx.x & 63;
  const int node = blockIdx.x * 4 + wid;
  if (node >= N) {
    if (lane < 16) {
      size_t dst = (size_t)node * 128 + (size_t)((lane ^ (node & 7)) * 8);
#pragma unroll
      for (int j = 0; j < 8; ++j) { Xhi[dst + j] = 0; Xlo[dst + j] = 0; }
    }
    return;
  }
  const int head = lane >> 4;
  const float adn = a_d[node * 4 + head];
  const float asn = a_s[node * 4 + head];
  float lself = asn + adn;
  lself = lself >= 0.f ? lself : 0.2f * lself;

  float mx = lself;
  float ssum = 1.f;
  float acc[8];
  {
    const float* xr = xh + (size_t)node * 512 + lane * 8;
    float4 x0 = *(const float4*)(xr);
    float4 x1_ = *(const float4*)(xr + 4);
    acc[0]=x0.x; acc[1]=x0.y; acc[2]=x0.z; acc[3]=x0.w;
    acc[4]=x1_.x; acc[5]=x1_.y; acc[6]=x1_.z; acc[7]=x1_.w;
  }

  const int beg = offs[node], end = offs[node + 1];
  int e = beg;
  for (; e + 2 <= end; e += 2) {
    int s0 = csr_src[e];
    int s1 = csr_src[e + 1];
    float l0 = a_s[s0 * 4 + head] + adn;
    float l1 = a_s[s1 * 4 + head] + adn;
    l0 = l0 >= 0.f ? l0 : 0.2f * l0;
    l1 = l1 >= 0.f ? l1 : 0.2f * l1;
    const float* r0 = xh + (size_t)s0 * 512 + lane * 8;
    const float* r1 = xh + (size_t)s1 * 512 + lane * 8;
    float4 xa0 = *(const float4*)(r0);
    float4 xa1 = *(const float4*)(r0 + 4);
    float4 xb0 = *(const float4*)(r1);
    float4 xb1 = *(const float4*)(r1 + 4);
    float nm = fmaxf(mx, fmaxf(l0, l1));
    float sc = expf(mx - nm);
    float w0 = expf(l0 - nm);
    float w1 = expf(l1 - nm);
    ssum = ssum * sc + w0 + w1;
    acc[0] = acc[0]*sc + w0*xa0.x + w1*xb0.x;
    acc[1] = acc[1]*sc + w0*xa0.y + w1*xb0.y;
    acc[2] = acc[2]*sc + w0*xa0.z + w1*xb0.z;
    acc[3] = acc[3]*sc + w0*xa0.w + w1*xb0.w;
    acc[4] = acc[4]*sc + w0*xa1.x + w1*xb1.x;
    acc[5] = acc[5]*sc + w0*xa1.y + w1*xb1.y;
    acc[6] = acc[6]*sc + w0*xa1.z + w1*xb1.z;
    acc[7] = acc[7]*sc + w0*xa1.w + w1*xb1.w;
    mx = nm;
  }
  if (e < end) {
    int s0 = csr_src[e];
    float l0 = a_s[s0 * 4 + head] + adn;
    l0 = l0 >= 0.f ? l0 : 0.2f * l0;
    const float* r0 = xh + (size_t)s0 * 512 + lane * 8;
    float4 xa0 = *(const float4*)(r0);
    float4 xa1 = *(const float4*)(r0 + 4);
    float nm = fmaxf(mx, l0);
    float sc = expf(mx - nm);
    float w0 = expf(l0 - nm);
    ssum = ssum * sc + w0;
    acc[0] = acc[0]*sc + w0*xa0.x;
    acc[1] = acc[1]*sc + w0*xa0.y;
    acc[2] = acc[2]*sc + w0*xa0.z;
    acc[3] = acc[3]*sc + w0*xa0.w;
    acc[4] = acc[4]*sc + w0*xa1.x;
    acc[5] = acc[5]*sc + w0*xa1.y;
    acc[6] = acc[6]*sc + w0*xa1.z;
    acc[7] = acc[7]*sc + w0*xa1.w;
  }

  float inv = 1.f / (ssum + 1e-16f);
#pragma unroll
  for (int j = 0; j < 8; ++j) acc[j] *= inv;
#pragma unroll
  for (int j = 0; j < 8; ++j) {
    acc[j] += __shfl_xor(acc[j], 16);
    acc[j] += __shfl_xor(acc[j], 32);
  }
  if (lane < 16) {
    const float* b = bias + lane * 8;
    size_t dst = (size_t)node * 128 + (size_t)((lane ^ (node & 7)) * 8);
#pragma unroll
    for (int j = 0; j < 8; ++j) {
      float x = fmaxf(0.25f * acc[j] + b[j], 0.f);
      u16 h, l;
      split_bf16(x, h, l);
      Xhi[dst + j] = h; Xlo[dst + j] = l;
    }
  }
}

// ---------------------------------------------------------------------------
// LSTM elementwise epilogue (h0=c0=0; gate order i,f,g,o; gf unused)
// ---------------------------------------------------------------------------
__global__ __launch_bounds__(256) void k_lstm(
    const float* __restrict__ gates, float* __restrict__ out, int N)
{
  int idx = blockIdx.x * 256 + threadIdx.x;
  if (idx >= N * 128) return;
  int n = idx >> 7, c = idx & 127;
  const float* g = gates + (size_t)n * 512;
  float gi = g[c], gg = g[256 + c], go = g[384 + c];
  float cv = (1.f / (1.f + expf(-gi))) * tanhf(gg);
  float hv = (1.f / (1.f + expf(-go))) * tanhf(cv);
  out[idx] = hv;
  out[(size_t)N * 128 + idx] = cv;
}

// ---------------------------------------------------------------------------
extern "C" void kernel_launch(void* const* d_in, const int* in_sizes, int n_in,
                              void* d_out, int out_size, void* d_ws, size_t ws_size,
                              hipStream_t stream) {
  const int*   node_ids = (const int*)d_in[0];
  const int*   etid     = (const int*)d_in[1];
  const int*   src      = (const int*)d_in[2];
  const int*   dst      = (const int*)d_in[3];
  const float* ef       = (const float*)d_in[4];
  const float* inten    = (const float*)d_in[5];
  const float* nemb     = (const float*)d_in[6];
  const float* ett      = (const float*)d_in[7];
  const float* ev_w1 = (const float*)d_in[8],  *ev_b1 = (const float*)d_in[9];
  const float* ev_g1 = (const float*)d_in[10], *ev_bt1 = (const float*)d_in[11];
  const float* ev_w2 = (const float*)d_in[12], *ev_b2 = (const float*)d_in[13];
  const float* ev_g2 = (const float*)d_in[14], *ev_bt2 = (const float*)d_in[15];
  const float* wq = (const float*)d_in[16], *bq = (const float*)d_in[17];
  const float* wk = (const float*)d_in[18], *bk = (const float*)d_in[19];
  const float* wv = (const float*)d_in[20], *bv = (const float*)d_in[21];
  const float* wskip = (const float*)d_in[22], *bskip = (const float*)d_in[23];
  const float* g0_w = (const float*)d_in[24], *g0_as = (const float*)d_in[25];
  const float* g0_ad = (const float*)d_in[26], *g0_b = (const float*)d_in[27];
  const float* g1_w = (const float*)d_in[28], *g1_as = (const float*)d_in[29];
  const float* g1_ad = (const float*)d_in[30], *g1_b = (const float*)d_in[31];
  const float* wih = (const float*)d_in[32];
  const float* bih = (const float*)d_in[34], *bhh = (const float*)d_in[35];

  const int N = in_sizes[0];
  const int K = in_sizes[1];
  const int E = in_sizes[2];
  const int EV = in_sizes[4];

  const int gridMy = (N + 127) / 128;
  const int Npad = gridMy * 128;

  float* ws = (float*)d_ws;
  size_t o = 0;
  float* e_vec = ws + o; o += 128;
  float* cvec1 = ws + o; o += QKV_N;
  float* cvec2 = ws + o; o += 512;
  float* B1    = ws + o; o += (size_t)128 * QKV_N;
  float* C1    = ws + o; o += (size_t)N * QKV_N;
  float* xh    = ws + o; o += (size_t)N * 512;
  // bf16 split buffers (u16), carved in float units (all multiples of 4 floats)
  u16* Ahi  = (u16*)(ws + o); o += (size_t)Npad * 64;
  u16* Alo  = (u16*)(ws + o); o += (size_t)Npad * 64;
  u16* XShi = (u16*)(ws + o); o += (size_t)Npad * 64;
  u16* XSlo = (u16*)(ws + o); o += (size_t)Npad * 64;
  u16* Bqhi = (u16*)(ws + o); o += (size_t)QKV_N * 64;
  u16* Bqlo = (u16*)(ws + o); o += (size_t)QKV_N * 64;
  u16* Bg0hi = (u16*)(ws + o); o += 512 * 64;
  u16* Bg0lo = (u16*)(ws + o); o += 512 * 64;
  u16* Bg1hi = (u16*)(ws + o); o += 512 * 64;
  u16* Bg1lo = (u16*)(ws + o); o += 512 * 64;
  u16* Bwhi  = (u16*)(ws + o); o += 512 * 64;
  u16* Bwlo  = (u16*)(ws + o); o += 512 * 64;
  float* a_s   = ws + o; o += (size_t)N * 4;
  float* a_d   = ws + o; o += (size_t)N * 4;
  int* counts  = (int*)(ws + o); o += N;
  int* offs    = (int*)(ws + o); o += (size_t)N + 1;
  int* cursor  = (int*)(ws + o); o += N;
  int* csr_src = (int*)(ws + o); o += E;

  float* out = (float*)d_out;

  const int nodeBlocks = (N + 3) / 4;
  const int nodeBlocksPad = Npad / 4;

  // --- tiny setup kernels ---
  k_event<<<1, 128, 0, stream>>>(ef, EV, ev_w1, ev_b1, ev_g1, ev_bt1,
                                 ev_w2, ev_b2, ev_g2, ev_bt2,
                                 ett, etid, inten, K, e_vec);
  k_cvec<<<(QKV_N + 255) / 256, 256, 0, stream>>>(e_vec, wq, bq, wk, bk, wv, bv,
                                                  wskip, bskip, cvec1);
  k_pack<<<(D_DIM * QKV_N + 255) / 256, 256, 0, stream>>>(wq, wk, wv, wskip, B1);
  k_cvec2<<<2, 256, 0, stream>>>(bih, bhh, cvec2);

  // --- operand pre-split (bf16 hi/lo, granule-swizzled) ---
  k_split_a<<<(Npad * 16 + 255) / 256, 256, 0, stream>>>(nemb, node_ids, Ahi, Alo, N, Npad);
  k_split_bt<<<(QKV_N * 16 + 255) / 256, 256, 0, stream>>>(B1, Bqhi, Bqlo, QKV_N);
  k_split_bt<<<(512 * 16 + 255) / 256, 256, 0, stream>>>(g0_w, Bg0hi, Bg0lo, 512);
  k_split_bt<<<(512 * 16 + 255) / 256, 256, 0, stream>>>(g1_w, Bg1hi, Bg1lo, 512);
  k_split_bt<<<(512 * 16 + 255) / 256, 256, 0, stream>>>(wih, Bwhi, Bwlo, 512);

  // --- CSR build ---
  k_zero<<<(N + 255) / 256, 256, 0, stream>>>(counts, N);
  k_count<<<(E + 255) / 256, 256, 0, stream>>>(dst, counts, E);
  k_scan<<<1, 1024, 0, stream>>>(counts, offs, cursor, N);
  k_fill<<<(E + 255) / 256, 256, 0, stream>>>(src, dst, cursor, csr_src, E);

  // --- QKV + skip fused GEMM: C1[N,1664] ---
  mfma_gemm<<<dim3(QKV_N / 128, gridMy), 256, 0, stream>>>(
      Ahi, Alo, Bqhi, Bqlo, cvec1, C1, N, QKV_N);

  // --- TransformerConv aggregation -> XS split ---
  k_tconv<<<nodeBlocksPad, 256, 0, stream>>>(C1, offs, csr_src, XShi, XSlo, N);

  // --- GAT layer 1 ---
  mfma_gemm<<<dim3(4, gridMy), 256, 0, stream>>>(
      XShi, XSlo, Bg0hi, Bg0lo, nullptr, xh, N, 512);
  k_gat_ad<<<nodeBlocks, 256, 0, stream>>>(xh, g0_as, g0_ad, a_s, a_d, N);
  k_gat_agg<<<nodeBlocksPad, 256, 0, stream>>>(xh, a_s, a_d, offs, csr_src, g0_b,
                                               XShi, XSlo, N);

  // --- GAT layer 2 ---
  mfma_gemm<<<dim3(4, gridMy), 256, 0, stream>>>(
      XShi, XSlo, Bg1hi, Bg1lo, nullptr, xh, N, 512);
  k_gat_ad<<<nodeBlocks, 256, 0, stream>>>(xh, g1_as, g1_ad, a_s, a_d, N);
  k_gat_agg<<<nodeBlocksPad, 256, 0, stream>>>(xh, a_s, a_d, offs, csr_src, g1_b,
                                               XShi, XSlo, N);

  // --- LSTM ---
  mfma_gemm<<<dim3(4, gridMy), 256, 0, stream>>>(
      XShi, XSlo, Bwhi, Bwlo, cvec2, xh, N, 512);
  k_lstm<<<((N * 128) + 255) / 256, 256, 0, stream>>>(xh, out, N);
}

// Round 5
// 530.433 us; speedup vs baseline: 1.5948x; 1.2124x over previous
//
#include <hip/hip_runtime.h>
#include <math.h>

#define D_DIM 128
#define H_DIM 128
#define QKV_N 1664
#define SQRT_H_INV 0.08838834764831845f

typedef unsigned short u16;
typedef unsigned short ushort8v __attribute__((ext_vector_type(8)));
typedef __bf16 bf16x8 __attribute__((ext_vector_type(8)));
typedef float f32x4 __attribute__((ext_vector_type(4)));

__device__ __forceinline__ float grp16_sum(float v) {
  v += __shfl_xor(v, 1);
  v += __shfl_xor(v, 2);
  v += __shfl_xor(v, 4);
  v += __shfl_xor(v, 8);
  return v;
}

__device__ __forceinline__ void split_bf16(float x, u16& h, u16& l) {
  __bf16 hb = (__bf16)x;
  float rm = x - (float)hb;
  __bf16 lb = (__bf16)rm;
  h = __builtin_bit_cast(u16, hb);
  l = __builtin_bit_cast(u16, lb);
}

// ---------------------------------------------------------------------------
__global__ __launch_bounds__(128) void k_event(
    const float* __restrict__ ef, int EV,
    const float* __restrict__ w1, const float* __restrict__ b1,
    const float* __restrict__ g1, const float* __restrict__ bt1,
    const float* __restrict__ w2, const float* __restrict__ b2,
    const float* __restrict__ g2, const float* __restrict__ bt2,
    const float* __restrict__ ett, const int* __restrict__ etid,
    const float* __restrict__ inten, int K,
    float* __restrict__ e_out)
{
  __shared__ float sh[H_DIM];
  __shared__ float red[H_DIM];
  const int t = threadIdx.x;

  float acc = b1[t];
  for (int i = 0; i < EV; ++i) acc += ef[i] * w1[i * H_DIM + t];

  red[t] = acc; __syncthreads();
  for (int s = 64; s > 0; s >>= 1) { if (t < s) red[t] += red[t + s]; __syncthreads(); }
  float mu = red[0] / H_DIM; __syncthreads();
  float d = acc - mu;
  red[t] = d * d; __syncthreads();
  for (int s = 64; s > 0; s >>= 1) { if (t < s) red[t] += red[t + s]; __syncthreads(); }
  float var = red[0] / H_DIM; __syncthreads();
  float y = d * rsqrtf(var + 1e-5f) * g1[t] + bt1[t];
  y = fmaxf(y, 0.f);
  sh[t] = y; __syncthreads();

  float acc2 = b2[t];
  for (int i = 0; i < H_DIM; ++i) acc2 += sh[i] * w2[i * H_DIM + t];

  red[t] = acc2; __syncthreads();
  for (int s = 64; s > 0; s >>= 1) { if (t < s) red[t] += red[t + s]; __syncthreads(); }
  mu = red[0] / H_DIM; __syncthreads();
  d = acc2 - mu;
  red[t] = d * d; __syncthreads();
  for (int s = 64; s > 0; s >>= 1) { if (t < s) red[t] += red[t + s]; __syncthreads(); }
  var = red[0] / H_DIM; __syncthreads();
  float y2 = d * rsqrtf(var + 1e-5f) * g2[t] + bt2[t];
  y2 = fmaxf(y2, 0.f);

  float m = 0.f;
  for (int k = 0; k < K; ++k) m += ett[etid[k] * H_DIM + t] * inten[k];
  e_out[t] = y2 + m / (float)K;
}

// ---------------------------------------------------------------------------
__global__ __launch_bounds__(256) void k_cvec(
    const float* __restrict__ e,
    const float* __restrict__ wq, const float* __restrict__ bq,
    const float* __restrict__ wk, const float* __restrict__ bk,
    const float* __restrict__ wv, const float* __restrict__ bv,
    const float* __restrict__ wskip, const float* __restrict__ bskip,
    float* __restrict__ cvec)
{
  __shared__ float es[H_DIM];
  const int t = threadIdx.x;
  if (t < H_DIM) es[t] = e[t];
  __syncthreads();
  int j = blockIdx.x * 256 + t;
  if (j >= QKV_N) return;
  const float* W; const float* b; int col; int stride;
  if (j < 512)       { W = wq;    b = bq;    col = j;        stride = 512; }
  else if (j < 1024) { W = wk;    b = bk;    col = j - 512;  stride = 512; }
  else if (j < 1536) { W = wv;    b = bv;    col = j - 1024; stride = 512; }
  else               { W = wskip; b = bskip; col = j - 1536; stride = 128; }
  float a = b[col];
  for (int i = 0; i < H_DIM; ++i) a += es[i] * W[(D_DIM + i) * stride + col];
  cvec[j] = a;
}

__global__ __launch_bounds__(256) void k_pack(
    const float* __restrict__ wq, const float* __restrict__ wk,
    const float* __restrict__ wv, const float* __restrict__ wskip,
    float* __restrict__ B1)
{
  int idx = blockIdx.x * 256 + threadIdx.x;
  if (idx >= D_DIM * QKV_N) return;
  int i = idx / QKV_N, j = idx - i * QKV_N;
  float v;
  if (j < 512)       v = wq[i * 512 + j];
  else if (j < 1024) v = wk[i * 512 + (j - 512)];
  else if (j < 1536) v = wv[i * 512 + (j - 1024)];
  else               v = wskip[i * 128 + (j - 1536)];
  B1[idx] = v;
}

__global__ __launch_bounds__(256) void k_cvec2(
    const float* __restrict__ bih, const float* __restrict__ bhh,
    float* __restrict__ cvec2)
{
  int j = blockIdx.x * 256 + threadIdx.x;
  if (j < 512) cvec2[j] = bih[j] + bhh[j];
}

// ---------------------------------------------------------------------------
__global__ __launch_bounds__(256) void k_split_a(
    const float* __restrict__ A, const int* __restrict__ ids,
    u16* __restrict__ hi, u16* __restrict__ lo, int M, int Mpad)
{
  int idx = blockIdx.x * 256 + threadIdx.x;   // row*16 + g
  if (idx >= Mpad * 16) return;
  int row = idx >> 4, g = idx & 15;
  int gp = g ^ (row & 7);
  size_t dst = (size_t)row * 128 + gp * 8;
  if (row < M) {
    int ar = ids ? ids[row] : row;
    const float* srcp = A + (size_t)ar * 128 + g * 8;
#pragma unroll
    for (int j = 0; j < 8; ++j) {
      u16 h, l;
      split_bf16(srcp[j], h, l);
      hi[dst + j] = h; lo[dst + j] = l;
    }
  } else {
#pragma unroll
    for (int j = 0; j < 8; ++j) { hi[dst + j] = 0; lo[dst + j] = 0; }
  }
}

__global__ __launch_bounds__(256) void k_split_bt(
    const float* __restrict__ W,
    u16* __restrict__ hi, u16* __restrict__ lo, int Nc)
{
  int idx = blockIdx.x * 256 + threadIdx.x;  // n*16 + g
  if (idx >= Nc * 16) return;
  int n = idx >> 4, g = idx & 15;
  int gp = g ^ (n & 7);
  size_t dst = (size_t)n * 128 + gp * 8;
#pragma unroll
  for (int j = 0; j < 8; ++j) {
    u16 h, l;
    split_bf16(W[(size_t)(g * 8 + j) * Nc + n], h, l);
    hi[dst + j] = h; lo[dst + j] = l;
  }
}

// ---------------------------------------------------------------------------
// Split-bf16 MFMA GEMM. Epilogue optionally emits bf16 panel for cols
// [bf_lo,bf_hi) at stride bf_stride; skipf32 drops fp32 store in that range.
// ---------------------------------------------------------------------------
__global__ __launch_bounds__(256, 1) void mfma_gemm(
    const u16* __restrict__ Ahi, const u16* __restrict__ Alo,
    const u16* __restrict__ Bhi, const u16* __restrict__ Blo,
    const float* __restrict__ cvec, float* __restrict__ C, int M, int Nn,
    u16* __restrict__ bf_out, int bf_lo, int bf_hi, int bf_stride, int skipf32)
{
  __shared__ u16 lds[4 * 16384];   // 128 KB
  u16* As_hi = lds;
  u16* As_lo = lds + 16384;
  u16* Bs_hi = lds + 32768;
  u16* Bs_lo = lds + 49152;

  const int t = threadIdx.x;
  const int bm = blockIdx.y * 128;
  const int bn = blockIdx.x * 128;

  const u16* gAh = Ahi + (size_t)bm * 128;
  const u16* gAl = Alo + (size_t)bm * 128;
  const u16* gBh = Bhi + (size_t)bn * 128;
  const u16* gBl = Blo + (size_t)bn * 128;

#pragma unroll
  for (int i = 0; i < 8; ++i) {
    int off = (i * 256 + t) * 8;
    *(ushort8v*)&As_hi[off] = *(const ushort8v*)&gAh[off];
    *(ushort8v*)&As_lo[off] = *(const ushort8v*)&gAl[off];
    *(ushort8v*)&Bs_hi[off] = *(const ushort8v*)&gBh[off];
    *(ushort8v*)&Bs_lo[off] = *(const ushort8v*)&gBl[off];
  }
  __syncthreads();

  const int lane = t & 63;
  const int wid = t >> 6;
  const int wr = wid >> 1, wc = wid & 1;
  const int abase = wr * 64 + (lane & 15);
  const int bbase = wc * 64 + (lane & 15);

  f32x4 acc[4][4];
  const f32x4 zero = {0.f, 0.f, 0.f, 0.f};
#pragma unroll
  for (int i = 0; i < 4; ++i)
#pragma unroll
    for (int j = 0; j < 4; ++j) acc[i][j] = zero;

#pragma unroll
  for (int ks = 0; ks < 4; ++ks) {
    const int gp = ((ks << 2) + (lane >> 4)) ^ (lane & 7);
    bf16x8 ah[4], al[4], bh[4], bl[4];
#pragma unroll
    for (int i = 0; i < 4; ++i) {
      int ra = (abase + i * 16) * 128 + gp * 8;
      ah[i] = *(const bf16x8*)&As_hi[ra];
      al[i] = *(const bf16x8*)&As_lo[ra];
      int rb = (bbase + i * 16) * 128 + gp * 8;
      bh[i] = *(const bf16x8*)&Bs_hi[rb];
      bl[i] = *(const bf16x8*)&Bs_lo[rb];
    }
#pragma unroll
    for (int i = 0; i < 4; ++i)
#pragma unroll
      for (int j = 0; j < 4; ++j) {
        acc[i][j] = __builtin_amdgcn_mfma_f32_16x16x32_bf16(ah[i], bh[j], acc[i][j], 0, 0, 0);
        acc[i][j] = __builtin_amdgcn_mfma_f32_16x16x32_bf16(ah[i], bl[j], acc[i][j], 0, 0, 0);
        acc[i][j] = __builtin_amdgcn_mfma_f32_16x16x32_bf16(al[i], bh[j], acc[i][j], 0, 0, 0);
      }
  }

  const int rq = (lane >> 4) << 2;
  const int cq = lane & 15;
#pragma unroll
  for (int j = 0; j < 4; ++j) {
    int col = bn + wc * 64 + j * 16 + cq;
    float cv = cvec ? cvec[col] : 0.f;
    bool inbf = bf_out && col >= bf_lo && col < bf_hi;
    bool wf32 = !(inbf && skipf32);
#pragma unroll
    for (int i = 0; i < 4; ++i) {
#pragma unroll
      for (int r = 0; r < 4; ++r) {
        int row = bm + wr * 64 + i * 16 + rq + r;
        if (row < M) {
          float val = acc[i][j][r] + cv;
          if (wf32) C[(size_t)row * Nn + col] = val;
          if (inbf) bf_out[(size_t)row * bf_stride + (col - bf_lo)] =
              __builtin_bit_cast(u16, (__bf16)val);
        }
      }
    }
  }
}

// ---------------------------------------------------------------------------
__global__ __launch_bounds__(256) void k_zero(int* __restrict__ p, int n) {
  int i = blockIdx.x * 256 + threadIdx.x;
  if (i < n) p[i] = 0;
}
__global__ __launch_bounds__(256) void k_count(
    const int* __restrict__ dst, int* __restrict__ counts, int E) {
  int e = blockIdx.x * 256 + threadIdx.x;
  if (e < E) atomicAdd(&counts[dst[e]], 1);
}
__global__ __launch_bounds__(1024) void k_scan(
    const int* __restrict__ counts, int* __restrict__ offs,
    int* __restrict__ cursor, int N)
{
  __shared__ int wsum[16];
  const int t = threadIdx.x;
  const int lane = t & 63;
  const int wid = t >> 6;
  int running = 0;
  for (int base = 0; base < N; base += 1024) {
    int v = (base + t < N) ? counts[base + t] : 0;
    int incl = v;
#pragma unroll
    for (int s = 1; s < 64; s <<= 1) {
      int u = __shfl_up(incl, s);
      if (lane >= s) incl += u;
    }
    if (lane == 63) wsum[wid] = incl;
    __syncthreads();
    if (wid == 0) {
      int w = (lane < 16) ? wsum[lane] : 0;
#pragma unroll
      for (int s = 1; s < 16; s <<= 1) {
        int u = __shfl_up(w, s);
        if (lane >= s) w += u;
      }
      if (lane < 16) wsum[lane] = w;
    }
    __syncthreads();
    int wpre = (wid > 0) ? wsum[wid - 1] : 0;
    int tot = wsum[15];
    int inclg = incl + wpre;
    if (base + t < N) {
      offs[base + t + 1] = running + inclg;
      cursor[base + t] = running + inclg - v;
    }
    running += tot;
    __syncthreads();
  }
  if (t == 0) offs[0] = 0;
}
__global__ __launch_bounds__(256) void k_fill(
    const int* __restrict__ src, const int* __restrict__ dst,
    int* __restrict__ cursor, int* __restrict__ csr_src, int E) {
  int e = blockIdx.x * 256 + threadIdx.x;
  if (e < E) {
    int slot = atomicAdd(&cursor[dst[e]], 1);
    csr_src[slot] = src[e];
  }
}

// ---------------------------------------------------------------------------
// TransformerConv aggregation, ONLINE softmax. One wave per node.
// Q (cols 0..511) and skip (cols 1536..1663) from fp32 C1 (stride 1664);
// K/V gathered from bf16 panel KV[N][1024].
// ---------------------------------------------------------------------------
__global__ __launch_bounds__(256) void k_tconv(
    const float* __restrict__ C1, const u16* __restrict__ KV,
    const int* __restrict__ offs, const int* __restrict__ csr_src,
    u16* __restrict__ Xhi, u16* __restrict__ Xlo, int N)
{
  const int wid = threadIdx.x >> 6;
  const int lane = threadIdx.x & 63;
  const int node = blockIdx.x * 4 + wid;
  if (node >= N) {
    if (lane < 16) {
      size_t dst = (size_t)node * 128 + (size_t)((lane ^ (node & 7)) * 8);
#pragma unroll
      for (int j = 0; j < 8; ++j) { Xhi[dst + j] = 0; Xlo[dst + j] = 0; }
    }
    return;
  }
  const float* crow = C1 + (size_t)node * QKV_N;
  float q[8];
  {
    float4 q0 = *(const float4*)(crow + lane * 8);
    float4 q1 = *(const float4*)(crow + lane * 8 + 4);
    q[0]=q0.x; q[1]=q0.y; q[2]=q0.z; q[3]=q0.w;
    q[4]=q1.x; q[5]=q1.y; q[6]=q1.z; q[7]=q1.w;
  }
  const int beg = offs[node], end = offs[node + 1];
  float mx = -1e30f;
  float ssum = 0.f;
  float acc[8] = {0.f,0.f,0.f,0.f,0.f,0.f,0.f,0.f};

  int e = beg;
  for (; e + 2 <= end; e += 2) {
    int s0 = csr_src[e];
    int s1 = csr_src[e + 1];
    const u16* r0 = KV + (size_t)s0 * 1024 + lane * 8;
    const u16* r1 = KV + (size_t)s1 * 1024 + lane * 8;
    bf16x8 ka = *(const bf16x8*)(r0);
    bf16x8 kb = *(const bf16x8*)(r1);
    bf16x8 va = *(const bf16x8*)(r0 + 512);
    bf16x8 vb = *(const bf16x8*)(r1 + 512);
    float p0 = 0.f, p1 = 0.f;
#pragma unroll
    for (int j = 0; j < 8; ++j) {
      p0 += q[j] * (float)ka[j];
      p1 += q[j] * (float)kb[j];
    }
    p0 = grp16_sum(p0) * SQRT_H_INV;
    p1 = grp16_sum(p1) * SQRT_H_INV;
    float nm = fmaxf(mx, fmaxf(p0, p1));
    float sc = expf(mx - nm);
    float w0 = expf(p0 - nm);
    float w1 = expf(p1 - nm);
    ssum = ssum * sc + w0 + w1;
#pragma unroll
    for (int j = 0; j < 8; ++j)
      acc[j] = acc[j] * sc + w0 * (float)va[j] + w1 * (float)vb[j];
    mx = nm;
  }
  if (e < end) {
    int s0 = csr_src[e];
    const u16* r0 = KV + (size_t)s0 * 1024 + lane * 8;
    bf16x8 ka = *(const bf16x8*)(r0);
    bf16x8 va = *(const bf16x8*)(r0 + 512);
    float p0 = 0.f;
#pragma unroll
    for (int j = 0; j < 8; ++j) p0 += q[j] * (float)ka[j];
    p0 = grp16_sum(p0) * SQRT_H_INV;
    float nm = fmaxf(mx, p0);
    float sc = expf(mx - nm);
    float w0 = expf(p0 - nm);
    ssum = ssum * sc + w0;
#pragma unroll
    for (int j = 0; j < 8; ++j)
      acc[j] = acc[j] * sc + w0 * (float)va[j];
  }

  float inv = 1.f / (ssum + 1e-16f);
#pragma unroll
  for (int j = 0; j < 8; ++j) acc[j] *= inv;
#pragma unroll
  for (int j = 0; j < 8; ++j) {
    acc[j] += __shfl_xor(acc[j], 16);
    acc[j] += __shfl_xor(acc[j], 32);
  }
  if (lane < 16) {
    const float* sk = crow + 1536 + lane * 8;
    size_t dst = (size_t)node * 128 + (size_t)((lane ^ (node & 7)) * 8);
#pragma unroll
    for (int j = 0; j < 8; ++j) {
      float x = 0.25f * acc[j] + sk[j];
      u16 h, l;
      split_bf16(x, h, l);
      Xhi[dst + j] = h; Xlo[dst + j] = l;
    }
  }
}

// ---------------------------------------------------------------------------
__global__ __launch_bounds__(256) void k_gat_ad(
    const float* __restrict__ xh, const float* __restrict__ as_w,
    const float* __restrict__ ad_w, float* __restrict__ a_s,
    float* __restrict__ a_d, int N)
{
  const int wid = threadIdx.x >> 6;
  const int lane = threadIdx.x & 63;
  const int node = blockIdx.x * 4 + wid;
  if (node >= N) return;
  const int head = lane >> 4;
  const int c0 = (lane & 15) * 8;
  const float* xr = xh + (size_t)node * 512 + lane * 8;
  float4 x0 = *(const float4*)(xr);
  float4 x1_ = *(const float4*)(xr + 4);
  const float* aw = as_w + head * 128 + c0;
  const float* dw = ad_w + head * 128 + c0;
  float s1 = x0.x*aw[0] + x0.y*aw[1] + x0.z*aw[2] + x0.w*aw[3]
           + x1_.x*aw[4] + x1_.y*aw[5] + x1_.z*aw[6] + x1_.w*aw[7];
  float s2 = x0.x*dw[0] + x0.y*dw[1] + x0.z*dw[2] + x0.w*dw[3]
           + x1_.x*dw[4] + x1_.y*dw[5] + x1_.z*dw[6] + x1_.w*dw[7];
  s1 = grp16_sum(s1);
  s2 = grp16_sum(s2);
  if ((lane & 15) == 0) {
    a_s[node * 4 + head] = s1;
    a_d[node * 4 + head] = s2;
  }
}

// ---------------------------------------------------------------------------
// GAT aggregation, ONLINE softmax; self from fp32 xh, neighbors from bf16
// panel xhb[N][512]; writes split hi/lo bf16 for next GEMM.
// ---------------------------------------------------------------------------
__global__ __launch_bounds__(256) void k_gat_agg(
    const float* __restrict__ xh, const u16* __restrict__ xhb,
    const float* __restrict__ a_s, const float* __restrict__ a_d,
    const int* __restrict__ offs, const int* __restrict__ csr_src,
    const float* __restrict__ bias,
    u16* __restrict__ Xhi, u16* __restrict__ Xlo, int N)
{
  const int wid = threadIdx.x >> 6;
  const int lane = threadIdx.x & 63;
  const int node = blockIdx.x * 4 + wid;
  if (node >= N) {
    if (lane < 16) {
      size_t dst = (size_t)node * 128 + (size_t)((lane ^ (node & 7)) * 8);
#pragma unroll
      for (int j = 0; j < 8; ++j) { Xhi[dst + j] = 0; Xlo[dst + j] = 0; }
    }
    return;
  }
  const int head = lane >> 4;
  const float adn = a_d[node * 4 + head];
  const float asn = a_s[node * 4 + head];
  float lself = asn + adn;
  lself = lself >= 0.f ? lself : 0.2f * lself;

  float mx = lself;
  float ssum = 1.f;
  float acc[8];
  {
    const float* xr = xh + (size_t)node * 512 + lane * 8;
    float4 x0 = *(const float4*)(xr);
    float4 x1_ = *(const float4*)(xr + 4);
    acc[0]=x0.x; acc[1]=x0.y; acc[2]=x0.z; acc[3]=x0.w;
    acc[4]=x1_.x; acc[5]=x1_.y; acc[6]=x1_.z; acc[7]=x1_.w;
  }

  const int beg = offs[node], end = offs[node + 1];
  int e = beg;
  for (; e + 2 <= end; e += 2) {
    int s0 = csr_src[e];
    int s1 = csr_src[e + 1];
    float l0 = a_s[s0 * 4 + head] + adn;
    float l1 = a_s[s1 * 4 + head] + adn;
    l0 = l0 >= 0.f ? l0 : 0.2f * l0;
    l1 = l1 >= 0.f ? l1 : 0.2f * l1;
    const u16* r0 = xhb + (size_t)s0 * 512 + lane * 8;
    const u16* r1 = xhb + (size_t)s1 * 512 + lane * 8;
    bf16x8 xa = *(const bf16x8*)(r0);
    bf16x8 xb = *(const bf16x8*)(r1);
    float nm = fmaxf(mx, fmaxf(l0, l1));
    float sc = expf(mx - nm);
    float w0 = expf(l0 - nm);
    float w1 = expf(l1 - nm);
    ssum = ssum * sc + w0 + w1;
#pragma unroll
    for (int j = 0; j < 8; ++j)
      acc[j] = acc[j] * sc + w0 * (float)xa[j] + w1 * (float)xb[j];
    mx = nm;
  }
  if (e < end) {
    int s0 = csr_src[e];
    float l0 = a_s[s0 * 4 + head] + adn;
    l0 = l0 >= 0.f ? l0 : 0.2f * l0;
    const u16* r0 = xhb + (size_t)s0 * 512 + lane * 8;
    bf16x8 xa = *(const bf16x8*)(r0);
    float nm = fmaxf(mx, l0);
    float sc = expf(mx - nm);
    float w0 = expf(l0 - nm);
    ssum = ssum * sc + w0;
#pragma unroll
    for (int j = 0; j < 8; ++j)
      acc[j] = acc[j] * sc + w0 * (float)xa[j];
  }

  float inv = 1.f / (ssum + 1e-16f);
#pragma unroll
  for (int j = 0; j < 8; ++j) acc[j] *= inv;
#pragma unroll
  for (int j = 0; j < 8; ++j) {
    acc[j] += __shfl_xor(acc[j], 16);
    acc[j] += __shfl_xor(acc[j], 32);
  }
  if (lane < 16) {
    const float* b = bias + lane * 8;
    size_t dst = (size_t)node * 128 + (size_t)((lane ^ (node & 7)) * 8);
#pragma unroll
    for (int j = 0; j < 8; ++j) {
      float x = fmaxf(0.25f * acc[j] + b[j], 0.f);
      u16 h, l;
      split_bf16(x, h, l);
      Xhi[dst + j] = h; Xlo[dst + j] = l;
    }
  }
}

// ---------------------------------------------------------------------------
__global__ __launch_bounds__(256) void k_lstm(
    const float* __restrict__ gates, float* __restrict__ out, int N)
{
  int idx = blockIdx.x * 256 + threadIdx.x;
  if (idx >= N * 128) return;
  int n = idx >> 7, c = idx & 127;
  const float* g = gates + (size_t)n * 512;
  float gi = g[c], gg = g[256 + c], go = g[384 + c];
  float cv = (1.f / (1.f + expf(-gi))) * tanhf(gg);
  float hv = (1.f / (1.f + expf(-go))) * tanhf(cv);
  out[idx] = hv;
  out[(size_t)N * 128 + idx] = cv;
}

// ---------------------------------------------------------------------------
extern "C" void kernel_launch(void* const* d_in, const int* in_sizes, int n_in,
                              void* d_out, int out_size, void* d_ws, size_t ws_size,
                              hipStream_t stream) {
  const int*   node_ids = (const int*)d_in[0];
  const int*   etid     = (const int*)d_in[1];
  const int*   src      = (const int*)d_in[2];
  const int*   dst      = (const int*)d_in[3];
  const float* ef       = (const float*)d_in[4];
  const float* inten    = (const float*)d_in[5];
  const float* nemb     = (const float*)d_in[6];
  const float* ett      = (const float*)d_in[7];
  const float* ev_w1 = (const float*)d_in[8],  *ev_b1 = (const float*)d_in[9];
  const float* ev_g1 = (const float*)d_in[10], *ev_bt1 = (const float*)d_in[11];
  const float* ev_w2 = (const float*)d_in[12], *ev_b2 = (const float*)d_in[13];
  const float* ev_g2 = (const float*)d_in[14], *ev_bt2 = (const float*)d_in[15];
  const float* wq = (const float*)d_in[16], *bq = (const float*)d_in[17];
  const float* wk = (const float*)d_in[18], *bk = (const float*)d_in[19];
  const float* wv = (const float*)d_in[20], *bv = (const float*)d_in[21];
  const float* wskip = (const float*)d_in[22], *bskip = (const float*)d_in[23];
  const float* g0_w = (const float*)d_in[24], *g0_as = (const float*)d_in[25];
  const float* g0_ad = (const float*)d_in[26], *g0_b = (const float*)d_in[27];
  const float* g1_w = (const float*)d_in[28], *g1_as = (const float*)d_in[29];
  const float* g1_ad = (const float*)d_in[30], *g1_b = (const float*)d_in[31];
  const float* wih = (const float*)d_in[32];
  const float* bih = (const float*)d_in[34], *bhh = (const float*)d_in[35];

  const int N = in_sizes[0];
  const int K = in_sizes[1];
  const int E = in_sizes[2];
  const int EV = in_sizes[4];

  const int gridMy = (N + 127) / 128;
  const int Npad = gridMy * 128;

  float* ws = (float*)d_ws;
  size_t o = 0;
  float* e_vec = ws + o; o += 128;
  float* cvec1 = ws + o; o += QKV_N;
  float* cvec2 = ws + o; o += 512;
  float* B1    = ws + o; o += (size_t)128 * QKV_N;
  float* C1    = ws + o; o += (size_t)N * QKV_N;
  float* xh    = ws + o; o += (size_t)N * 512;
  u16* Ahi  = (u16*)(ws + o); o += (size_t)Npad * 64;
  u16* Alo  = (u16*)(ws + o); o += (size_t)Npad * 64;
  u16* XShi = (u16*)(ws + o); o += (size_t)Npad * 64;
  u16* XSlo = (u16*)(ws + o); o += (size_t)Npad * 64;
  u16* Bqhi = (u16*)(ws + o); o += (size_t)QKV_N * 64;
  u16* Bqlo = (u16*)(ws + o); o += (size_t)QKV_N * 64;
  u16* Bg0hi = (u16*)(ws + o); o += 512 * 64;
  u16* Bg0lo = (u16*)(ws + o); o += 512 * 64;
  u16* Bg1hi = (u16*)(ws + o); o += 512 * 64;
  u16* Bg1lo = (u16*)(ws + o); o += 512 * 64;
  u16* Bwhi  = (u16*)(ws + o); o += 512 * 64;
  u16* Bwlo  = (u16*)(ws + o); o += 512 * 64;
  u16* KV   = (u16*)(ws + o); o += (size_t)Npad * 512;  // [N][1024] u16
  u16* xhb  = (u16*)(ws + o); o += (size_t)Npad * 256;  // [N][512] u16
  float* a_s   = ws + o; o += (size_t)N * 4;
  float* a_d   = ws + o; o += (size_t)N * 4;
  int* counts  = (int*)(ws + o); o += N;
  int* offs    = (int*)(ws + o); o += (size_t)N + 1;
  int* cursor  = (int*)(ws + o); o += N;
  int* csr_src = (int*)(ws + o); o += E;

  float* out = (float*)d_out;

  const int nodeBlocks = (N + 3) / 4;
  const int nodeBlocksPad = Npad / 4;

  k_event<<<1, 128, 0, stream>>>(ef, EV, ev_w1, ev_b1, ev_g1, ev_bt1,
                                 ev_w2, ev_b2, ev_g2, ev_bt2,
                                 ett, etid, inten, K, e_vec);
  k_cvec<<<(QKV_N + 255) / 256, 256, 0, stream>>>(e_vec, wq, bq, wk, bk, wv, bv,
                                                  wskip, bskip, cvec1);
  k_pack<<<(D_DIM * QKV_N + 255) / 256, 256, 0, stream>>>(wq, wk, wv, wskip, B1);
  k_cvec2<<<2, 256, 0, stream>>>(bih, bhh, cvec2);

  k_split_a<<<(Npad * 16 + 255) / 256, 256, 0, stream>>>(nemb, node_ids, Ahi, Alo, N, Npad);
  k_split_bt<<<(QKV_N * 16 + 255) / 256, 256, 0, stream>>>(B1, Bqhi, Bqlo, QKV_N);
  k_split_bt<<<(512 * 16 + 255) / 256, 256, 0, stream>>>(g0_w, Bg0hi, Bg0lo, 512);
  k_split_bt<<<(512 * 16 + 255) / 256, 256, 0, stream>>>(g1_w, Bg1hi, Bg1lo, 512);
  k_split_bt<<<(512 * 16 + 255) / 256, 256, 0, stream>>>(wih, Bwhi, Bwlo, 512);

  k_zero<<<(N + 255) / 256, 256, 0, stream>>>(counts, N);
  k_count<<<(E + 255) / 256, 256, 0, stream>>>(dst, counts, E);
  k_scan<<<1, 1024, 0, stream>>>(counts, offs, cursor, N);
  k_fill<<<(E + 255) / 256, 256, 0, stream>>>(src, dst, cursor, csr_src, E);

  // QKV: fp32 q/skip -> C1 (K/V cols skipped); bf16 K/V -> KV panel
  mfma_gemm<<<dim3(QKV_N / 128, gridMy), 256, 0, stream>>>(
      Ahi, Alo, Bqhi, Bqlo, cvec1, C1, N, QKV_N,
      KV, 512, 1536, 1024, 1);

  k_tconv<<<nodeBlocksPad, 256, 0, stream>>>(C1, KV, offs, csr_src, XShi, XSlo, N);

  // GAT layer 1: fp32 xh + bf16 xhb
  mfma_gemm<<<dim3(4, gridMy), 256, 0, stream>>>(
      XShi, XSlo, Bg0hi, Bg0lo, nullptr, xh, N, 512,
      xhb, 0, 512, 512, 0);
  k_gat_ad<<<nodeBlocks, 256, 0, stream>>>(xh, g0_as, g0_ad, a_s, a_d, N);
  k_gat_agg<<<nodeBlocksPad, 256, 0, stream>>>(xh, xhb, a_s, a_d, offs, csr_src,
                                               g0_b, XShi, XSlo, N);

  // GAT layer 2
  mfma_gemm<<<dim3(4, gridMy), 256, 0, stream>>>(
      XShi, XSlo, Bg1hi, Bg1lo, nullptr, xh, N, 512,
      xhb, 0, 512, 512, 0);
  k_gat_ad<<<nodeBlocks, 256, 0, stream>>>(xh, g1_as, g1_ad, a_s, a_d, N);
  k_gat_agg<<<nodeBlocksPad, 256, 0, stream>>>(xh, xhb, a_s, a_d, offs, csr_src,
                                               g1_b, XShi, XSlo, N);

  // LSTM
  mfma_gemm<<<dim3(4, gridMy), 256, 0, stream>>>(
      XShi, XSlo, Bwhi, Bwlo, cvec2, xh, N, 512,
      nullptr, 0, 0, 0, 0);
  k_lstm<<<((N * 128) + 255) / 256, 256, 0, stream>>>(xh, out, N);
}

// Round 6
// 450.967 us; speedup vs baseline: 1.8759x; 1.1762x over previous
//
#include <hip/hip_runtime.h>
#include <math.h>

#define D_DIM 128
#define H_DIM 128
#define QKV_N 1664
#define SQRT_H_INV 0.08838834764831845f

typedef unsigned short u16;
typedef unsigned short ushort8v __attribute__((ext_vector_type(8)));
typedef __bf16 bf16x8 __attribute__((ext_vector_type(8)));
typedef float f32x4 __attribute__((ext_vector_type(4)));

__device__ __forceinline__ float grp16_sum(float v) {
  v += __shfl_xor(v, 1);
  v += __shfl_xor(v, 2);
  v += __shfl_xor(v, 4);
  v += __shfl_xor(v, 8);
  return v;
}

__device__ __forceinline__ void split_bf16(float x, u16& h, u16& l) {
  __bf16 hb = (__bf16)x;
  float rm = x - (float)hb;
  __bf16 lb = (__bf16)rm;
  h = __builtin_bit_cast(u16, hb);
  l = __builtin_bit_cast(u16, lb);
}

// ---------------------------------------------------------------------------
__global__ __launch_bounds__(128) void k_event(
    const float* __restrict__ ef, int EV,
    const float* __restrict__ w1, const float* __restrict__ b1,
    const float* __restrict__ g1, const float* __restrict__ bt1,
    const float* __restrict__ w2, const float* __restrict__ b2,
    const float* __restrict__ g2, const float* __restrict__ bt2,
    const float* __restrict__ ett, const int* __restrict__ etid,
    const float* __restrict__ inten, int K,
    float* __restrict__ e_out)
{
  __shared__ float sh[H_DIM];
  __shared__ float red[H_DIM];
  const int t = threadIdx.x;

  float acc = b1[t];
  for (int i = 0; i < EV; ++i) acc += ef[i] * w1[i * H_DIM + t];

  red[t] = acc; __syncthreads();
  for (int s = 64; s > 0; s >>= 1) { if (t < s) red[t] += red[t + s]; __syncthreads(); }
  float mu = red[0] / H_DIM; __syncthreads();
  float d = acc - mu;
  red[t] = d * d; __syncthreads();
  for (int s = 64; s > 0; s >>= 1) { if (t < s) red[t] += red[t + s]; __syncthreads(); }
  float var = red[0] / H_DIM; __syncthreads();
  float y = d * rsqrtf(var + 1e-5f) * g1[t] + bt1[t];
  y = fmaxf(y, 0.f);
  sh[t] = y; __syncthreads();

  float acc2 = b2[t];
  for (int i = 0; i < H_DIM; ++i) acc2 += sh[i] * w2[i * H_DIM + t];

  red[t] = acc2; __syncthreads();
  for (int s = 64; s > 0; s >>= 1) { if (t < s) red[t] += red[t + s]; __syncthreads(); }
  mu = red[0] / H_DIM; __syncthreads();
  d = acc2 - mu;
  red[t] = d * d; __syncthreads();
  for (int s = 64; s > 0; s >>= 1) { if (t < s) red[t] += red[t + s]; __syncthreads(); }
  var = red[0] / H_DIM; __syncthreads();
  float y2 = d * rsqrtf(var + 1e-5f) * g2[t] + bt2[t];
  y2 = fmaxf(y2, 0.f);

  float m = 0.f;
  for (int k = 0; k < K; ++k) m += ett[etid[k] * H_DIM + t] * inten[k];
  e_out[t] = y2 + m / (float)K;
}

// ---------------------------------------------------------------------------
__global__ __launch_bounds__(256) void k_cvec(
    const float* __restrict__ e,
    const float* __restrict__ wq, const float* __restrict__ bq,
    const float* __restrict__ wk, const float* __restrict__ bk,
    const float* __restrict__ wv, const float* __restrict__ bv,
    const float* __restrict__ wskip, const float* __restrict__ bskip,
    float* __restrict__ cvec)
{
  __shared__ float es[H_DIM];
  const int t = threadIdx.x;
  if (t < H_DIM) es[t] = e[t];
  __syncthreads();
  int j = blockIdx.x * 256 + t;
  if (j >= QKV_N) return;
  const float* W; const float* b; int col; int stride;
  if (j < 512)       { W = wq;    b = bq;    col = j;        stride = 512; }
  else if (j < 1024) { W = wk;    b = bk;    col = j - 512;  stride = 512; }
  else if (j < 1536) { W = wv;    b = bv;    col = j - 1024; stride = 512; }
  else               { W = wskip; b = bskip; col = j - 1536; stride = 128; }
  float a = b[col];
  for (int i = 0; i < H_DIM; ++i) a += es[i] * W[(D_DIM + i) * stride + col];
  cvec[j] = a;
}

__global__ __launch_bounds__(256) void k_pack(
    const float* __restrict__ wq, const float* __restrict__ wk,
    const float* __restrict__ wv, const float* __restrict__ wskip,
    float* __restrict__ B1)
{
  int idx = blockIdx.x * 256 + threadIdx.x;
  if (idx >= D_DIM * QKV_N) return;
  int i = idx / QKV_N, j = idx - i * QKV_N;
  float v;
  if (j < 512)       v = wq[i * 512 + j];
  else if (j < 1024) v = wk[i * 512 + (j - 512)];
  else if (j < 1536) v = wv[i * 512 + (j - 1024)];
  else               v = wskip[i * 128 + (j - 1536)];
  B1[idx] = v;
}

__global__ __launch_bounds__(256) void k_cvec2(
    const float* __restrict__ bih, const float* __restrict__ bhh,
    float* __restrict__ cvec2)
{
  int j = blockIdx.x * 256 + threadIdx.x;
  if (j < 512) cvec2[j] = bih[j] + bhh[j];
}

// ---------------------------------------------------------------------------
__global__ __launch_bounds__(256) void k_split_a(
    const float* __restrict__ A, const int* __restrict__ ids,
    u16* __restrict__ hi, u16* __restrict__ lo, int M, int Mpad)
{
  int idx = blockIdx.x * 256 + threadIdx.x;   // row*16 + g
  if (idx >= Mpad * 16) return;
  int row = idx >> 4, g = idx & 15;
  int gp = g ^ (row & 7);
  size_t dst = (size_t)row * 128 + gp * 8;
  if (row < M) {
    int ar = ids ? ids[row] : row;
    const float* srcp = A + (size_t)ar * 128 + g * 8;
#pragma unroll
    for (int j = 0; j < 8; ++j) {
      u16 h, l;
      split_bf16(srcp[j], h, l);
      hi[dst + j] = h; lo[dst + j] = l;
    }
  } else {
#pragma unroll
    for (int j = 0; j < 8; ++j) { hi[dst + j] = 0; lo[dst + j] = 0; }
  }
}

__global__ __launch_bounds__(256) void k_split_bt(
    const float* __restrict__ W,
    u16* __restrict__ hi, u16* __restrict__ lo, int Nc)
{
  int idx = blockIdx.x * 256 + threadIdx.x;  // n*16 + g
  if (idx >= Nc * 16) return;
  int n = idx >> 4, g = idx & 15;
  int gp = g ^ (n & 7);
  size_t dst = (size_t)n * 128 + gp * 8;
#pragma unroll
  for (int j = 0; j < 8; ++j) {
    u16 h, l;
    split_bf16(W[(size_t)(g * 8 + j) * Nc + n], h, l);
    hi[dst + j] = h; lo[dst + j] = l;
  }
}

// ---------------------------------------------------------------------------
// Split-bf16 MFMA GEMM, BK=64 two-phase, 64KB LDS (2 blocks/CU), with
// register prefetch of phase 1 overlapping phase-0 MFMAs (T14 async-stage).
// Epilogue optionally emits bf16 panel for cols [bf_lo,bf_hi); skipf32 drops
// the fp32 store in that range.
// ---------------------------------------------------------------------------
__global__ __launch_bounds__(256, 2) void mfma_gemm(
    const u16* __restrict__ Ahi, const u16* __restrict__ Alo,
    const u16* __restrict__ Bhi, const u16* __restrict__ Blo,
    const float* __restrict__ cvec, float* __restrict__ C, int M, int Nn,
    u16* __restrict__ bf_out, int bf_lo, int bf_hi, int bf_stride, int skipf32)
{
  __shared__ u16 lds[32768];   // 64 KB
  u16* As_hi = lds;            // [128 rows][64 u16]  (k-phase half)
  u16* As_lo = lds + 8192;
  u16* Bs_hi = lds + 16384;
  u16* Bs_lo = lds + 24576;

  const int t = threadIdx.x;
  const int bm = blockIdx.y * 128;
  const int bn = blockIdx.x * 128;
  const int lane = t & 63;
  const int wid = t >> 6;
  const int wr = wid >> 1, wc = wid & 1;
  const int abase = wr * 64 + (lane & 15);
  const int bbase = wc * 64 + (lane & 15);

  // staging map: chunk idx = i*256+t; row = idx>>3 (0..127), g = idx&7
  int srow[4], sg[4];
#pragma unroll
  for (int i = 0; i < 4; ++i) {
    int idx = i * 256 + t;
    srow[i] = idx >> 3;
    sg[i] = idx & 7;
  }

  ushort8v ra_h[4], ra_l[4], rb_h[4], rb_l[4];

  // load phase 0 (k granules 0..7 of each row)
#pragma unroll
  for (int i = 0; i < 4; ++i) {
    size_t ga = (size_t)(bm + srow[i]) * 128 + sg[i] * 8;
    size_t gb = (size_t)(bn + srow[i]) * 128 + sg[i] * 8;
    ra_h[i] = *(const ushort8v*)&Ahi[ga];
    ra_l[i] = *(const ushort8v*)&Alo[ga];
    rb_h[i] = *(const ushort8v*)&Bhi[gb];
    rb_l[i] = *(const ushort8v*)&Blo[gb];
  }
#pragma unroll
  for (int i = 0; i < 4; ++i) {
    int lo_ = srow[i] * 64 + sg[i] * 8;
    *(ushort8v*)&As_hi[lo_] = ra_h[i];
    *(ushort8v*)&As_lo[lo_] = ra_l[i];
    *(ushort8v*)&Bs_hi[lo_] = rb_h[i];
    *(ushort8v*)&Bs_lo[lo_] = rb_l[i];
  }
  __syncthreads();

  // issue phase-1 global loads (land under phase-0 MFMAs)
#pragma unroll
  for (int i = 0; i < 4; ++i) {
    size_t ga = (size_t)(bm + srow[i]) * 128 + 64 + sg[i] * 8;
    size_t gb = (size_t)(bn + srow[i]) * 128 + 64 + sg[i] * 8;
    ra_h[i] = *(const ushort8v*)&Ahi[ga];
    ra_l[i] = *(const ushort8v*)&Alo[ga];
    rb_h[i] = *(const ushort8v*)&Bhi[gb];
    rb_l[i] = *(const ushort8v*)&Blo[gb];
  }

  f32x4 acc[4][4];
  const f32x4 zero = {0.f, 0.f, 0.f, 0.f};
#pragma unroll
  for (int i = 0; i < 4; ++i)
#pragma unroll
    for (int j = 0; j < 4; ++j) acc[i][j] = zero;

  // compute phase 0: ks = 0,1
#pragma unroll
  for (int ks = 0; ks < 2; ++ks) {
    const int gl = (((ks & 1) << 2) + (lane >> 4)) ^ (lane & 7);
    bf16x8 ah[4], al[4], bh[4], bl[4];
#pragma unroll
    for (int i = 0; i < 4; ++i) {
      int ra = (abase + i * 16) * 64 + gl * 8;
      ah[i] = *(const bf16x8*)&As_hi[ra];
      al[i] = *(const bf16x8*)&As_lo[ra];
      int rb = (bbase + i * 16) * 64 + gl * 8;
      bh[i] = *(const bf16x8*)&Bs_hi[rb];
      bl[i] = *(const bf16x8*)&Bs_lo[rb];
    }
#pragma unroll
    for (int i = 0; i < 4; ++i)
#pragma unroll
      for (int j = 0; j < 4; ++j) {
        acc[i][j] = __builtin_amdgcn_mfma_f32_16x16x32_bf16(ah[i], bh[j], acc[i][j], 0, 0, 0);
        acc[i][j] = __builtin_amdgcn_mfma_f32_16x16x32_bf16(ah[i], bl[j], acc[i][j], 0, 0, 0);
        acc[i][j] = __builtin_amdgcn_mfma_f32_16x16x32_bf16(al[i], bh[j], acc[i][j], 0, 0, 0);
      }
  }
  __syncthreads();

  // write phase 1 to LDS
#pragma unroll
  for (int i = 0; i < 4; ++i) {
    int lo_ = srow[i] * 64 + sg[i] * 8;
    *(ushort8v*)&As_hi[lo_] = ra_h[i];
    *(ushort8v*)&As_lo[lo_] = ra_l[i];
    *(ushort8v*)&Bs_hi[lo_] = rb_h[i];
    *(ushort8v*)&Bs_lo[lo_] = rb_l[i];
  }
  __syncthreads();

  // compute phase 1: ks = 2,3
#pragma unroll
  for (int ks = 2; ks < 4; ++ks) {
    const int gl = (((ks & 1) << 2) + (lane >> 4)) ^ (lane & 7);
    bf16x8 ah[4], al[4], bh[4], bl[4];
#pragma unroll
    for (int i = 0; i < 4; ++i) {
      int ra = (abase + i * 16) * 64 + gl * 8;
      ah[i] = *(const bf16x8*)&As_hi[ra];
      al[i] = *(const bf16x8*)&As_lo[ra];
      int rb = (bbase + i * 16) * 64 + gl * 8;
      bh[i] = *(const bf16x8*)&Bs_hi[rb];
      bl[i] = *(const bf16x8*)&Bs_lo[rb];
    }
#pragma unroll
    for (int i = 0; i < 4; ++i)
#pragma unroll
      for (int j = 0; j < 4; ++j) {
        acc[i][j] = __builtin_amdgcn_mfma_f32_16x16x32_bf16(ah[i], bh[j], acc[i][j], 0, 0, 0);
        acc[i][j] = __builtin_amdgcn_mfma_f32_16x16x32_bf16(ah[i], bl[j], acc[i][j], 0, 0, 0);
        acc[i][j] = __builtin_amdgcn_mfma_f32_16x16x32_bf16(al[i], bh[j], acc[i][j], 0, 0, 0);
      }
  }

  const int rq = (lane >> 4) << 2;
  const int cq = lane & 15;
#pragma unroll
  for (int j = 0; j < 4; ++j) {
    int col = bn + wc * 64 + j * 16 + cq;
    float cv = cvec ? cvec[col] : 0.f;
    bool inbf = bf_out && col >= bf_lo && col < bf_hi;
    bool wf32 = !(inbf && skipf32);
#pragma unroll
    for (int i = 0; i < 4; ++i) {
#pragma unroll
      for (int r = 0; r < 4; ++r) {
        int row = bm + wr * 64 + i * 16 + rq + r;
        if (row < M) {
          float val = acc[i][j][r] + cv;
          if (wf32) C[(size_t)row * Nn + col] = val;
          if (inbf) bf_out[(size_t)row * bf_stride + (col - bf_lo)] =
              __builtin_bit_cast(u16, (__bf16)val);
        }
      }
    }
  }
}

// ---------------------------------------------------------------------------
__global__ __launch_bounds__(256) void k_zero(int* __restrict__ p, int n) {
  int i = blockIdx.x * 256 + threadIdx.x;
  if (i < n) p[i] = 0;
}
__global__ __launch_bounds__(256) void k_count(
    const int* __restrict__ dst, int* __restrict__ counts, int E) {
  int e = blockIdx.x * 256 + threadIdx.x;
  if (e < E) atomicAdd(&counts[dst[e]], 1);
}
__global__ __launch_bounds__(1024) void k_scan(
    const int* __restrict__ counts, int* __restrict__ offs,
    int* __restrict__ cursor, int N)
{
  __shared__ int wsum[16];
  const int t = threadIdx.x;
  const int lane = t & 63;
  const int wid = t >> 6;
  int running = 0;
  for (int base = 0; base < N; base += 1024) {
    int v = (base + t < N) ? counts[base + t] : 0;
    int incl = v;
#pragma unroll
    for (int s = 1; s < 64; s <<= 1) {
      int u = __shfl_up(incl, s);
      if (lane >= s) incl += u;
    }
    if (lane == 63) wsum[wid] = incl;
    __syncthreads();
    if (wid == 0) {
      int w = (lane < 16) ? wsum[lane] : 0;
#pragma unroll
      for (int s = 1; s < 16; s <<= 1) {
        int u = __shfl_up(w, s);
        if (lane >= s) w += u;
      }
      if (lane < 16) wsum[lane] = w;
    }
    __syncthreads();
    int wpre = (wid > 0) ? wsum[wid - 1] : 0;
    int tot = wsum[15];
    int inclg = incl + wpre;
    if (base + t < N) {
      offs[base + t + 1] = running + inclg;
      cursor[base + t] = running + inclg - v;
    }
    running += tot;
    __syncthreads();
  }
  if (t == 0) offs[0] = 0;
}
__global__ __launch_bounds__(256) void k_fill(
    const int* __restrict__ src, const int* __restrict__ dst,
    int* __restrict__ cursor, int* __restrict__ csr_src, int E) {
  int e = blockIdx.x * 256 + threadIdx.x;
  if (e < E) {
    int slot = atomicAdd(&cursor[dst[e]], 1);
    csr_src[slot] = src[e];
  }
}

// ---------------------------------------------------------------------------
// TransformerConv aggregation, ONLINE softmax. One wave per node.
// Q (cols 0..511) and skip (cols 1536..1663) from fp32 C1 (stride 1664);
// K/V gathered from bf16 panel KV[N][1024].
// ---------------------------------------------------------------------------
__global__ __launch_bounds__(256) void k_tconv(
    const float* __restrict__ C1, const u16* __restrict__ KV,
    const int* __restrict__ offs, const int* __restrict__ csr_src,
    u16* __restrict__ Xhi, u16* __restrict__ Xlo, int N)
{
  const int wid = threadIdx.x >> 6;
  const int lane = threadIdx.x & 63;
  const int node = blockIdx.x * 4 + wid;
  if (node >= N) {
    if (lane < 16) {
      size_t dst = (size_t)node * 128 + (size_t)((lane ^ (node & 7)) * 8);
#pragma unroll
      for (int j = 0; j < 8; ++j) { Xhi[dst + j] = 0; Xlo[dst + j] = 0; }
    }
    return;
  }
  const float* crow = C1 + (size_t)node * QKV_N;
  float q[8];
  {
    float4 q0 = *(const float4*)(crow + lane * 8);
    float4 q1 = *(const float4*)(crow + lane * 8 + 4);
    q[0]=q0.x; q[1]=q0.y; q[2]=q0.z; q[3]=q0.w;
    q[4]=q1.x; q[5]=q1.y; q[6]=q1.z; q[7]=q1.w;
  }
  const int beg = offs[node], end = offs[node + 1];
  float mx = -1e30f;
  float ssum = 0.f;
  float acc[8] = {0.f,0.f,0.f,0.f,0.f,0.f,0.f,0.f};

  int e = beg;
  for (; e + 2 <= end; e += 2) {
    int s0 = csr_src[e];
    int s1 = csr_src[e + 1];
    const u16* r0 = KV + (size_t)s0 * 1024 + lane * 8;
    const u16* r1 = KV + (size_t)s1 * 1024 + lane * 8;
    bf16x8 ka = *(const bf16x8*)(r0);
    bf16x8 kb = *(const bf16x8*)(r1);
    bf16x8 va = *(const bf16x8*)(r0 + 512);
    bf16x8 vb = *(const bf16x8*)(r1 + 512);
    float p0 = 0.f, p1 = 0.f;
#pragma unroll
    for (int j = 0; j < 8; ++j) {
      p0 += q[j] * (float)ka[j];
      p1 += q[j] * (float)kb[j];
    }
    p0 = grp16_sum(p0) * SQRT_H_INV;
    p1 = grp16_sum(p1) * SQRT_H_INV;
    float nm = fmaxf(mx, fmaxf(p0, p1));
    float sc = expf(mx - nm);
    float w0 = expf(p0 - nm);
    float w1 = expf(p1 - nm);
    ssum = ssum * sc + w0 + w1;
#pragma unroll
    for (int j = 0; j < 8; ++j)
      acc[j] = acc[j] * sc + w0 * (float)va[j] + w1 * (float)vb[j];
    mx = nm;
  }
  if (e < end) {
    int s0 = csr_src[e];
    const u16* r0 = KV + (size_t)s0 * 1024 + lane * 8;
    bf16x8 ka = *(const bf16x8*)(r0);
    bf16x8 va = *(const bf16x8*)(r0 + 512);
    float p0 = 0.f;
#pragma unroll
    for (int j = 0; j < 8; ++j) p0 += q[j] * (float)ka[j];
    p0 = grp16_sum(p0) * SQRT_H_INV;
    float nm = fmaxf(mx, p0);
    float sc = expf(mx - nm);
    float w0 = expf(p0 - nm);
    ssum = ssum * sc + w0;
#pragma unroll
    for (int j = 0; j < 8; ++j)
      acc[j] = acc[j] * sc + w0 * (float)va[j];
  }

  float inv = 1.f / (ssum + 1e-16f);
#pragma unroll
  for (int j = 0; j < 8; ++j) acc[j] *= inv;
#pragma unroll
  for (int j = 0; j < 8; ++j) {
    acc[j] += __shfl_xor(acc[j], 16);
    acc[j] += __shfl_xor(acc[j], 32);
  }
  if (lane < 16) {
    const float* sk = crow + 1536 + lane * 8;
    size_t dst = (size_t)node * 128 + (size_t)((lane ^ (node & 7)) * 8);
#pragma unroll
    for (int j = 0; j < 8; ++j) {
      float x = 0.25f * acc[j] + sk[j];
      u16 h, l;
      split_bf16(x, h, l);
      Xhi[dst + j] = h; Xlo[dst + j] = l;
    }
  }
}

// ---------------------------------------------------------------------------
__global__ __launch_bounds__(256) void k_gat_ad(
    const float* __restrict__ xh, const float* __restrict__ as_w,
    const float* __restrict__ ad_w, float* __restrict__ a_s,
    float* __restrict__ a_d, int N)
{
  const int wid = threadIdx.x >> 6;
  const int lane = threadIdx.x & 63;
  const int node = blockIdx.x * 4 + wid;
  if (node >= N) return;
  const int head = lane >> 4;
  const int c0 = (lane & 15) * 8;
  const float* xr = xh + (size_t)node * 512 + lane * 8;
  float4 x0 = *(const float4*)(xr);
  float4 x1_ = *(const float4*)(xr + 4);
  const float* aw = as_w + head * 128 + c0;
  const float* dw = ad_w + head * 128 + c0;
  float s1 = x0.x*aw[0] + x0.y*aw[1] + x0.z*aw[2] + x0.w*aw[3]
           + x1_.x*aw[4] + x1_.y*aw[5] + x1_.z*aw[6] + x1_.w*aw[7];
  float s2 = x0.x*dw[0] + x0.y*dw[1] + x0.z*dw[2] + x0.w*dw[3]
           + x1_.x*dw[4] + x1_.y*dw[5] + x1_.z*dw[6] + x1_.w*dw[7];
  s1 = grp16_sum(s1);
  s2 = grp16_sum(s2);
  if ((lane & 15) == 0) {
    a_s[node * 4 + head] = s1;
    a_d[node * 4 + head] = s2;
  }
}

// ---------------------------------------------------------------------------
// GAT aggregation, ONLINE softmax; self from fp32 xh, neighbors from bf16
// panel xhb[N][512]; writes split hi/lo bf16 for next GEMM.
// ---------------------------------------------------------------------------
__global__ __launch_bounds__(256) void k_gat_agg(
    const float* __restrict__ xh, const u16* __restrict__ xhb,
    const float* __restrict__ a_s, const float* __restrict__ a_d,
    const int* __restrict__ offs, const int* __restrict__ csr_src,
    const float* __restrict__ bias,
    u16* __restrict__ Xhi, u16* __restrict__ Xlo, int N)
{
  const int wid = threadIdx.x >> 6;
  const int lane = threadIdx.x & 63;
  const int node = blockIdx.x * 4 + wid;
  if (node >= N) {
    if (lane < 16) {
      size_t dst = (size_t)node * 128 + (size_t)((lane ^ (node & 7)) * 8);
#pragma unroll
      for (int j = 0; j < 8; ++j) { Xhi[dst + j] = 0; Xlo[dst + j] = 0; }
    }
    return;
  }
  const int head = lane >> 4;
  const float adn = a_d[node * 4 + head];
  const float asn = a_s[node * 4 + head];
  float lself = asn + adn;
  lself = lself >= 0.f ? lself : 0.2f * lself;

  float mx = lself;
  float ssum = 1.f;
  float acc[8];
  {
    const float* xr = xh + (size_t)node * 512 + lane * 8;
    float4 x0 = *(const float4*)(xr);
    float4 x1_ = *(const float4*)(xr + 4);
    acc[0]=x0.x; acc[1]=x0.y; acc[2]=x0.z; acc[3]=x0.w;
    acc[4]=x1_.x; acc[5]=x1_.y; acc[6]=x1_.z; acc[7]=x1_.w;
  }

  const int beg = offs[node], end = offs[node + 1];
  int e = beg;
  for (; e + 2 <= end; e += 2) {
    int s0 = csr_src[e];
    int s1 = csr_src[e + 1];
    float l0 = a_s[s0 * 4 + head] + adn;
    float l1 = a_s[s1 * 4 + head] + adn;
    l0 = l0 >= 0.f ? l0 : 0.2f * l0;
    l1 = l1 >= 0.f ? l1 : 0.2f * l1;
    const u16* r0 = xhb + (size_t)s0 * 512 + lane * 8;
    const u16* r1 = xhb + (size_t)s1 * 512 + lane * 8;
    bf16x8 xa = *(const bf16x8*)(r0);
    bf16x8 xb = *(const bf16x8*)(r1);
    float nm = fmaxf(mx, fmaxf(l0, l1));
    float sc = expf(mx - nm);
    float w0 = expf(l0 - nm);
    float w1 = expf(l1 - nm);
    ssum = ssum * sc + w0 + w1;
#pragma unroll
    for (int j = 0; j < 8; ++j)
      acc[j] = acc[j] * sc + w0 * (float)xa[j] + w1 * (float)xb[j];
    mx = nm;
  }
  if (e < end) {
    int s0 = csr_src[e];
    float l0 = a_s[s0 * 4 + head] + adn;
    l0 = l0 >= 0.f ? l0 : 0.2f * l0;
    const u16* r0 = xhb + (size_t)s0 * 512 + lane * 8;
    bf16x8 xa = *(const bf16x8*)(r0);
    float nm = fmaxf(mx, l0);
    float sc = expf(mx - nm);
    float w0 = expf(l0 - nm);
    ssum = ssum * sc + w0;
#pragma unroll
    for (int j = 0; j < 8; ++j)
      acc[j] = acc[j] * sc + w0 * (float)xa[j];
  }

  float inv = 1.f / (ssum + 1e-16f);
#pragma unroll
  for (int j = 0; j < 8; ++j) acc[j] *= inv;
#pragma unroll
  for (int j = 0; j < 8; ++j) {
    acc[j] += __shfl_xor(acc[j], 16);
    acc[j] += __shfl_xor(acc[j], 32);
  }
  if (lane < 16) {
    const float* b = bias + lane * 8;
    size_t dst = (size_t)node * 128 + (size_t)((lane ^ (node & 7)) * 8);
#pragma unroll
    for (int j = 0; j < 8; ++j) {
      float x = fmaxf(0.25f * acc[j] + b[j], 0.f);
      u16 h, l;
      split_bf16(x, h, l);
      Xhi[dst + j] = h; Xlo[dst + j] = l;
    }
  }
}

// ---------------------------------------------------------------------------
__global__ __launch_bounds__(256) void k_lstm(
    const float* __restrict__ gates, float* __restrict__ out, int N)
{
  int idx = blockIdx.x * 256 + threadIdx.x;
  if (idx >= N * 128) return;
  int n = idx >> 7, c = idx & 127;
  const float* g = gates + (size_t)n * 512;
  float gi = g[c], gg = g[256 + c], go = g[384 + c];
  float cv = (1.f / (1.f + expf(-gi))) * tanhf(gg);
  float hv = (1.f / (1.f + expf(-go))) * tanhf(cv);
  out[idx] = hv;
  out[(size_t)N * 128 + idx] = cv;
}

// ---------------------------------------------------------------------------
extern "C" void kernel_launch(void* const* d_in, const int* in_sizes, int n_in,
                              void* d_out, int out_size, void* d_ws, size_t ws_size,
                              hipStream_t stream) {
  const int*   node_ids = (const int*)d_in[0];
  const int*   etid     = (const int*)d_in[1];
  const int*   src      = (const int*)d_in[2];
  const int*   dst      = (const int*)d_in[3];
  const float* ef       = (const float*)d_in[4];
  const float* inten    = (const float*)d_in[5];
  const float* nemb     = (const float*)d_in[6];
  const float* ett      = (const float*)d_in[7];
  const float* ev_w1 = (const float*)d_in[8],  *ev_b1 = (const float*)d_in[9];
  const float* ev_g1 = (const float*)d_in[10], *ev_bt1 = (const float*)d_in[11];
  const float* ev_w2 = (const float*)d_in[12], *ev_b2 = (const float*)d_in[13];
  const float* ev_g2 = (const float*)d_in[14], *ev_bt2 = (const float*)d_in[15];
  const float* wq = (const float*)d_in[16], *bq = (const float*)d_in[17];
  const float* wk = (const float*)d_in[18], *bk = (const float*)d_in[19];
  const float* wv = (const float*)d_in[20], *bv = (const float*)d_in[21];
  const float* wskip = (const float*)d_in[22], *bskip = (const float*)d_in[23];
  const float* g0_w = (const float*)d_in[24], *g0_as = (const float*)d_in[25];
  const float* g0_ad = (const float*)d_in[26], *g0_b = (const float*)d_in[27];
  const float* g1_w = (const float*)d_in[28], *g1_as = (const float*)d_in[29];
  const float* g1_ad = (const float*)d_in[30], *g1_b = (const float*)d_in[31];
  const float* wih = (const float*)d_in[32];
  const float* bih = (const float*)d_in[34], *bhh = (const float*)d_in[35];

  const int N = in_sizes[0];
  const int K = in_sizes[1];
  const int E = in_sizes[2];
  const int EV = in_sizes[4];

  const int gridMy = (N + 127) / 128;
  const int Npad = gridMy * 128;

  float* ws = (float*)d_ws;
  size_t o = 0;
  float* e_vec = ws + o; o += 128;
  float* cvec1 = ws + o; o += QKV_N;
  float* cvec2 = ws + o; o += 512;
  float* B1    = ws + o; o += (size_t)128 * QKV_N;
  float* C1    = ws + o; o += (size_t)N * QKV_N;
  float* xh    = ws + o; o += (size_t)N * 512;
  u16* Ahi  = (u16*)(ws + o); o += (size_t)Npad * 64;
  u16* Alo  = (u16*)(ws + o); o += (size_t)Npad * 64;
  u16* XShi = (u16*)(ws + o); o += (size_t)Npad * 64;
  u16* XSlo = (u16*)(ws + o); o += (size_t)Npad * 64;
  u16* Bqhi = (u16*)(ws + o); o += (size_t)QKV_N * 64;
  u16* Bqlo = (u16*)(ws + o); o += (size_t)QKV_N * 64;
  u16* Bg0hi = (u16*)(ws + o); o += 512 * 64;
  u16* Bg0lo = (u16*)(ws + o); o += 512 * 64;
  u16* Bg1hi = (u16*)(ws + o); o += 512 * 64;
  u16* Bg1lo = (u16*)(ws + o); o += 512 * 64;
  u16* Bwhi  = (u16*)(ws + o); o += 512 * 64;
  u16* Bwlo  = (u16*)(ws + o); o += 512 * 64;
  u16* KV   = (u16*)(ws + o); o += (size_t)Npad * 512;  // [N][1024] u16
  u16* xhb  = (u16*)(ws + o); o += (size_t)Npad * 256;  // [N][512] u16
  float* a_s   = ws + o; o += (size_t)N * 4;
  float* a_d   = ws + o; o += (size_t)N * 4;
  int* counts  = (int*)(ws + o); o += N;
  int* offs    = (int*)(ws + o); o += (size_t)N + 1;
  int* cursor  = (int*)(ws + o); o += N;
  int* csr_src = (int*)(ws + o); o += E;

  float* out = (float*)d_out;

  const int nodeBlocks = (N + 3) / 4;
  const int nodeBlocksPad = Npad / 4;

  k_event<<<1, 128, 0, stream>>>(ef, EV, ev_w1, ev_b1, ev_g1, ev_bt1,
                                 ev_w2, ev_b2, ev_g2, ev_bt2,
                                 ett, etid, inten, K, e_vec);
  k_cvec<<<(QKV_N + 255) / 256, 256, 0, stream>>>(e_vec, wq, bq, wk, bk, wv, bv,
                                                  wskip, bskip, cvec1);
  k_pack<<<(D_DIM * QKV_N + 255) / 256, 256, 0, stream>>>(wq, wk, wv, wskip, B1);
  k_cvec2<<<2, 256, 0, stream>>>(bih, bhh, cvec2);

  k_split_a<<<(Npad * 16 + 255) / 256, 256, 0, stream>>>(nemb, node_ids, Ahi, Alo, N, Npad);
  k_split_bt<<<(QKV_N * 16 + 255) / 256, 256, 0, stream>>>(B1, Bqhi, Bqlo, QKV_N);
  k_split_bt<<<(512 * 16 + 255) / 256, 256, 0, stream>>>(g0_w, Bg0hi, Bg0lo, 512);
  k_split_bt<<<(512 * 16 + 255) / 256, 256, 0, stream>>>(g1_w, Bg1hi, Bg1lo, 512);
  k_split_bt<<<(512 * 16 + 255) / 256, 256, 0, stream>>>(wih, Bwhi, Bwlo, 512);

  k_zero<<<(N + 255) / 256, 256, 0, stream>>>(counts, N);
  k_count<<<(E + 255) / 256, 256, 0, stream>>>(dst, counts, E);
  k_scan<<<1, 1024, 0, stream>>>(counts, offs, cursor, N);
  k_fill<<<(E + 255) / 256, 256, 0, stream>>>(src, dst, cursor, csr_src, E);

  // QKV: fp32 q/skip -> C1 (K/V cols skipped); bf16 K/V -> KV panel
  mfma_gemm<<<dim3(QKV_N / 128, gridMy), 256, 0, stream>>>(
      Ahi, Alo, Bqhi, Bqlo, cvec1, C1, N, QKV_N,
      KV, 512, 1536, 1024, 1);

  k_tconv<<<nodeBlocksPad, 256, 0, stream>>>(C1, KV, offs, csr_src, XShi, XSlo, N);

  // GAT layer 1: fp32 xh + bf16 xhb
  mfma_gemm<<<dim3(4, gridMy), 256, 0, stream>>>(
      XShi, XSlo, Bg0hi, Bg0lo, nullptr, xh, N, 512,
      xhb, 0, 512, 512, 0);
  k_gat_ad<<<nodeBlocks, 256, 0, stream>>>(xh, g0_as, g0_ad, a_s, a_d, N);
  k_gat_agg<<<nodeBlocksPad, 256, 0, stream>>>(xh, xhb, a_s, a_d, offs, csr_src,
                                               g0_b, XShi, XSlo, N);

  // GAT layer 2
  mfma_gemm<<<dim3(4, gridMy), 256, 0, stream>>>(
      XShi, XSlo, Bg1hi, Bg1lo, nullptr, xh, N, 512,
      xhb, 0, 512, 512, 0);
  k_gat_ad<<<nodeBlocks, 256, 0, stream>>>(xh, g1_as, g1_ad, a_s, a_d, N);
  k_gat_agg<<<nodeBlocksPad, 256, 0, stream>>>(xh, xhb, a_s, a_d, offs, csr_src,
                                               g1_b, XShi, XSlo, N);

  // LSTM
  mfma_gemm<<<dim3(4, gridMy), 256, 0, stream>>>(
      XShi, XSlo, Bwhi, Bwlo, cvec2, xh, N, 512,
      nullptr, 0, 0, 0, 0);
  k_lstm<<<((N * 128) + 255) / 256, 256, 0, stream>>>(xh, out, N);
}

// Round 7
// 447.110 us; speedup vs baseline: 1.8920x; 1.0086x over previous
//
#include <hip/hip_runtime.h>
#include <math.h>

#define D_DIM 128
#define H_DIM 128
#define QKV_N 1664
#define SQRT_H_INV 0.08838834764831845f

typedef unsigned short u16;
typedef unsigned short ushort8v __attribute__((ext_vector_type(8)));
typedef __bf16 bf16x8 __attribute__((ext_vector_type(8)));
typedef float f32x4 __attribute__((ext_vector_type(4)));

__device__ __forceinline__ float grp16_sum(float v) {
  v += __shfl_xor(v, 1);
  v += __shfl_xor(v, 2);
  v += __shfl_xor(v, 4);
  v += __shfl_xor(v, 8);
  return v;
}

__device__ __forceinline__ void split_bf16(float x, u16& h, u16& l) {
  __bf16 hb = (__bf16)x;
  float rm = x - (float)hb;
  __bf16 lb = (__bf16)rm;
  h = __builtin_bit_cast(u16, hb);
  l = __builtin_bit_cast(u16, lb);
}

// ---------------------------------------------------------------------------
__global__ __launch_bounds__(128) void k_event(
    const float* __restrict__ ef, int EV,
    const float* __restrict__ w1, const float* __restrict__ b1,
    const float* __restrict__ g1, const float* __restrict__ bt1,
    const float* __restrict__ w2, const float* __restrict__ b2,
    const float* __restrict__ g2, const float* __restrict__ bt2,
    const float* __restrict__ ett, const int* __restrict__ etid,
    const float* __restrict__ inten, int K,
    float* __restrict__ e_out)
{
  __shared__ float sh[H_DIM];
  __shared__ float red[H_DIM];
  const int t = threadIdx.x;

  float acc = b1[t];
  for (int i = 0; i < EV; ++i) acc += ef[i] * w1[i * H_DIM + t];

  red[t] = acc; __syncthreads();
  for (int s = 64; s > 0; s >>= 1) { if (t < s) red[t] += red[t + s]; __syncthreads(); }
  float mu = red[0] / H_DIM; __syncthreads();
  float d = acc - mu;
  red[t] = d * d; __syncthreads();
  for (int s = 64; s > 0; s >>= 1) { if (t < s) red[t] += red[t + s]; __syncthreads(); }
  float var = red[0] / H_DIM; __syncthreads();
  float y = d * rsqrtf(var + 1e-5f) * g1[t] + bt1[t];
  y = fmaxf(y, 0.f);
  sh[t] = y; __syncthreads();

  float acc2 = b2[t];
  for (int i = 0; i < H_DIM; ++i) acc2 += sh[i] * w2[i * H_DIM + t];

  red[t] = acc2; __syncthreads();
  for (int s = 64; s > 0; s >>= 1) { if (t < s) red[t] += red[t + s]; __syncthreads(); }
  mu = red[0] / H_DIM; __syncthreads();
  d = acc2 - mu;
  red[t] = d * d; __syncthreads();
  for (int s = 64; s > 0; s >>= 1) { if (t < s) red[t] += red[t + s]; __syncthreads(); }
  var = red[0] / H_DIM; __syncthreads();
  float y2 = d * rsqrtf(var + 1e-5f) * g2[t] + bt2[t];
  y2 = fmaxf(y2, 0.f);

  float m = 0.f;
  for (int k = 0; k < K; ++k) m += ett[etid[k] * H_DIM + t] * inten[k];
  e_out[t] = y2 + m / (float)K;
}

// ---------------------------------------------------------------------------
__global__ __launch_bounds__(256) void k_cvec(
    const float* __restrict__ e,
    const float* __restrict__ wq, const float* __restrict__ bq,
    const float* __restrict__ wk, const float* __restrict__ bk,
    const float* __restrict__ wv, const float* __restrict__ bv,
    const float* __restrict__ wskip, const float* __restrict__ bskip,
    float* __restrict__ cvec)
{
  __shared__ float es[H_DIM];
  const int t = threadIdx.x;
  if (t < H_DIM) es[t] = e[t];
  __syncthreads();
  int j = blockIdx.x * 256 + t;
  if (j >= QKV_N) return;
  const float* W; const float* b; int col; int stride;
  if (j < 512)       { W = wq;    b = bq;    col = j;        stride = 512; }
  else if (j < 1024) { W = wk;    b = bk;    col = j - 512;  stride = 512; }
  else if (j < 1536) { W = wv;    b = bv;    col = j - 1024; stride = 512; }
  else               { W = wskip; b = bskip; col = j - 1536; stride = 128; }
  float a = b[col];
  for (int i = 0; i < H_DIM; ++i) a += es[i] * W[(D_DIM + i) * stride + col];
  cvec[j] = a;
}

__global__ __launch_bounds__(256) void k_pack(
    const float* __restrict__ wq, const float* __restrict__ wk,
    const float* __restrict__ wv, const float* __restrict__ wskip,
    float* __restrict__ B1)
{
  int idx = blockIdx.x * 256 + threadIdx.x;
  if (idx >= D_DIM * QKV_N) return;
  int i = idx / QKV_N, j = idx - i * QKV_N;
  float v;
  if (j < 512)       v = wq[i * 512 + j];
  else if (j < 1024) v = wk[i * 512 + (j - 512)];
  else if (j < 1536) v = wv[i * 512 + (j - 1024)];
  else               v = wskip[i * 128 + (j - 1536)];
  B1[idx] = v;
}

__global__ __launch_bounds__(256) void k_cvec2(
    const float* __restrict__ bih, const float* __restrict__ bhh,
    float* __restrict__ cvec2)
{
  int j = blockIdx.x * 256 + threadIdx.x;
  if (j < 512) cvec2[j] = bih[j] + bhh[j];
}

// ---------------------------------------------------------------------------
__global__ __launch_bounds__(256) void k_split_a(
    const float* __restrict__ A, const int* __restrict__ ids,
    u16* __restrict__ hi, u16* __restrict__ lo, int M, int Mpad)
{
  int idx = blockIdx.x * 256 + threadIdx.x;   // row*16 + g
  if (idx >= Mpad * 16) return;
  int row = idx >> 4, g = idx & 15;
  int gp = g ^ (row & 7);
  size_t dst = (size_t)row * 128 + gp * 8;
  if (row < M) {
    int ar = ids ? ids[row] : row;
    const float* srcp = A + (size_t)ar * 128 + g * 8;
#pragma unroll
    for (int j = 0; j < 8; ++j) {
      u16 h, l;
      split_bf16(srcp[j], h, l);
      hi[dst + j] = h; lo[dst + j] = l;
    }
  } else {
#pragma unroll
    for (int j = 0; j < 8; ++j) { hi[dst + j] = 0; lo[dst + j] = 0; }
  }
}

__global__ __launch_bounds__(256) void k_split_bt(
    const float* __restrict__ W,
    u16* __restrict__ hi, u16* __restrict__ lo, int Nc)
{
  int idx = blockIdx.x * 256 + threadIdx.x;  // n*16 + g
  if (idx >= Nc * 16) return;
  int n = idx >> 4, g = idx & 15;
  int gp = g ^ (n & 7);
  size_t dst = (size_t)n * 128 + gp * 8;
#pragma unroll
  for (int j = 0; j < 8; ++j) {
    u16 h, l;
    split_bf16(W[(size_t)(g * 8 + j) * Nc + n], h, l);
    hi[dst + j] = h; lo[dst + j] = l;
  }
}

// ---------------------------------------------------------------------------
// Split-bf16 MFMA GEMM, BK=64 two-phase, 64KB LDS (2 blocks/CU), with
// register prefetch of phase 1 overlapping phase-0 MFMAs.
// ---------------------------------------------------------------------------
__global__ __launch_bounds__(256, 2) void mfma_gemm(
    const u16* __restrict__ Ahi, const u16* __restrict__ Alo,
    const u16* __restrict__ Bhi, const u16* __restrict__ Blo,
    const float* __restrict__ cvec, float* __restrict__ C, int M, int Nn,
    u16* __restrict__ bf_out, int bf_lo, int bf_hi, int bf_stride, int skipf32)
{
  __shared__ u16 lds[32768];   // 64 KB
  u16* As_hi = lds;
  u16* As_lo = lds + 8192;
  u16* Bs_hi = lds + 16384;
  u16* Bs_lo = lds + 24576;

  const int t = threadIdx.x;
  const int bm = blockIdx.y * 128;
  const int bn = blockIdx.x * 128;
  const int lane = t & 63;
  const int wid = t >> 6;
  const int wr = wid >> 1, wc = wid & 1;
  const int abase = wr * 64 + (lane & 15);
  const int bbase = wc * 64 + (lane & 15);

  int srow[4], sg[4];
#pragma unroll
  for (int i = 0; i < 4; ++i) {
    int idx = i * 256 + t;
    srow[i] = idx >> 3;
    sg[i] = idx & 7;
  }

  ushort8v ra_h[4], ra_l[4], rb_h[4], rb_l[4];

#pragma unroll
  for (int i = 0; i < 4; ++i) {
    size_t ga = (size_t)(bm + srow[i]) * 128 + sg[i] * 8;
    size_t gb = (size_t)(bn + srow[i]) * 128 + sg[i] * 8;
    ra_h[i] = *(const ushort8v*)&Ahi[ga];
    ra_l[i] = *(const ushort8v*)&Alo[ga];
    rb_h[i] = *(const ushort8v*)&Bhi[gb];
    rb_l[i] = *(const ushort8v*)&Blo[gb];
  }
#pragma unroll
  for (int i = 0; i < 4; ++i) {
    int lo_ = srow[i] * 64 + sg[i] * 8;
    *(ushort8v*)&As_hi[lo_] = ra_h[i];
    *(ushort8v*)&As_lo[lo_] = ra_l[i];
    *(ushort8v*)&Bs_hi[lo_] = rb_h[i];
    *(ushort8v*)&Bs_lo[lo_] = rb_l[i];
  }
  __syncthreads();

#pragma unroll
  for (int i = 0; i < 4; ++i) {
    size_t ga = (size_t)(bm + srow[i]) * 128 + 64 + sg[i] * 8;
    size_t gb = (size_t)(bn + srow[i]) * 128 + 64 + sg[i] * 8;
    ra_h[i] = *(const ushort8v*)&Ahi[ga];
    ra_l[i] = *(const ushort8v*)&Alo[ga];
    rb_h[i] = *(const ushort8v*)&Bhi[gb];
    rb_l[i] = *(const ushort8v*)&Blo[gb];
  }

  f32x4 acc[4][4];
  const f32x4 zero = {0.f, 0.f, 0.f, 0.f};
#pragma unroll
  for (int i = 0; i < 4; ++i)
#pragma unroll
    for (int j = 0; j < 4; ++j) acc[i][j] = zero;

#pragma unroll
  for (int ks = 0; ks < 2; ++ks) {
    const int gl = (((ks & 1) << 2) + (lane >> 4)) ^ (lane & 7);
    bf16x8 ah[4], al[4], bh[4], bl[4];
#pragma unroll
    for (int i = 0; i < 4; ++i) {
      int ra = (abase + i * 16) * 64 + gl * 8;
      ah[i] = *(const bf16x8*)&As_hi[ra];
      al[i] = *(const bf16x8*)&As_lo[ra];
      int rb = (bbase + i * 16) * 64 + gl * 8;
      bh[i] = *(const bf16x8*)&Bs_hi[rb];
      bl[i] = *(const bf16x8*)&Bs_lo[rb];
    }
#pragma unroll
    for (int i = 0; i < 4; ++i)
#pragma unroll
      for (int j = 0; j < 4; ++j) {
        acc[i][j] = __builtin_amdgcn_mfma_f32_16x16x32_bf16(ah[i], bh[j], acc[i][j], 0, 0, 0);
        acc[i][j] = __builtin_amdgcn_mfma_f32_16x16x32_bf16(ah[i], bl[j], acc[i][j], 0, 0, 0);
        acc[i][j] = __builtin_amdgcn_mfma_f32_16x16x32_bf16(al[i], bh[j], acc[i][j], 0, 0, 0);
      }
  }
  __syncthreads();

#pragma unroll
  for (int i = 0; i < 4; ++i) {
    int lo_ = srow[i] * 64 + sg[i] * 8;
    *(ushort8v*)&As_hi[lo_] = ra_h[i];
    *(ushort8v*)&As_lo[lo_] = ra_l[i];
    *(ushort8v*)&Bs_hi[lo_] = rb_h[i];
    *(ushort8v*)&Bs_lo[lo_] = rb_l[i];
  }
  __syncthreads();

#pragma unroll
  for (int ks = 2; ks < 4; ++ks) {
    const int gl = (((ks & 1) << 2) + (lane >> 4)) ^ (lane & 7);
    bf16x8 ah[4], al[4], bh[4], bl[4];
#pragma unroll
    for (int i = 0; i < 4; ++i) {
      int ra = (abase + i * 16) * 64 + gl * 8;
      ah[i] = *(const bf16x8*)&As_hi[ra];
      al[i] = *(const bf16x8*)&As_lo[ra];
      int rb = (bbase + i * 16) * 64 + gl * 8;
      bh[i] = *(const bf16x8*)&Bs_hi[rb];
      bl[i] = *(const bf16x8*)&Bs_lo[rb];
    }
#pragma unroll
    for (int i = 0; i < 4; ++i)
#pragma unroll
      for (int j = 0; j < 4; ++j) {
        acc[i][j] = __builtin_amdgcn_mfma_f32_16x16x32_bf16(ah[i], bh[j], acc[i][j], 0, 0, 0);
        acc[i][j] = __builtin_amdgcn_mfma_f32_16x16x32_bf16(ah[i], bl[j], acc[i][j], 0, 0, 0);
        acc[i][j] = __builtin_amdgcn_mfma_f32_16x16x32_bf16(al[i], bh[j], acc[i][j], 0, 0, 0);
      }
  }

  const int rq = (lane >> 4) << 2;
  const int cq = lane & 15;
#pragma unroll
  for (int j = 0; j < 4; ++j) {
    int col = bn + wc * 64 + j * 16 + cq;
    float cv = cvec ? cvec[col] : 0.f;
    bool inbf = bf_out && col >= bf_lo && col < bf_hi;
    bool wf32 = !(inbf && skipf32);
#pragma unroll
    for (int i = 0; i < 4; ++i) {
#pragma unroll
      for (int r = 0; r < 4; ++r) {
        int row = bm + wr * 64 + i * 16 + rq + r;
        if (row < M) {
          float val = acc[i][j][r] + cv;
          if (wf32) C[(size_t)row * Nn + col] = val;
          if (inbf) bf_out[(size_t)row * bf_stride + (col - bf_lo)] =
              __builtin_bit_cast(u16, (__bf16)val);
        }
      }
    }
  }
}

// ---------------------------------------------------------------------------
__global__ __launch_bounds__(256) void k_zero(int* __restrict__ p, int n) {
  int i = blockIdx.x * 256 + threadIdx.x;
  if (i < n) p[i] = 0;
}
__global__ __launch_bounds__(256) void k_count(
    const int* __restrict__ dst, int* __restrict__ counts, int E) {
  int e = blockIdx.x * 256 + threadIdx.x;
  if (e < E) atomicAdd(&counts[dst[e]], 1);
}
__global__ __launch_bounds__(1024) void k_scan(
    const int* __restrict__ counts, int* __restrict__ offs,
    int* __restrict__ cursor, int N)
{
  __shared__ int wsum[16];
  const int t = threadIdx.x;
  const int lane = t & 63;
  const int wid = t >> 6;
  int running = 0;
  for (int base = 0; base < N; base += 1024) {
    int v = (base + t < N) ? counts[base + t] : 0;
    int incl = v;
#pragma unroll
    for (int s = 1; s < 64; s <<= 1) {
      int u = __shfl_up(incl, s);
      if (lane >= s) incl += u;
    }
    if (lane == 63) wsum[wid] = incl;
    __syncthreads();
    if (wid == 0) {
      int w = (lane < 16) ? wsum[lane] : 0;
#pragma unroll
      for (int s = 1; s < 16; s <<= 1) {
        int u = __shfl_up(w, s);
        if (lane >= s) w += u;
      }
      if (lane < 16) wsum[lane] = w;
    }
    __syncthreads();
    int wpre = (wid > 0) ? wsum[wid - 1] : 0;
    int tot = wsum[15];
    int inclg = incl + wpre;
    if (base + t < N) {
      offs[base + t + 1] = running + inclg;
      cursor[base + t] = running + inclg - v;
    }
    running += tot;
    __syncthreads();
  }
  if (t == 0) offs[0] = 0;
}
__global__ __launch_bounds__(256) void k_fill(
    const int* __restrict__ src, const int* __restrict__ dst,
    int* __restrict__ cursor, int* __restrict__ csr_src, int E) {
  int e = blockIdx.x * 256 + threadIdx.x;
  if (e < E) {
    int slot = atomicAdd(&cursor[dst[e]], 1);
    csr_src[slot] = src[e];
  }
}

// ---------------------------------------------------------------------------
// TransformerConv aggregation, ONLINE softmax, 4-edge unrolled.
// Q/skip from fp32 C1 (stride 1664); K/V from bf16 panel KV[N][1024].
// ---------------------------------------------------------------------------
__global__ __launch_bounds__(256) void k_tconv(
    const float* __restrict__ C1, const u16* __restrict__ KV,
    const int* __restrict__ offs, const int* __restrict__ csr_src,
    u16* __restrict__ Xhi, u16* __restrict__ Xlo, int N)
{
  const int wid = threadIdx.x >> 6;
  const int lane = threadIdx.x & 63;
  const int node = blockIdx.x * 4 + wid;
  if (node >= N) {
    if (lane < 16) {
      size_t dst = (size_t)node * 128 + (size_t)((lane ^ (node & 7)) * 8);
#pragma unroll
      for (int j = 0; j < 8; ++j) { Xhi[dst + j] = 0; Xlo[dst + j] = 0; }
    }
    return;
  }
  const float* crow = C1 + (size_t)node * QKV_N;
  float q[8];
  {
    float4 q0 = *(const float4*)(crow + lane * 8);
    float4 q1 = *(const float4*)(crow + lane * 8 + 4);
    q[0]=q0.x; q[1]=q0.y; q[2]=q0.z; q[3]=q0.w;
    q[4]=q1.x; q[5]=q1.y; q[6]=q1.z; q[7]=q1.w;
  }
  const int beg = offs[node], end = offs[node + 1];
  float mx = -1e30f;
  float ssum = 0.f;
  float acc[8] = {0.f,0.f,0.f,0.f,0.f,0.f,0.f,0.f};

  int e = beg;
  for (; e + 4 <= end; e += 4) {
    int s0 = csr_src[e];
    int s1 = csr_src[e + 1];
    int s2 = csr_src[e + 2];
    int s3 = csr_src[e + 3];
    const u16* r0 = KV + (size_t)s0 * 1024 + lane * 8;
    const u16* r1 = KV + (size_t)s1 * 1024 + lane * 8;
    const u16* r2 = KV + (size_t)s2 * 1024 + lane * 8;
    const u16* r3 = KV + (size_t)s3 * 1024 + lane * 8;
    bf16x8 k0 = *(const bf16x8*)(r0);
    bf16x8 k1 = *(const bf16x8*)(r1);
    bf16x8 k2 = *(const bf16x8*)(r2);
    bf16x8 k3 = *(const bf16x8*)(r3);
    bf16x8 v0 = *(const bf16x8*)(r0 + 512);
    bf16x8 v1 = *(const bf16x8*)(r1 + 512);
    bf16x8 v2 = *(const bf16x8*)(r2 + 512);
    bf16x8 v3 = *(const bf16x8*)(r3 + 512);
    float p0 = 0.f, p1 = 0.f, p2 = 0.f, p3 = 0.f;
#pragma unroll
    for (int j = 0; j < 8; ++j) {
      p0 += q[j] * (float)k0[j];
      p1 += q[j] * (float)k1[j];
      p2 += q[j] * (float)k2[j];
      p3 += q[j] * (float)k3[j];
    }
    p0 = grp16_sum(p0) * SQRT_H_INV;
    p1 = grp16_sum(p1) * SQRT_H_INV;
    p2 = grp16_sum(p2) * SQRT_H_INV;
    p3 = grp16_sum(p3) * SQRT_H_INV;
    float nm = fmaxf(fmaxf(fmaxf(p0, p1), fmaxf(p2, p3)), mx);
    float sc = expf(mx - nm);
    float w0 = expf(p0 - nm);
    float w1 = expf(p1 - nm);
    float w2 = expf(p2 - nm);
    float w3 = expf(p3 - nm);
    ssum = ssum * sc + (w0 + w1) + (w2 + w3);
#pragma unroll
    for (int j = 0; j < 8; ++j)
      acc[j] = acc[j] * sc + (w0 * (float)v0[j] + w1 * (float)v1[j])
                           + (w2 * (float)v2[j] + w3 * (float)v3[j]);
    mx = nm;
  }
  for (; e < end; ++e) {
    int s0 = csr_src[e];
    const u16* r0 = KV + (size_t)s0 * 1024 + lane * 8;
    bf16x8 ka = *(const bf16x8*)(r0);
    bf16x8 va = *(const bf16x8*)(r0 + 512);
    float p0 = 0.f;
#pragma unroll
    for (int j = 0; j < 8; ++j) p0 += q[j] * (float)ka[j];
    p0 = grp16_sum(p0) * SQRT_H_INV;
    float nm = fmaxf(mx, p0);
    float sc = expf(mx - nm);
    float w0 = expf(p0 - nm);
    ssum = ssum * sc + w0;
#pragma unroll
    for (int j = 0; j < 8; ++j)
      acc[j] = acc[j] * sc + w0 * (float)va[j];
    mx = nm;
  }

  float inv = 1.f / (ssum + 1e-16f);
#pragma unroll
  for (int j = 0; j < 8; ++j) acc[j] *= inv;
#pragma unroll
  for (int j = 0; j < 8; ++j) {
    acc[j] += __shfl_xor(acc[j], 16);
    acc[j] += __shfl_xor(acc[j], 32);
  }
  if (lane < 16) {
    const float* sk = crow + 1536 + lane * 8;
    size_t dst = (size_t)node * 128 + (size_t)((lane ^ (node & 7)) * 8);
#pragma unroll
    for (int j = 0; j < 8; ++j) {
      float x = 0.25f * acc[j] + sk[j];
      u16 h, l;
      split_bf16(x, h, l);
      Xhi[dst + j] = h; Xlo[dst + j] = l;
    }
  }
}

// ---------------------------------------------------------------------------
__global__ __launch_bounds__(256) void k_gat_ad(
    const float* __restrict__ xh, const float* __restrict__ as_w,
    const float* __restrict__ ad_w, float* __restrict__ a_s,
    float* __restrict__ a_d, int N)
{
  const int wid = threadIdx.x >> 6;
  const int lane = threadIdx.x & 63;
  const int node = blockIdx.x * 4 + wid;
  if (node >= N) return;
  const int head = lane >> 4;
  const int c0 = (lane & 15) * 8;
  const float* xr = xh + (size_t)node * 512 + lane * 8;
  float4 x0 = *(const float4*)(xr);
  float4 x1_ = *(const float4*)(xr + 4);
  const float* aw = as_w + head * 128 + c0;
  const float* dw = ad_w + head * 128 + c0;
  float s1 = x0.x*aw[0] + x0.y*aw[1] + x0.z*aw[2] + x0.w*aw[3]
           + x1_.x*aw[4] + x1_.y*aw[5] + x1_.z*aw[6] + x1_.w*aw[7];
  float s2 = x0.x*dw[0] + x0.y*dw[1] + x0.z*dw[2] + x0.w*dw[3]
           + x1_.x*dw[4] + x1_.y*dw[5] + x1_.z*dw[6] + x1_.w*dw[7];
  s1 = grp16_sum(s1);
  s2 = grp16_sum(s2);
  if ((lane & 15) == 0) {
    a_s[node * 4 + head] = s1;
    a_d[node * 4 + head] = s2;
  }
}

// ---------------------------------------------------------------------------
// GAT aggregation, ONLINE softmax, 4-edge unrolled; self from fp32 xh,
// neighbors from bf16 panel xhb[N][512]; writes split hi/lo bf16.
// ---------------------------------------------------------------------------
__global__ __launch_bounds__(256) void k_gat_agg(
    const float* __restrict__ xh, const u16* __restrict__ xhb,
    const float* __restrict__ a_s, const float* __restrict__ a_d,
    const int* __restrict__ offs, const int* __restrict__ csr_src,
    const float* __restrict__ bias,
    u16* __restrict__ Xhi, u16* __restrict__ Xlo, int N)
{
  const int wid = threadIdx.x >> 6;
  const int lane = threadIdx.x & 63;
  const int node = blockIdx.x * 4 + wid;
  if (node >= N) {
    if (lane < 16) {
      size_t dst = (size_t)node * 128 + (size_t)((lane ^ (node & 7)) * 8);
#pragma unroll
      for (int j = 0; j < 8; ++j) { Xhi[dst + j] = 0; Xlo[dst + j] = 0; }
    }
    return;
  }
  const int head = lane >> 4;
  const float adn = a_d[node * 4 + head];
  const float asn = a_s[node * 4 + head];
  float lself = asn + adn;
  lself = lself >= 0.f ? lself : 0.2f * lself;

  float mx = lself;
  float ssum = 1.f;
  float acc[8];
  {
    const float* xr = xh + (size_t)node * 512 + lane * 8;
    float4 x0 = *(const float4*)(xr);
    float4 x1_ = *(const float4*)(xr + 4);
    acc[0]=x0.x; acc[1]=x0.y; acc[2]=x0.z; acc[3]=x0.w;
    acc[4]=x1_.x; acc[5]=x1_.y; acc[6]=x1_.z; acc[7]=x1_.w;
  }

  const int beg = offs[node], end = offs[node + 1];
  int e = beg;
  for (; e + 4 <= end; e += 4) {
    int s0 = csr_src[e];
    int s1 = csr_src[e + 1];
    int s2 = csr_src[e + 2];
    int s3 = csr_src[e + 3];
    float l0 = a_s[s0 * 4 + head];
    float l1 = a_s[s1 * 4 + head];
    float l2 = a_s[s2 * 4 + head];
    float l3 = a_s[s3 * 4 + head];
    const u16* r0 = xhb + (size_t)s0 * 512 + lane * 8;
    const u16* r1 = xhb + (size_t)s1 * 512 + lane * 8;
    const u16* r2 = xhb + (size_t)s2 * 512 + lane * 8;
    const u16* r3 = xhb + (size_t)s3 * 512 + lane * 8;
    bf16x8 xa = *(const bf16x8*)(r0);
    bf16x8 xb = *(const bf16x8*)(r1);
    bf16x8 xc = *(const bf16x8*)(r2);
    bf16x8 xd = *(const bf16x8*)(r3);
    l0 += adn; l1 += adn; l2 += adn; l3 += adn;
    l0 = l0 >= 0.f ? l0 : 0.2f * l0;
    l1 = l1 >= 0.f ? l1 : 0.2f * l1;
    l2 = l2 >= 0.f ? l2 : 0.2f * l2;
    l3 = l3 >= 0.f ? l3 : 0.2f * l3;
    float nm = fmaxf(fmaxf(fmaxf(l0, l1), fmaxf(l2, l3)), mx);
    float sc = expf(mx - nm);
    float w0 = expf(l0 - nm);
    float w1 = expf(l1 - nm);
    float w2 = expf(l2 - nm);
    float w3 = expf(l3 - nm);
    ssum = ssum * sc + (w0 + w1) + (w2 + w3);
#pragma unroll
    for (int j = 0; j < 8; ++j)
      acc[j] = acc[j] * sc + (w0 * (float)xa[j] + w1 * (float)xb[j])
                           + (w2 * (float)xc[j] + w3 * (float)xd[j]);
    mx = nm;
  }
  for (; e < end; ++e) {
    int s0 = csr_src[e];
    float l0 = a_s[s0 * 4 + head] + adn;
    l0 = l0 >= 0.f ? l0 : 0.2f * l0;
    const u16* r0 = xhb + (size_t)s0 * 512 + lane * 8;
    bf16x8 xa = *(const bf16x8*)(r0);
    float nm = fmaxf(mx, l0);
    float sc = expf(mx - nm);
    float w0 = expf(l0 - nm);
    ssum = ssum * sc + w0;
#pragma unroll
    for (int j = 0; j < 8; ++j)
      acc[j] = acc[j] * sc + w0 * (float)xa[j];
    mx = nm;
  }

  float inv = 1.f / (ssum + 1e-16f);
#pragma unroll
  for (int j = 0; j < 8; ++j) acc[j] *= inv;
#pragma unroll
  for (int j = 0; j < 8; ++j) {
    acc[j] += __shfl_xor(acc[j], 16);
    acc[j] += __shfl_xor(acc[j], 32);
  }
  if (lane < 16) {
    const float* b = bias + lane * 8;
    size_t dst = (size_t)node * 128 + (size_t)((lane ^ (node & 7)) * 8);
#pragma unroll
    for (int j = 0; j < 8; ++j) {
      float x = fmaxf(0.25f * acc[j] + b[j], 0.f);
      u16 h, l;
      split_bf16(x, h, l);
      Xhi[dst + j] = h; Xlo[dst + j] = l;
    }
  }
}

// ---------------------------------------------------------------------------
__global__ __launch_bounds__(256) void k_lstm(
    const float* __restrict__ gates, float* __restrict__ out, int N)
{
  int idx = blockIdx.x * 256 + threadIdx.x;
  if (idx >= N * 128) return;
  int n = idx >> 7, c = idx & 127;
  const float* g = gates + (size_t)n * 512;
  float gi = g[c], gg = g[256 + c], go = g[384 + c];
  float cv = (1.f / (1.f + expf(-gi))) * tanhf(gg);
  float hv = (1.f / (1.f + expf(-go))) * tanhf(cv);
  out[idx] = hv;
  out[(size_t)N * 128 + idx] = cv;
}

// ---------------------------------------------------------------------------
extern "C" void kernel_launch(void* const* d_in, const int* in_sizes, int n_in,
                              void* d_out, int out_size, void* d_ws, size_t ws_size,
                              hipStream_t stream) {
  const int*   node_ids = (const int*)d_in[0];
  const int*   etid     = (const int*)d_in[1];
  const int*   src      = (const int*)d_in[2];
  const int*   dst      = (const int*)d_in[3];
  const float* ef       = (const float*)d_in[4];
  const float* inten    = (const float*)d_in[5];
  const float* nemb     = (const float*)d_in[6];
  const float* ett      = (const float*)d_in[7];
  const float* ev_w1 = (const float*)d_in[8],  *ev_b1 = (const float*)d_in[9];
  const float* ev_g1 = (const float*)d_in[10], *ev_bt1 = (const float*)d_in[11];
  const float* ev_w2 = (const float*)d_in[12], *ev_b2 = (const float*)d_in[13];
  const float* ev_g2 = (const float*)d_in[14], *ev_bt2 = (const float*)d_in[15];
  const float* wq = (const float*)d_in[16], *bq = (const float*)d_in[17];
  const float* wk = (const float*)d_in[18], *bk = (const float*)d_in[19];
  const float* wv = (const float*)d_in[20], *bv = (const float*)d_in[21];
  const float* wskip = (const float*)d_in[22], *bskip = (const float*)d_in[23];
  const float* g0_w = (const float*)d_in[24], *g0_as = (const float*)d_in[25];
  const float* g0_ad = (const float*)d_in[26], *g0_b = (const float*)d_in[27];
  const float* g1_w = (const float*)d_in[28], *g1_as = (const float*)d_in[29];
  const float* g1_ad = (const float*)d_in[30], *g1_b = (const float*)d_in[31];
  const float* wih = (const float*)d_in[32];
  const float* bih = (const float*)d_in[34], *bhh = (const float*)d_in[35];

  const int N = in_sizes[0];
  const int K = in_sizes[1];
  const int E = in_sizes[2];
  const int EV = in_sizes[4];

  const int gridMy = (N + 127) / 128;
  const int Npad = gridMy * 128;

  float* ws = (float*)d_ws;
  size_t o = 0;
  float* e_vec = ws + o; o += 128;
  float* cvec1 = ws + o; o += QKV_N;
  float* cvec2 = ws + o; o += 512;
  float* B1    = ws + o; o += (size_t)128 * QKV_N;
  float* C1    = ws + o; o += (size_t)N * QKV_N;
  float* xh    = ws + o; o += (size_t)N * 512;
  u16* Ahi  = (u16*)(ws + o); o += (size_t)Npad * 64;
  u16* Alo  = (u16*)(ws + o); o += (size_t)Npad * 64;
  u16* XShi = (u16*)(ws + o); o += (size_t)Npad * 64;
  u16* XSlo = (u16*)(ws + o); o += (size_t)Npad * 64;
  u16* Bqhi = (u16*)(ws + o); o += (size_t)QKV_N * 64;
  u16* Bqlo = (u16*)(ws + o); o += (size_t)QKV_N * 64;
  u16* Bg0hi = (u16*)(ws + o); o += 512 * 64;
  u16* Bg0lo = (u16*)(ws + o); o += 512 * 64;
  u16* Bg1hi = (u16*)(ws + o); o += 512 * 64;
  u16* Bg1lo = (u16*)(ws + o); o += 512 * 64;
  u16* Bwhi  = (u16*)(ws + o); o += 512 * 64;
  u16* Bwlo  = (u16*)(ws + o); o += 512 * 64;
  u16* KV   = (u16*)(ws + o); o += (size_t)Npad * 512;  // [N][1024] u16
  u16* xhb  = (u16*)(ws + o); o += (size_t)Npad * 256;  // [N][512] u16
  float* a_s   = ws + o; o += (size_t)N * 4;
  float* a_d   = ws + o; o += (size_t)N * 4;
  int* counts  = (int*)(ws + o); o += N;
  int* offs    = (int*)(ws + o); o += (size_t)N + 1;
  int* cursor  = (int*)(ws + o); o += N;
  int* csr_src = (int*)(ws + o); o += E;

  float* out = (float*)d_out;

  const int nodeBlocks = (N + 3) / 4;
  const int nodeBlocksPad = Npad / 4;

  k_event<<<1, 128, 0, stream>>>(ef, EV, ev_w1, ev_b1, ev_g1, ev_bt1,
                                 ev_w2, ev_b2, ev_g2, ev_bt2,
                                 ett, etid, inten, K, e_vec);
  k_cvec<<<(QKV_N + 255) / 256, 256, 0, stream>>>(e_vec, wq, bq, wk, bk, wv, bv,
                                                  wskip, bskip, cvec1);
  k_pack<<<(D_DIM * QKV_N + 255) / 256, 256, 0, stream>>>(wq, wk, wv, wskip, B1);
  k_cvec2<<<2, 256, 0, stream>>>(bih, bhh, cvec2);

  k_split_a<<<(Npad * 16 + 255) / 256, 256, 0, stream>>>(nemb, node_ids, Ahi, Alo, N, Npad);
  k_split_bt<<<(QKV_N * 16 + 255) / 256, 256, 0, stream>>>(B1, Bqhi, Bqlo, QKV_N);
  k_split_bt<<<(512 * 16 + 255) / 256, 256, 0, stream>>>(g0_w, Bg0hi, Bg0lo, 512);
  k_split_bt<<<(512 * 16 + 255) / 256, 256, 0, stream>>>(g1_w, Bg1hi, Bg1lo, 512);
  k_split_bt<<<(512 * 16 + 255) / 256, 256, 0, stream>>>(wih, Bwhi, Bwlo, 512);

  k_zero<<<(N + 255) / 256, 256, 0, stream>>>(counts, N);
  k_count<<<(E + 255) / 256, 256, 0, stream>>>(dst, counts, E);
  k_scan<<<1, 1024, 0, stream>>>(counts, offs, cursor, N);
  k_fill<<<(E + 255) / 256, 256, 0, stream>>>(src, dst, cursor, csr_src, E);

  // QKV: fp32 q/skip -> C1 (K/V cols skipped); bf16 K/V -> KV panel
  mfma_gemm<<<dim3(QKV_N / 128, gridMy), 256, 0, stream>>>(
      Ahi, Alo, Bqhi, Bqlo, cvec1, C1, N, QKV_N,
      KV, 512, 1536, 1024, 1);

  k_tconv<<<nodeBlocksPad, 256, 0, stream>>>(C1, KV, offs, csr_src, XShi, XSlo, N);

  // GAT layer 1: fp32 xh + bf16 xhb
  mfma_gemm<<<dim3(4, gridMy), 256, 0, stream>>>(
      XShi, XSlo, Bg0hi, Bg0lo, nullptr, xh, N, 512,
      xhb, 0, 512, 512, 0);
  k_gat_ad<<<nodeBlocks, 256, 0, stream>>>(xh, g0_as, g0_ad, a_s, a_d, N);
  k_gat_agg<<<nodeBlocksPad, 256, 0, stream>>>(xh, xhb, a_s, a_d, offs, csr_src,
                                               g0_b, XShi, XSlo, N);

  // GAT layer 2
  mfma_gemm<<<dim3(4, gridMy), 256, 0, stream>>>(
      XShi, XSlo, Bg1hi, Bg1lo, nullptr, xh, N, 512,
      xhb, 0, 512, 512, 0);
  k_gat_ad<<<nodeBlocks, 256, 0, stream>>>(xh, g1_as, g1_ad, a_s, a_d, N);
  k_gat_agg<<<nodeBlocksPad, 256, 0, stream>>>(xh, xhb, a_s, a_d, offs, csr_src,
                                               g1_b, XShi, XSlo, N);

  // LSTM
  mfma_gemm<<<dim3(4, gridMy), 256, 0, stream>>>(
      XShi, XSlo, Bwhi, Bwlo, cvec2, xh, N, 512,
      nullptr, 0, 0, 0, 0);
  k_lstm<<<((N * 128) + 255) / 256, 256, 0, stream>>>(xh, out, N);
}